// Round 7
// baseline (2180.379 us; speedup 1.0000x reference)
//
#include <hip/hip_runtime.h>

typedef unsigned long long ull;

#define NN0 80000
#define EE0 480000
#define KK1 40000
#define KK2 20000
#define FLATMAX 8000000
#define SCH 4096
#define CDIV(a,b) (((a)+(b)-1)/(b))
#define HBINS (1<<21)
#define LSZ 2048

// counter slots
#define C_E1 2
#define C_E2 3
#define C_M0 5
#define C_M1 6

__device__ __forceinline__ int getE(const int* p, int s){ if(!p) return s; int e=*p; return e<s? e : s; }
__device__ __forceinline__ float leakyf(float x){ return x>0.f? x : 0.2f*x; }
__device__ __forceinline__ double leakyd(double x){ return x>0.0? x : 0.2*x; }
__device__ __forceinline__ float eluf(float x){ return x>0.f? x : (expf(x)-1.f); }

__device__ __forceinline__ ull encd(double f){ ull u=(ull)__double_as_longlong(f); return (u>>63)? ~u : (u|0x8000000000000000ULL); }

// ---------------- GEMM: xl/xr projections ----------------
// 32 rows per block; input tile staged in LDS; each thread owns a 4row x 4col (x dual) register tile.
template<int MODE, bool DUAL>
__global__ void gemm_k(const float* __restrict__ F1, const float* __restrict__ pos,
                       const float* __restrict__ yv,
                       const float* __restrict__ W1, const float* __restrict__ W2,
                       const float* __restrict__ bias,
                       float* __restrict__ O1, float* __restrict__ O2, int N)
{
  const int K = MODE==0? 11 : (MODE==1? 131 : 128);
  __shared__ float lf[32][132];   // stride 132: float4-aligned rows, broadcast reads
  int t = threadIdx.x;
  int row0 = blockIdx.x*32;

  // ---- stage 32-row input tile into LDS (coalesced) ----
  if(MODE==0){
    for(int i=t;i<32*11;i+=256){
      int r=i/11, k=i-r*11; int row=row0+r;
      float f=0.f;
      if(row<N) f = (k<5)? F1[(size_t)row*5+k] : (k<8? pos[(size_t)row*3+(k-5)] : yv[0]);
      lf[r][k]=f;
    }
  } else {
    for(int i=t;i<32*32;i+=256){
      int r=i>>5, c4=i&31; int row=row0+r;
      float4 v; v.x=0.f;v.y=0.f;v.z=0.f;v.w=0.f;
      if(row<N) v = *(const float4*)(F1+(size_t)row*128+c4*4);
      *(float4*)(&lf[r][c4*4]) = v;
    }
    if(MODE==1){
      for(int i=t;i<32*3;i+=256){
        int r=i/3, d=i-r*3; int row=row0+r;
        lf[r][128+d] = (row<N)? pos[(size_t)row*3+d] : 0.f;
      }
    }
  }
  __syncthreads();

  int cg = t&31, rg = t>>5;      // 32 col-groups x 8 row-groups
  int g = cg*4;
  int rbase = rg*4;

  float acc1[4][4]; float acc2[4][4];
  #pragma unroll
  for(int rr=0;rr<4;rr++)
    #pragma unroll
    for(int c=0;c<4;c++){ acc1[rr][c]=0.f; acc2[rr][c]=0.f; }

  #pragma unroll 4
  for(int k=0;k<K;k++){
    float4 w = *(const float4*)(W1 + (size_t)k*128 + g);
    float4 v; v.x=0.f;v.y=0.f;v.z=0.f;v.w=0.f;
    if(DUAL) v = *(const float4*)(W2 + (size_t)k*128 + g);
    #pragma unroll
    for(int rr=0;rr<4;rr++){
      float f = lf[rbase+rr][k];
      acc1[rr][0]+=f*w.x; acc1[rr][1]+=f*w.y; acc1[rr][2]+=f*w.z; acc1[rr][3]+=f*w.w;
      if(DUAL){ acc2[rr][0]+=f*v.x; acc2[rr][1]+=f*v.y; acc2[rr][2]+=f*v.z; acc2[rr][3]+=f*v.w; }
    }
  }

  float4 bb; bb.x=0.f;bb.y=0.f;bb.z=0.f;bb.w=0.f;
  if(bias) bb = *(const float4*)(bias+g);
  #pragma unroll
  for(int rr=0;rr<4;rr++){
    int row = row0 + rbase + rr;
    if(row<N){
      float4 r1; r1.x=acc1[rr][0]+bb.x; r1.y=acc1[rr][1]+bb.y; r1.z=acc1[rr][2]+bb.z; r1.w=acc1[rr][3]+bb.w;
      *(float4*)(O1+(size_t)row*128+g) = r1;
      if(DUAL){
        float4 r2; r2.x=acc2[rr][0]; r2.y=acc2[rr][1]; r2.z=acc2[rr][2]; r2.w=acc2[rr][3];
        *(float4*)(O2+(size_t)row*128+g) = r2;
      }
    }
  }
}

// ---------------- multi-block exclusive scan ----------------
__global__ void scan_p1(const int* __restrict__ in, const int* pN, int Ns, int* __restrict__ bsums){
  __shared__ int red[256];
  int n = getE(pN,Ns);
  int base = blockIdx.x*SCH;
  int s=0;
  for(int i=base+threadIdx.x; i<base+SCH; i+=256) if(i<n) s+=in[i];
  red[threadIdx.x]=s; __syncthreads();
  for(int o=128;o;o>>=1){ if(threadIdx.x<(unsigned)o) red[threadIdx.x]+=red[threadIdx.x+o]; __syncthreads(); }
  if(threadIdx.x==0) bsums[blockIdx.x]=red[0];
}
__global__ void scan_p2(int* bsums, int nb){
  __shared__ int lds[256];
  int t=threadIdx.x;
  int v = (t<nb)? bsums[t] : 0;
  lds[t]=v; __syncthreads();
  for(int o=1;o<256;o<<=1){ int u=0; if(t>=o) u=lds[t-o]; __syncthreads(); lds[t]+=u; __syncthreads(); }
  if(t<nb) bsums[t]=lds[t]-v;
}
__global__ void scan_p3(const int* __restrict__ in, int* __restrict__ out, const int* pN, int Ns,
                        const int* __restrict__ bsums, int* total){
  __shared__ int tsum[256];
  int n = getE(pN,Ns);
  int base = blockIdx.x*SCH + threadIdx.x*16;
  int v[16]; int s=0;
  #pragma unroll
  for(int q=0;q<16;q++){ int i=base+q; int xv=(i<n)? in[i]:0; v[q]=s; s+=xv; }
  tsum[threadIdx.x]=s; __syncthreads();
  int mine=s;
  for(int o=1;o<256;o<<=1){ int u=0; if(threadIdx.x>=(unsigned)o) u=tsum[threadIdx.x-o]; __syncthreads(); tsum[threadIdx.x]+=u; __syncthreads(); }
  int pre = bsums[blockIdx.x] + tsum[threadIdx.x] - mine;
  #pragma unroll
  for(int q=0;q<16;q++){
    int i=base+q;
    if(i<=n){
      int val = pre+v[q];
      out[i]=val;
      if(i==n && total) *total=val;
    }
  }
}

// ---------------- CSR builders ----------------
__global__ void count_src(const int* __restrict__ es, const int* pE, int Es, int* cnts){
  int e = blockIdx.x*256+threadIdx.x; int E = getE(pE,Es); if(e>=E) return;
  atomicAdd(&cnts[es[e]], 1);
}
// dst-CSR: eord = edge id ordered by dst; insrc = source node ordered by dst
__global__ void fill_eord(const int* __restrict__ es, const int* __restrict__ ed, const int* pE, int Es,
                          const int* __restrict__ dstarts, int* cursor, int* eord, int* insrc){
  int e = blockIdx.x*256+threadIdx.x; int E = getE(pE,Es); if(e>=E) return;
  int d = ed[e];
  int p = dstarts[d] + atomicAdd(&cursor[d],1);
  eord[p] = e;
  insrc[p] = es[e];
}
__global__ void loop_csr_f(const int* __restrict__ insrc,
                           const int* __restrict__ dstarts, const float* __restrict__ pos,
                           float* __restrict__ loopat, int N)
{
  int d = blockIdx.x*256+threadIdx.x; if(d>=N) return;
  int r0=dstarts[d], r1=dstarts[d+1];
  float pd0=pos[d*3], pd1=pos[d*3+1], pd2=pos[d*3+2];
  float l0=0,l1=0,l2=0;
  for(int j=r0;j<r1;j++){
    int s = insrc[j];
    l0 += pd0-pos[s*3]; l1 += pd1-pos[s*3+1]; l2 += pd2-pos[s*3+2];
  }
  float inv = 1.f/fmaxf((float)(r1-r0), 1.f);
  loopat[d*3+0]=l0*inv; loopat[d*3+1]=l1*inv; loopat[d*3+2]=l2*inv;
}

// ---------------- feature GATv2 (fp32) ----------------
__global__ void feat_logits(const int* __restrict__ es, const int* __restrict__ ed, const int* pE, int Es, int N,
    const float* __restrict__ A, const float* __restrict__ B, const float* __restrict__ pos,
    const float* __restrict__ We, const float* __restrict__ att, const float* __restrict__ loopat,
    float* __restrict__ zb)
{
  int gid = blockIdx.x*blockDim.x + threadIdx.x;
  int w = gid>>6, lane = gid&63;
  int E = getE(pE,Es);
  if(w >= E+N) return;
  int s,d; float e0,e1,e2;
  if(w<E){ s=es[w]; d=ed[w]; e0=pos[d*3]-pos[s*3]; e1=pos[d*3+1]-pos[s*3+1]; e2=pos[d*3+2]-pos[s*3+2]; }
  else   { int n=w-E; s=n; d=n; e0=loopat[n*3]; e1=loopat[n*3+1]; e2=loopat[n*3+2]; }
  int c=lane, c2=lane+64;
  float m1 = A[(size_t)s*128+c ] + B[(size_t)d*128+c ] + e0*We[c ] + e1*We[128+c ] + e2*We[256+c ];
  float m2 = A[(size_t)s*128+c2] + B[(size_t)d*128+c2] + e0*We[c2] + e1*We[128+c2] + e2*We[256+c2];
  float p = leakyf(m1)*att[c] + leakyf(m2)*att[c2];
  for(int off=32; off; off>>=1) p += __shfl_down(p, off, 64);
  if(lane==0) zb[w]=p;
}

__global__ void feat_acc_csr(const int* __restrict__ insrc, const int* __restrict__ eord,
                             const int* __restrict__ dstarts, const int* pE, int Es,
                             const float* __restrict__ A, const float* __restrict__ zb,
                             const float* __restrict__ bias, float* __restrict__ h, int N)
{
  int w = (blockIdx.x*256+threadIdx.x)>>6;
  int lane = threadIdx.x&63;
  if(w>=N) return;
  int E = getE(pE,Es);
  int r0=dstarts[w], r1=dstarts[w+1];
  float mx = zb[E+w];
  for(int j=r0+lane; j<r1; j+=64) mx = fmaxf(mx, zb[eord[j]]);
  for(int o=32;o;o>>=1) mx = fmaxf(mx, __shfl_down(mx,o,64));
  mx = __shfl(mx, 0, 64);
  float denom = 0.f;
  float2 acc; acc.x=0.f; acc.y=0.f;
  for(int j=r0;j<r1;j++){
    int e = eord[j]; int s = insrc[j];
    float z = expf(zb[e]-mx);
    denom += z;
    float2 v = *(const float2*)(A + (size_t)s*128 + lane*2);
    acc.x += z*v.x; acc.y += z*v.y;
  }
  {
    float z = expf(zb[E+w]-mx);
    denom += z;
    float2 v = *(const float2*)(A + (size_t)w*128 + lane*2);
    acc.x += z*v.x; acc.y += z*v.y;
  }
  float inv = 1.f/denom;
  float2 bb = *(const float2*)(bias + lane*2);
  acc.x = eluf(acc.x*inv + bb.x); acc.y = eluf(acc.y*inv + bb.y);
  *(float2*)(h + (size_t)w*128 + lane*2) = acc;
}

// ---------------- score GATv2 (fp64) ----------------
// warp-cooperative: 32 lanes per node, coalesced reads of h, shfl-reduce.
__global__ void gemm_score(const float* __restrict__ h, const float* __restrict__ pos,
                           const float* __restrict__ pWl, const float* __restrict__ pWr,
                           double* __restrict__ xls, double* __restrict__ xrs, int N)
{
  int t = threadIdx.x;
  int lane = t&31;
  int n = blockIdx.x*8 + (t>>5);
  if(n>=N) return;
  double sl=0, sr=0;
  #pragma unroll
  for(int q=0;q<4;q++){
    int k = lane + q*32;
    double f = (double)h[(size_t)n*128+k];
    sl += f*(double)pWl[k]; sr += f*(double)pWr[k];
  }
  if(lane<3){
    double f = (double)pos[n*3+lane];
    sl += f*(double)pWl[128+lane]; sr += f*(double)pWr[128+lane];
  }
  for(int o=16;o;o>>=1){ sl += __shfl_down(sl,o,32); sr += __shfl_down(sr,o,32); }
  if(lane==0){ xls[n]=sl; xrs[n]=sr; }
}

// fused score GATv2 with ON-THE-FLY candidate enumeration from the dst-CSR:
// cand(w) = in(w) ∪ in(in(w)); phase-2 walk PARALLELIZED across lanes
// (one in-neighbor per lane; shfl exclusive scan gives LDS write offsets).
__global__ void score_fused2(const int* __restrict__ insrc, const int* __restrict__ dstarts,
                             const float* __restrict__ pos,
                             const double* __restrict__ xls, const double* __restrict__ xrs,
                             const float* __restrict__ pWe, const float* __restrict__ paP,
                             const float* __restrict__ pbP,
                             double* __restrict__ score, int N)
{
  int w = blockIdx.x; if(w>=N) return;
  __shared__ int ls[LSZ];
  int lane = threadIdx.x;
  int r0=dstarts[w], r1=dstarts[w+1]; int din=r1-r0;
  // phase 1: 1-hop candidates
  for(int j=lane;j<din && j<LSZ;j+=64) ls[j]=insrc[r0+j];
  __syncthreads();
  // phase 2 (lane-parallel): lane handles in-neighbor (base+lane); exclusive scan of lens -> offsets
  int off = din<LSZ? din : LSZ;
  for(int base=0; base<din && base<LSZ; base+=64){
    int t = base + lane;
    int u0=0, len=0;
    if(t<din && t<LSZ){
      int u = ls[t];
      u0 = dstarts[u]; len = dstarts[u+1]-u0;
    }
    int pre = len;
    #pragma unroll
    for(int o=1;o<64;o<<=1){ int v=__shfl_up(pre,o,64); if(lane>=o) pre+=v; }
    int tot = __shfl(pre, 63, 64);
    int myoff = off + pre - len;
    for(int j=0;j<len;j++){ int p=myoff+j; if(p<LSZ) ls[p]=insrc[u0+j]; }
    off += tot;
  }
  int d = off<LSZ? off : LSZ;
  __syncthreads();

  float pd0=pos[w*3], pd1=pos[w*3+1], pd2=pos[w*3+2];
  double w0=(double)pWe[0], w1=(double)pWe[1], w2=(double)pWe[2], pa=(double)paP[0];
  double xrd=xrs[w];
  ull umask=0;
  double mx=-1e300, s0=0,s1=0,s2=0; int ucnt=0;
  int nb=0;
  for(int j=lane; j<d; j+=64, nb++){
    int s = ls[j];
    bool uniq = true;
    for(int q=0;q<j;q++) if(ls[q]==s){ uniq=false; break; }
    if(uniq){
      umask |= 1ULL<<nb;
      ucnt++;
      double e0=(double)(pd0-pos[s*3]), e1=(double)(pd1-pos[s*3+1]), e2=(double)(pd2-pos[s*3+2]);
      s0+=e0; s1+=e1; s2+=e2;
      double lg = leakyd(xls[s]+xrd + e0*w0+e1*w1+e2*w2) * pa;
      mx = fmax(mx, lg);
    }
  }
  for(int o=32;o;o>>=1){
    mx = fmax(mx, __shfl_down(mx,o,64));
    s0 += __shfl_down(s0,o,64);
    s1 += __shfl_down(s1,o,64);
    s2 += __shfl_down(s2,o,64);
    ucnt += __shfl_down(ucnt,o,64);
  }
  mx=__shfl(mx,0,64); s0=__shfl(s0,0,64); s1=__shfl(s1,0,64); s2=__shfl(s2,0,64); ucnt=__shfl(ucnt,0,64);
  double invd = 1.0/(double)(ucnt>0? ucnt : 1);
  double lg_self = leakyd(xls[w]+xrd + (s0*invd)*w0 + (s1*invd)*w1 + (s2*invd)*w2) * pa;
  mx = fmax(mx, lg_self);
  double den=0, acc=0;
  nb=0;
  for(int j=lane; j<d; j+=64, nb++){
    if((umask>>nb)&1ULL){
      int s = ls[j];
      double e0=(double)(pd0-pos[s*3]), e1=(double)(pd1-pos[s*3+1]), e2=(double)(pd2-pos[s*3+2]);
      double lg = leakyd(xls[s]+xrd + e0*w0+e1*w1+e2*w2) * pa;
      double z = exp(lg-mx);
      den += z; acc += z*xls[s];
    }
  }
  for(int o=32;o;o>>=1){
    den += __shfl_down(den,o,64);
    acc += __shfl_down(acc,o,64);
  }
  if(lane==0){
    double z = exp(lg_self-mx);
    den += z; acc += z*xls[w];
    score[w] = tanh(acc/den + (double)pbP[0]);
  }
}

// ---------------- top-k: 2-round 21-bit refine select + bucketed ranking ----------------
__global__ void enc_scores(const double* __restrict__ score, int N, ull* __restrict__ ek,
                           int* __restrict__ rank){
  int i = blockIdx.x*256+threadIdx.x; if(i>=N) return;
  ek[i] = encd(score[i]);
  rank[i] = 0x3f3f3f3f;
}
// histogram of 21-bit digit at `shift`, restricted to keys whose bits above shift+21 match selT
__global__ void hist_g(const ull* __restrict__ ek, int N, int shift, const ull* __restrict__ selT,
                       int* __restrict__ hist){
  int i = blockIdx.x*256+threadIdx.x; if(i>=N) return;
  ull key = ek[i];
  if(shift+21 < 64){
    if((key >> (shift+21)) != ((*selT) >> (shift+21))) return;
  }
  atomicAdd(&hist[(int)((key>>shift)&0x1FFFFF)], 1);
}
__global__ void part21(const int* __restrict__ hist, int* __restrict__ partial){
  __shared__ int red[256];
  int b = blockIdx.x;
  int s=0;
  for(int i=threadIdx.x;i<1024;i+=256) s += hist[b*1024+i];
  red[threadIdx.x]=s; __syncthreads();
  for(int o=128;o;o>>=1){ if(threadIdx.x<(unsigned)o) red[threadIdx.x]+=red[threadIdx.x+o]; __syncthreads(); }
  if(threadIdx.x==0) partial[b]=red[0];
}
// find the bin containing the keff-th largest key; update selT (bin at `shift`) and selRB (count strictly above)
__global__ void findbin_g(const int* __restrict__ partial, const int* __restrict__ hist,
                          ull* __restrict__ selT, int* __restrict__ selRB, int k, int shift){
  __shared__ int ts[256];
  __shared__ int cstar, rbase;
  int t=threadIdx.x;
  int keff = k - *selRB;
  int s8[8]; int mysum=0;
  #pragma unroll
  for(int q=0;q<8;q++){ s8[q]=partial[t*8+q]; mysum+=s8[q]; }
  ts[t]=mysum; __syncthreads();
  for(int o=1;o<256;o<<=1){ int u=(t+o<256)? ts[t+o]:0; __syncthreads(); ts[t]+=u; __syncthreads(); }
  int after = (t<255)? ts[t+1] : 0;
  if(ts[t] >= keff && after < keff){
    int run = after;
    for(int q=7;q>=0;q--){
      if(run < keff && run + s8[q] >= keff){ cstar = t*8+q; rbase = run; }
      run += s8[q];
    }
  }
  __syncthreads();
  int cs=cstar, rb=rbase;
  int b4[4]; int ms=0;
  #pragma unroll
  for(int q=0;q<4;q++){ b4[q]=hist[cs*1024 + t*4 + q]; ms+=b4[q]; }
  ts[t]=ms; __syncthreads();
  for(int o=1;o<256;o<<=1){ int u=(t+o<256)? ts[t+o]:0; __syncthreads(); ts[t]+=u; __syncthreads(); }
  int after2 = (t<255)? ts[t+1] : 0;
  if(rb+ts[t] >= keff && rb+after2 < keff){
    int run = rb+after2;
    for(int q=3;q>=0;q--){
      if(run < keff && run + b4[q] >= keff){
        *selT |= ((ull)(cs*1024 + t*4 + q)) << shift;
        *selRB = (k - keff) + run;
      }
      run += b4[q];
    }
  }
}
// ----- bucketed exact ranking of candidates (key >= selT) -----
// bucket digit = complemented top-21 bits => ascending bucket = descending key.
__global__ void rank_hist(const ull* __restrict__ ek, int N, const ull* __restrict__ selT,
                          int* __restrict__ hist){
  int i = blockIdx.x*256+threadIdx.x; if(i>=N) return;
  ull key = ek[i]; if(key < *selT) return;
  int dg = (int)((~key >> 43) & 0x1FFFFF);
  atomicAdd(&hist[dg], 1);
}
// per-1024-bin-block exclusive scan + global block offset -> binstarts; last thread writes total
__global__ void binscan(const int* __restrict__ hist, const int* __restrict__ p2,
                        int* __restrict__ binstarts){
  __shared__ int ts[256];
  int b = blockIdx.x, t = threadIdx.x;
  int v[4]; int s=0;
  #pragma unroll
  for(int q=0;q<4;q++){ v[q]=s; s+=hist[b*1024 + t*4 + q]; }
  ts[t]=s; __syncthreads();
  int mine=s;
  for(int o=1;o<256;o<<=1){ int u=0; if(t>=(unsigned)o) u=ts[t-o]; __syncthreads(); ts[t]+=u; __syncthreads(); }
  int pre = p2[b] + ts[t] - mine;
  #pragma unroll
  for(int q=0;q<4;q++) binstarts[b*1024 + t*4 + q] = pre + v[q];
  if(b==2047 && t==255) binstarts[HBINS] = p2[b] + ts[255];
}
// scatter candidate (key,idx) into bucket-ordered member arrays (consumes hist counts)
__global__ void rank_fill(const ull* __restrict__ ek, int N, const ull* __restrict__ selT,
                          const int* __restrict__ binstarts, int* __restrict__ hist,
                          ull* __restrict__ mkeys, int* __restrict__ midx){
  int i = blockIdx.x*256+threadIdx.x; if(i>=N) return;
  ull key = ek[i]; if(key < *selT) return;
  int dg = (int)((~key >> 43) & 0x1FFFFF);
  int o = atomicSub(&hist[dg], 1) - 1;
  int p = binstarts[dg] + o;
  mkeys[p] = key; midx[p] = i;
}
// exact rank: bucket start + same-bucket (key desc, idx asc) pairwise over STREAMED inline keys
__global__ void rank_within(const int* __restrict__ binstarts,
                            const ull* __restrict__ mkeys, const int* __restrict__ midx,
                            int* __restrict__ rank, int Nmax){
  int m = blockIdx.x*256+threadIdx.x; if(m>=Nmax) return;
  int total = binstarts[HBINS]; if(m>=total) return;
  ull key = mkeys[m]; int ii = midx[m];
  int dg = (int)((~key >> 43) & 0x1FFFFF);
  int s = binstarts[dg], e = binstarts[dg+1];
  int cnt = 0;
  for(int j=s;j<e;j++){
    ull kj = mkeys[j];
    cnt += (kj > key) || (kj == key && midx[j] < ii);
  }
  rank[ii] = s + cnt;
}
__global__ void scatter_perm(const int* __restrict__ rank, int N, int k, int* __restrict__ perm){
  int i = blockIdx.x*256+threadIdx.x; if(i>=N) return;
  int r = rank[i]; if(r<k) perm[r]=i;
}
__global__ void pool_gather(const float* __restrict__ h, const double* __restrict__ score,
                            const int* __restrict__ perm, int k, float* __restrict__ outA){
  int idx = blockIdx.x*256+threadIdx.x; if(idx>=k*32) return;
  int r = idx>>5, g = (idx&31)*4;
  int p = perm[r]; float sc = (float)score[p];
  const float4 x = *(const float4*)(h + (size_t)p*128 + g);
  float4 o; o.x=x.x*sc; o.y=x.y*sc; o.z=x.z*sc; o.w=x.w*sc;
  *(float4*)(outA + (size_t)r*128 + g) = o;
}
__global__ void pos_gather(const float* __restrict__ posc, const int* __restrict__ perm, int k, float* __restrict__ posn){
  int idx = blockIdx.x*256+threadIdx.x; if(idx>=k*3) return;
  int r = idx/3, j = idx-r*3;
  posn[idx] = posc[perm[r]*3+j];
}

// ---------------- filter_adj ----------------
__global__ void filter_flags(const int* __restrict__ es, const int* __restrict__ ed, const int* pE, int Es,
                             const int* __restrict__ rank, int k, int* __restrict__ flags){
  int e = blockIdx.x*256+threadIdx.x; int E = getE(pE,Es); if(e>=E) return;
  flags[e] = (rank[es[e]]<k && rank[ed[e]]<k) ? 1 : 0;
}
__global__ void filter_write(const int* __restrict__ es, const int* __restrict__ ed, const int* pE, int Es,
                             const int* __restrict__ rank, int k, const int* __restrict__ scanout,
                             int* __restrict__ ns, int* __restrict__ nd){
  int e = blockIdx.x*256+threadIdx.x; int E = getE(pE,Es); if(e>=E) return;
  int rs = rank[es[e]], rd = rank[ed[e]];
  if(rs<k && rd<k){ int p = scanout[e]; ns[p]=rs; nd[p]=rd; }
}

// ---------------- output emit ----------------
__global__ void calc_offsets(const int* __restrict__ cnt, long long* __restrict__ offs){
  if(blockIdx.x==0 && threadIdx.x==0){
    long long E1 = cnt[C_E1], E2 = cnt[C_E2];
    long long o = (long long)KK2*128;
    offs[0]=0;
    offs[1]=o; o += 2*E2;
    offs[2]=o; o += 2*E1;
    offs[3]=o; o += 2*(long long)EE0;
    offs[4]=o; o += (long long)KK2*3;
    offs[5]=o; o += (long long)KK1*3;
    offs[6]=o; o += (long long)NN0*3;
    offs[7]=o; o += 3*E2;
    offs[8]=o; o += 3*E1;
    offs[9]=o;
  }
}
__global__ void emit_pe(const int* __restrict__ s, const int* __restrict__ d, const int* pE, int Es,
                        const long long* __restrict__ offs, int oi, float* __restrict__ out){
  int e = blockIdx.x*256+threadIdx.x; int E = getE(pE,Es); if(e>=E) return;
  long long o = offs[oi];
  out[o+e]   = (float)s[e];
  out[o+E+e] = (float)d[e];
}
__global__ void emit_pp(const float* __restrict__ p, int n, const long long* __restrict__ offs, int oi, float* __restrict__ out){
  int i = blockIdx.x*256+threadIdx.x; if(i>=n) return;
  out[offs[oi]+i] = p[i];
}
__global__ void emit_eas(const int* __restrict__ s, const int* __restrict__ d, const int* pE, int Es,
                         const float* __restrict__ pos, const long long* __restrict__ offs, int oi, float* __restrict__ out){
  int e = blockIdx.x*256+threadIdx.x; int E = getE(pE,Es); if(e>=E) return;
  long long o = offs[oi];
  int ss=s[e], dd=d[e];
  out[o+3*e+0] = pos[dd*3+0]-pos[ss*3+0];
  out[o+3*e+1] = pos[dd*3+1]-pos[ss*3+1];
  out[o+3*e+2] = pos[dd*3+2]-pos[ss*3+2];
}

// =======================================================================
extern "C" void kernel_launch(void* const* d_in, const int* in_sizes, int n_in,
                              void* d_out, int out_size, void* d_ws, size_t ws_size,
                              hipStream_t stream)
{
  const float* x    = (const float*)d_in[0];
  const float* yv   = (const float*)d_in[1];
  const float* pos0 = (const float*)d_in[2];
  const int*   ei   = (const int*)d_in[3];
  const float* Wl0  = (const float*)d_in[4];
  const float* Wr0  = (const float*)d_in[5];
  const float* We0  = (const float*)d_in[6];
  const float* a0   = (const float*)d_in[7];
  const float* b0   = (const float*)d_in[8];
  const float* Wls  = (const float*)d_in[9];
  const float* Wrs  = (const float*)d_in[10];
  const float* Wes  = (const float*)d_in[11];
  const float* atts = (const float*)d_in[12];
  const float* bs   = (const float*)d_in[13];
  const float* pWl  = (const float*)d_in[14];
  const float* pWr  = (const float*)d_in[15];
  const float* pWe  = (const float*)d_in[16];
  const float* pa   = (const float*)d_in[17];
  const float* pb   = (const float*)d_in[18];
  const float* linW = (const float*)d_in[19];
  const float* linb = (const float*)d_in[20];
  float* out = (float*)d_out;

  const int* eisrc = ei;
  const int* eidst = ei + EE0;

  char* base = (char*)d_ws; size_t off = 0;
  auto alloc = [&](size_t b)->void*{
    off = (off + 255) & ~(size_t)255;
    void* p = base + off; off += b; return p;
  };
  int*       cnt     = (int*)alloc(64*4);
  long long* offs    = (long long*)alloc(16*8);
  int*       bsums   = (int*)alloc(256*4);
  ull*       sel     = (ull*)alloc(2*8);
  int*       hist    = (int*)alloc((size_t)HBINS*4);
  int*       partial = (int*)alloc(2048*4);
  int*       partial2= (int*)alloc(2304*4);
  double*    xls     = (double*)alloc((size_t)NN0*8);
  double*    xrs     = (double*)alloc((size_t)NN0*8);
  double*    score   = (double*)alloc((size_t)NN0*8);
  ull*       ek      = (ull*)alloc((size_t)NN0*8);
  float*     loopatF = (float*)alloc((size_t)NN0*12);
  int*       rank    = (int*)alloc((size_t)NN0*4);
  int*       perm    = (int*)alloc((size_t)NN0*4);
  int*       cursor  = (int*)alloc((size_t)NN0*4);
  int*       ccnt    = (int*)alloc((size_t)NN0*4);
  int*       dstarts = (int*)alloc((size_t)(NN0+1)*4);
  int*       eord    = (int*)alloc((size_t)EE0*4);
  int*       insrc   = (int*)alloc((size_t)EE0*4);
  int*       flags   = (int*)alloc((size_t)EE0*4);
  int*       scanout = (int*)alloc((size_t)(EE0+1)*4);
  int*       eb0s    = (int*)alloc((size_t)EE0*4);
  int*       eb0d    = (int*)alloc((size_t)EE0*4);
  int*       eb1s    = (int*)alloc((size_t)EE0*4);
  int*       eb1d    = (int*)alloc((size_t)EE0*4);
  float*     pos1    = (float*)alloc((size_t)KK1*12);
  float*     pos2    = (float*)alloc((size_t)KK2*12);
  float*     A       = (float*)alloc((size_t)NN0*128*4);
  float*     B       = (float*)alloc((size_t)NN0*128*4);
  float*     h       = (float*)alloc((size_t)NN0*128*4);
  void*      uni     = alloc((size_t)(EE0+FLATMAX)*8);   // union: zbF (conv) / binstarts+mkeys+midx (ranking)
  if(off > ws_size) return;

  float*  zbF      = (float*)uni;
  int*    binstarts= (int*)uni;                          // HBINS+1 ints
  ull*    mkeys    = (ull*)((int*)uni + (HBINS + 256));  // up to NN0 ulls, 8B-aligned
  int*    midx     = (int*)(mkeys + NN0);                // up to NN0 ints
  ull*    selT  = sel;
  int*    selRB = (int*)(sel+1);

  hipMemsetAsync(cnt, 0, 64*4, stream);

  auto scan = [&](const int* in, int* sout, const int* pN, int Ns, int* total){
    int nb = CDIV(Ns+1, SCH);
    scan_p1<<<nb,256,0,stream>>>(in,pN,Ns,bsums);
    scan_p2<<<1,256,0,stream>>>(bsums,nb);
    scan_p3<<<nb,256,0,stream>>>(in,sout,pN,Ns,bsums,total);
  };

  auto build_csr_dst = [&](const int* es, const int* ed, const int* pE, int Emax, int N, const float* pcur){
    hipMemsetAsync(ccnt,0,(size_t)N*4,stream);
    count_src<<<CDIV(Emax,256),256,0,stream>>>(ed,pE,Emax,ccnt);
    scan(ccnt,dstarts,nullptr,N,nullptr);
    hipMemsetAsync(cursor,0,(size_t)N*4,stream);
    fill_eord<<<CDIV(Emax,256),256,0,stream>>>(es,ed,pE,Emax,dstarts,cursor,eord,insrc);
    loop_csr_f<<<CDIV(N,256),256,0,stream>>>(insrc,dstarts,pcur,loopatF,N);
  };

  auto feat_conv = [&](const float* Wl, const float* Wr, const float* We, const float* att, const float* bias,
                       const int* es, const int* ed, const int* pE, int Emax, int N, const float* pcur,
                       bool conv0mode){
    if(conv0mode)
      gemm_k<0,true><<<CDIV(N,32),256,0,stream>>>(x,pcur,yv,Wl,Wr,nullptr,A,B,N);
    else
      gemm_k<1,true><<<CDIV(N,32),256,0,stream>>>(h,pcur,nullptr,Wl,Wr,nullptr,A,B,N);
    long long wt = (long long)(Emax+N)*64;
    feat_logits<<<(int)CDIV(wt,256),256,0,stream>>>(es,ed,pE,Emax,N,A,B,pcur,We,att,loopatF,zbF);
    feat_acc_csr<<<CDIV(N*64,256),256,0,stream>>>(insrc,eord,dstarts,pE,Emax,A,zbF,bias,h,N);
  };

  auto pool = [&](int l, int N, int k, const int* es, const int* ed, const int* pE, int Emax,
                  const float* pcur, float* pnext, int* ns, int* nd, int eslot){
    // fused score GATv2 (fp64): candidates enumerated on-the-fly from dst-CSR (in ∪ in∘in)
    gemm_score<<<CDIV(N,8),256,0,stream>>>(h,pcur,pWl+l*131,pWr+l*131,xls,xrs,N);
    score_fused2<<<N,64,0,stream>>>(insrc,dstarts,pcur,xls,xrs,pWe+l*3,pa+l,pb+l,score,N);
    // top-k: 2-round refine select (bits 63..43, then 42..22)
    enc_scores<<<CDIV(N,256),256,0,stream>>>(score,N,ek,rank);
    hipMemsetAsync(sel,0,16,stream);
    for(int r=0;r<2;r++){
      int sh = 43 - 21*r;
      hipMemsetAsync(hist,0,(size_t)HBINS*4,stream);
      hist_g<<<CDIV(N,256),256,0,stream>>>(ek,N,sh,selT,hist);
      part21<<<2048,256,0,stream>>>(hist,partial);
      findbin_g<<<1,256,0,stream>>>(partial,hist,selT,selRB,k,sh);
    }
    // bucketed exact ranking of candidates (inline-key streaming within bucket)
    hipMemsetAsync(hist,0,(size_t)HBINS*4,stream);
    rank_hist  <<<CDIV(N,256),256,0,stream>>>(ek,N,selT,hist);
    part21     <<<2048,256,0,stream>>>(hist,partial);
    scan(partial,partial2,nullptr,2048,nullptr);
    binscan    <<<2048,256,0,stream>>>(hist,partial2,binstarts);
    rank_fill  <<<CDIV(N,256),256,0,stream>>>(ek,N,selT,binstarts,hist,mkeys,midx);
    rank_within<<<CDIV(N,256),256,0,stream>>>(binstarts,mkeys,midx,rank,N);
    scatter_perm<<<CDIV(N,256),256,0,stream>>>(rank,N,k,perm);
    pool_gather<<<CDIV(k*32,256),256,0,stream>>>(h,score,perm,k,A);
    hipMemcpyAsync(h,A,(size_t)k*128*4,hipMemcpyDeviceToDevice,stream);
    pos_gather<<<CDIV(k*3,256),256,0,stream>>>(pcur,perm,k,pnext);
    filter_flags<<<CDIV(Emax,256),256,0,stream>>>(es,ed,pE,Emax,rank,k,flags);
    scan(flags,scanout,pE,Emax,cnt+eslot);
    filter_write<<<CDIV(Emax,256),256,0,stream>>>(es,ed,pE,Emax,rank,k,scanout,ns,nd);
  };

  // ================= pipeline =================
  build_csr_dst(eisrc,eidst,nullptr,EE0, NN0, pos0);
  feat_conv(Wl0,Wr0,We0,a0,b0, eisrc,eidst,nullptr,EE0, NN0, pos0, true);
  feat_conv(Wls+0*16768,Wrs+0*16768,Wes+0*384,atts+0*128,bs+0*128, eisrc,eidst,nullptr,EE0, NN0, pos0, false);
  pool(0, NN0, KK1, eisrc,eidst,nullptr,EE0, pos0,pos1, eb0s,eb0d, C_E1);
  build_csr_dst(eb0s,eb0d,cnt+C_E1,EE0, KK1, pos1);
  feat_conv(Wls+1*16768,Wrs+1*16768,Wes+1*384,atts+1*128,bs+1*128, eb0s,eb0d,cnt+C_E1,EE0, KK1, pos1, false);
  pool(1, KK1, KK2, eb0s,eb0d,cnt+C_E1,EE0, pos1,pos2, eb1s,eb1d, C_E2);
  build_csr_dst(eb1s,eb1d,cnt+C_E2,EE0, KK2, pos2);
  feat_conv(Wls+2*16768,Wrs+2*16768,Wes+2*384,atts+2*128,bs+2*128, eb1s,eb1d,cnt+C_E2,EE0, KK2, pos2, false);
  feat_conv(Wls+3*16768,Wrs+3*16768,Wes+3*384,atts+3*128,bs+3*128, eb1s,eb1d,cnt+C_E2,EE0, KK2, pos2, false);
  gemm_k<2,false><<<CDIV(KK2,32),256,0,stream>>>(h,nullptr,nullptr,linW,nullptr,linb,out,nullptr,KK2);

  calc_offsets<<<1,32,0,stream>>>(cnt,offs);
  emit_pe <<<CDIV(EE0,256),256,0,stream>>>(eb1s,eb1d,cnt+C_E2,EE0,offs,1,out);
  emit_pe <<<CDIV(EE0,256),256,0,stream>>>(eb0s,eb0d,cnt+C_E1,EE0,offs,2,out);
  emit_pe <<<CDIV(EE0,256),256,0,stream>>>(eisrc,eidst,nullptr,EE0,offs,3,out);
  emit_pp <<<CDIV(KK2*3,256),256,0,stream>>>(pos2,KK2*3,offs,4,out);
  emit_pp <<<CDIV(KK1*3,256),256,0,stream>>>(pos1,KK1*3,offs,5,out);
  emit_pp <<<CDIV(NN0*3,256),256,0,stream>>>(pos0,NN0*3,offs,6,out);
  emit_eas<<<CDIV(EE0,256),256,0,stream>>>(eb1s,eb1d,cnt+C_E2,EE0,pos2,offs,7,out);
  emit_eas<<<CDIV(EE0,256),256,0,stream>>>(eb0s,eb0d,cnt+C_E1,EE0,pos1,offs,8,out);
  emit_eas<<<CDIV(EE0,256),256,0,stream>>>(eisrc,eidst,nullptr,EE0,pos0,offs,9,out);
}

// Round 8
// 2115.286 us; speedup vs baseline: 1.0308x; 1.0308x over previous
//
#include <hip/hip_runtime.h>

typedef unsigned long long ull;

#define NN0 80000
#define EE0 480000
#define KK1 40000
#define KK2 20000
#define FLATMAX 8000000
#define SCH 4096
#define CDIV(a,b) (((a)+(b)-1)/(b))
#define HBINS (1<<21)
#define LSW 1024

// counter slots
#define C_E1 2
#define C_E2 3
#define C_M0 5
#define C_M1 6

__device__ __forceinline__ int getE(const int* p, int s){ if(!p) return s; int e=*p; return e<s? e : s; }
__device__ __forceinline__ float leakyf(float x){ return x>0.f? x : 0.2f*x; }
__device__ __forceinline__ double leakyd(double x){ return x>0.0? x : 0.2*x; }
__device__ __forceinline__ float eluf(float x){ return x>0.f? x : (expf(x)-1.f); }

__device__ __forceinline__ ull encd(double f){ ull u=(ull)__double_as_longlong(f); return (u>>63)? ~u : (u|0x8000000000000000ULL); }

// ---------------- GEMM: xl/xr projections ----------------
// 32 rows per block; input tile staged in LDS; each thread owns a 4row x 4col (x dual) register tile.
template<int MODE, bool DUAL>
__global__ void gemm_k(const float* __restrict__ F1, const float* __restrict__ pos,
                       const float* __restrict__ yv,
                       const float* __restrict__ W1, const float* __restrict__ W2,
                       const float* __restrict__ bias,
                       float* __restrict__ O1, float* __restrict__ O2, int N)
{
  const int K = MODE==0? 11 : (MODE==1? 131 : 128);
  __shared__ float lf[32][132];   // stride 132: float4-aligned rows, broadcast reads
  int t = threadIdx.x;
  int row0 = blockIdx.x*32;

  // ---- stage 32-row input tile into LDS (coalesced) ----
  if(MODE==0){
    for(int i=t;i<32*11;i+=256){
      int r=i/11, k=i-r*11; int row=row0+r;
      float f=0.f;
      if(row<N) f = (k<5)? F1[(size_t)row*5+k] : (k<8? pos[(size_t)row*3+(k-5)] : yv[0]);
      lf[r][k]=f;
    }
  } else {
    for(int i=t;i<32*32;i+=256){
      int r=i>>5, c4=i&31; int row=row0+r;
      float4 v; v.x=0.f;v.y=0.f;v.z=0.f;v.w=0.f;
      if(row<N) v = *(const float4*)(F1+(size_t)row*128+c4*4);
      *(float4*)(&lf[r][c4*4]) = v;
    }
    if(MODE==1){
      for(int i=t;i<32*3;i+=256){
        int r=i/3, d=i-r*3; int row=row0+r;
        lf[r][128+d] = (row<N)? pos[(size_t)row*3+d] : 0.f;
      }
    }
  }
  __syncthreads();

  int cg = t&31, rg = t>>5;      // 32 col-groups x 8 row-groups
  int g = cg*4;
  int rbase = rg*4;

  float acc1[4][4]; float acc2[4][4];
  #pragma unroll
  for(int rr=0;rr<4;rr++)
    #pragma unroll
    for(int c=0;c<4;c++){ acc1[rr][c]=0.f; acc2[rr][c]=0.f; }

  #pragma unroll 4
  for(int k=0;k<K;k++){
    float4 w = *(const float4*)(W1 + (size_t)k*128 + g);
    float4 v; v.x=0.f;v.y=0.f;v.z=0.f;v.w=0.f;
    if(DUAL) v = *(const float4*)(W2 + (size_t)k*128 + g);
    #pragma unroll
    for(int rr=0;rr<4;rr++){
      float f = lf[rbase+rr][k];
      acc1[rr][0]+=f*w.x; acc1[rr][1]+=f*w.y; acc1[rr][2]+=f*w.z; acc1[rr][3]+=f*w.w;
      if(DUAL){ acc2[rr][0]+=f*v.x; acc2[rr][1]+=f*v.y; acc2[rr][2]+=f*v.z; acc2[rr][3]+=f*v.w; }
    }
  }

  float4 bb; bb.x=0.f;bb.y=0.f;bb.z=0.f;bb.w=0.f;
  if(bias) bb = *(const float4*)(bias+g);
  #pragma unroll
  for(int rr=0;rr<4;rr++){
    int row = row0 + rbase + rr;
    if(row<N){
      float4 r1; r1.x=acc1[rr][0]+bb.x; r1.y=acc1[rr][1]+bb.y; r1.z=acc1[rr][2]+bb.z; r1.w=acc1[rr][3]+bb.w;
      *(float4*)(O1+(size_t)row*128+g) = r1;
      if(DUAL){
        float4 r2; r2.x=acc2[rr][0]; r2.y=acc2[rr][1]; r2.z=acc2[rr][2]; r2.w=acc2[rr][3];
        *(float4*)(O2+(size_t)row*128+g) = r2;
      }
    }
  }
}

// ---------------- multi-block exclusive scan ----------------
__global__ void scan_p1(const int* __restrict__ in, const int* pN, int Ns, int* __restrict__ bsums){
  __shared__ int red[256];
  int n = getE(pN,Ns);
  int base = blockIdx.x*SCH;
  int s=0;
  for(int i=base+threadIdx.x; i<base+SCH; i+=256) if(i<n) s+=in[i];
  red[threadIdx.x]=s; __syncthreads();
  for(int o=128;o;o>>=1){ if(threadIdx.x<(unsigned)o) red[threadIdx.x]+=red[threadIdx.x+o]; __syncthreads(); }
  if(threadIdx.x==0) bsums[blockIdx.x]=red[0];
}
__global__ void scan_p2(int* bsums, int nb){
  __shared__ int lds[256];
  int t=threadIdx.x;
  int v = (t<nb)? bsums[t] : 0;
  lds[t]=v; __syncthreads();
  for(int o=1;o<256;o<<=1){ int u=0; if(t>=o) u=lds[t-o]; __syncthreads(); lds[t]+=u; __syncthreads(); }
  if(t<nb) bsums[t]=lds[t]-v;
}
__global__ void scan_p3(const int* __restrict__ in, int* __restrict__ out, const int* pN, int Ns,
                        const int* __restrict__ bsums, int* total){
  __shared__ int tsum[256];
  int n = getE(pN,Ns);
  int base = blockIdx.x*SCH + threadIdx.x*16;
  int v[16]; int s=0;
  #pragma unroll
  for(int q=0;q<16;q++){ int i=base+q; int xv=(i<n)? in[i]:0; v[q]=s; s+=xv; }
  tsum[threadIdx.x]=s; __syncthreads();
  int mine=s;
  for(int o=1;o<256;o<<=1){ int u=0; if(threadIdx.x>=(unsigned)o) u=tsum[threadIdx.x-o]; __syncthreads(); tsum[threadIdx.x]+=u; __syncthreads(); }
  int pre = bsums[blockIdx.x] + tsum[threadIdx.x] - mine;
  #pragma unroll
  for(int q=0;q<16;q++){
    int i=base+q;
    if(i<=n){
      int val = pre+v[q];
      out[i]=val;
      if(i==n && total) *total=val;
    }
  }
}

// ---------------- CSR builders ----------------
__global__ void count_src(const int* __restrict__ es, const int* pE, int Es, int* cnts){
  int e = blockIdx.x*256+threadIdx.x; int E = getE(pE,Es); if(e>=E) return;
  atomicAdd(&cnts[es[e]], 1);
}
// dst-CSR: eord = edge id ordered by dst; insrc = source node ordered by dst
__global__ void fill_eord(const int* __restrict__ es, const int* __restrict__ ed, const int* pE, int Es,
                          const int* __restrict__ dstarts, int* cursor, int* eord, int* insrc){
  int e = blockIdx.x*256+threadIdx.x; int E = getE(pE,Es); if(e>=E) return;
  int d = ed[e];
  int p = dstarts[d] + atomicAdd(&cursor[d],1);
  eord[p] = e;
  insrc[p] = es[e];
}
__global__ void loop_csr_f(const int* __restrict__ insrc,
                           const int* __restrict__ dstarts, const float* __restrict__ pos,
                           float* __restrict__ loopat, int N)
{
  int d = blockIdx.x*256+threadIdx.x; if(d>=N) return;
  int r0=dstarts[d], r1=dstarts[d+1];
  float pd0=pos[d*3], pd1=pos[d*3+1], pd2=pos[d*3+2];
  float l0=0,l1=0,l2=0;
  for(int j=r0;j<r1;j++){
    int s = insrc[j];
    l0 += pd0-pos[s*3]; l1 += pd1-pos[s*3+1]; l2 += pd2-pos[s*3+2];
  }
  float inv = 1.f/fmaxf((float)(r1-r0), 1.f);
  loopat[d*3+0]=l0*inv; loopat[d*3+1]=l1*inv; loopat[d*3+2]=l2*inv;
}

// ---------------- feature GATv2 (fp32) ----------------
__global__ void feat_logits(const int* __restrict__ es, const int* __restrict__ ed, const int* pE, int Es, int N,
    const float* __restrict__ A, const float* __restrict__ B, const float* __restrict__ pos,
    const float* __restrict__ We, const float* __restrict__ att, const float* __restrict__ loopat,
    float* __restrict__ zb)
{
  int gid = blockIdx.x*blockDim.x + threadIdx.x;
  int w = gid>>6, lane = gid&63;
  int E = getE(pE,Es);
  if(w >= E+N) return;
  int s,d; float e0,e1,e2;
  if(w<E){ s=es[w]; d=ed[w]; e0=pos[d*3]-pos[s*3]; e1=pos[d*3+1]-pos[s*3+1]; e2=pos[d*3+2]-pos[s*3+2]; }
  else   { int n=w-E; s=n; d=n; e0=loopat[n*3]; e1=loopat[n*3+1]; e2=loopat[n*3+2]; }
  int c=lane, c2=lane+64;
  float m1 = A[(size_t)s*128+c ] + B[(size_t)d*128+c ] + e0*We[c ] + e1*We[128+c ] + e2*We[256+c ];
  float m2 = A[(size_t)s*128+c2] + B[(size_t)d*128+c2] + e0*We[c2] + e1*We[128+c2] + e2*We[256+c2];
  float p = leakyf(m1)*att[c] + leakyf(m2)*att[c2];
  for(int off=32; off; off>>=1) p += __shfl_down(p, off, 64);
  if(lane==0) zb[w]=p;
}

__global__ void feat_acc_csr(const int* __restrict__ insrc, const int* __restrict__ eord,
                             const int* __restrict__ dstarts, const int* pE, int Es,
                             const float* __restrict__ A, const float* __restrict__ zb,
                             const float* __restrict__ bias, float* __restrict__ h, int N)
{
  int w = (blockIdx.x*256+threadIdx.x)>>6;
  int lane = threadIdx.x&63;
  if(w>=N) return;
  int E = getE(pE,Es);
  int r0=dstarts[w], r1=dstarts[w+1];
  float mx = zb[E+w];
  for(int j=r0+lane; j<r1; j+=64) mx = fmaxf(mx, zb[eord[j]]);
  for(int o=32;o;o>>=1) mx = fmaxf(mx, __shfl_down(mx,o,64));
  mx = __shfl(mx, 0, 64);
  float denom = 0.f;
  float2 acc; acc.x=0.f; acc.y=0.f;
  for(int j=r0;j<r1;j++){
    int e = eord[j]; int s = insrc[j];
    float z = expf(zb[e]-mx);
    denom += z;
    float2 v = *(const float2*)(A + (size_t)s*128 + lane*2);
    acc.x += z*v.x; acc.y += z*v.y;
  }
  {
    float z = expf(zb[E+w]-mx);
    denom += z;
    float2 v = *(const float2*)(A + (size_t)w*128 + lane*2);
    acc.x += z*v.x; acc.y += z*v.y;
  }
  float inv = 1.f/denom;
  float2 bb = *(const float2*)(bias + lane*2);
  acc.x = eluf(acc.x*inv + bb.x); acc.y = eluf(acc.y*inv + bb.y);
  *(float2*)(h + (size_t)w*128 + lane*2) = acc;
}

// ---------------- score GATv2 (fp64) ----------------
// warp-cooperative: 32 lanes per node, coalesced reads of h, shfl-reduce.
__global__ void gemm_score(const float* __restrict__ h, const float* __restrict__ pos,
                           const float* __restrict__ pWl, const float* __restrict__ pWr,
                           double* __restrict__ xls, double* __restrict__ xrs, int N)
{
  int t = threadIdx.x;
  int lane = t&31;
  int n = blockIdx.x*8 + (t>>5);
  if(n>=N) return;
  double sl=0, sr=0;
  #pragma unroll
  for(int q=0;q<4;q++){
    int k = lane + q*32;
    double f = (double)h[(size_t)n*128+k];
    sl += f*(double)pWl[k]; sr += f*(double)pWr[k];
  }
  if(lane<3){
    double f = (double)pos[n*3+lane];
    sl += f*(double)pWl[128+lane]; sr += f*(double)pWr[128+lane];
  }
  for(int o=16;o;o>>=1){ sl += __shfl_down(sl,o,32); sr += __shfl_down(sr,o,32); }
  if(lane==0){ xls[n]=sl; xrs[n]=sr; }
}

// fused score GATv2 with ON-THE-FLY candidate enumeration from the dst-CSR:
// cand(w) = in(w) ∪ in(in(w)); ONE NODE PER WAVE, 4 waves per block
// (16KB LDS/block -> 8 blocks x 4 waves = 32 waves/CU = full occupancy).
__global__ void score_fused2(const int* __restrict__ insrc, const int* __restrict__ dstarts,
                             const float* __restrict__ pos,
                             const double* __restrict__ xls, const double* __restrict__ xrs,
                             const float* __restrict__ pWe, const float* __restrict__ paP,
                             const float* __restrict__ pbP,
                             double* __restrict__ score, int N)
{
  __shared__ int lsAll[4][LSW];
  int wv = threadIdx.x>>6;
  int lane = threadIdx.x&63;
  int w = blockIdx.x*4 + wv;
  bool active = (w<N);
  if(!active) w = N-1;           // clamp: safe reads, no writes
  int* ls = lsAll[wv];
  int r0=dstarts[w], r1=dstarts[w+1]; int din=r1-r0;
  // phase 1: 1-hop candidates
  for(int j=lane;j<din && j<LSW;j+=64) ls[j]=insrc[r0+j];
  __syncthreads();
  // phase 2 (lane-parallel): lane handles in-neighbor (base+lane); exclusive scan of lens -> offsets
  int off = din<LSW? din : LSW;
  for(int base=0; base<din && base<LSW; base+=64){
    int t = base + lane;
    int u0=0, len=0;
    if(t<din && t<LSW){
      int u = ls[t];
      u0 = dstarts[u]; len = dstarts[u+1]-u0;
    }
    int pre = len;
    #pragma unroll
    for(int o=1;o<64;o<<=1){ int v=__shfl_up(pre,o,64); if(lane>=o) pre+=v; }
    int tot = __shfl(pre, 63, 64);
    int myoff = off + pre - len;
    for(int j=0;j<len;j++){ int p=myoff+j; if(p<LSW) ls[p]=insrc[u0+j]; }
    off += tot;
  }
  int d = off<LSW? off : LSW;
  __syncthreads();

  float pd0=pos[w*3], pd1=pos[w*3+1], pd2=pos[w*3+2];
  double w0=(double)pWe[0], w1=(double)pWe[1], w2=(double)pWe[2], pa=(double)paP[0];
  double xrd=xrs[w];
  ull umask=0;
  double mx=-1e300, s0=0,s1=0,s2=0; int ucnt=0;
  int nb=0;
  for(int j=lane; j<d; j+=64, nb++){
    int s = ls[j];
    bool uniq = true;
    for(int q=0;q<j;q++) if(ls[q]==s){ uniq=false; break; }
    if(uniq){
      umask |= 1ULL<<nb;
      ucnt++;
      double e0=(double)(pd0-pos[s*3]), e1=(double)(pd1-pos[s*3+1]), e2=(double)(pd2-pos[s*3+2]);
      s0+=e0; s1+=e1; s2+=e2;
      double lg = leakyd(xls[s]+xrd + e0*w0+e1*w1+e2*w2) * pa;
      mx = fmax(mx, lg);
    }
  }
  for(int o=32;o;o>>=1){
    mx = fmax(mx, __shfl_down(mx,o,64));
    s0 += __shfl_down(s0,o,64);
    s1 += __shfl_down(s1,o,64);
    s2 += __shfl_down(s2,o,64);
    ucnt += __shfl_down(ucnt,o,64);
  }
  mx=__shfl(mx,0,64); s0=__shfl(s0,0,64); s1=__shfl(s1,0,64); s2=__shfl(s2,0,64); ucnt=__shfl(ucnt,0,64);
  double invd = 1.0/(double)(ucnt>0? ucnt : 1);
  double lg_self = leakyd(xls[w]+xrd + (s0*invd)*w0 + (s1*invd)*w1 + (s2*invd)*w2) * pa;
  mx = fmax(mx, lg_self);
  double den=0, acc=0;
  nb=0;
  for(int j=lane; j<d; j+=64, nb++){
    if((umask>>nb)&1ULL){
      int s = ls[j];
      double e0=(double)(pd0-pos[s*3]), e1=(double)(pd1-pos[s*3+1]), e2=(double)(pd2-pos[s*3+2]);
      double lg = leakyd(xls[s]+xrd + e0*w0+e1*w1+e2*w2) * pa;
      double z = exp(lg-mx);
      den += z; acc += z*xls[s];
    }
  }
  for(int o=32;o;o>>=1){
    den += __shfl_down(den,o,64);
    acc += __shfl_down(acc,o,64);
  }
  if(lane==0 && active){
    double z = exp(lg_self-mx);
    den += z; acc += z*xls[w];
    score[w] = tanh(acc/den + (double)pbP[0]);
  }
}

// ---------------- top-k: 2-round 21-bit refine select + bucketed ranking ----------------
__global__ void enc_scores(const double* __restrict__ score, int N, ull* __restrict__ ek,
                           int* __restrict__ rank){
  int i = blockIdx.x*256+threadIdx.x; if(i>=N) return;
  ek[i] = encd(score[i]);
  rank[i] = 0x3f3f3f3f;
}
// histogram of 21-bit digit at `shift`, restricted to keys whose bits above shift+21 match selT
__global__ void hist_g(const ull* __restrict__ ek, int N, int shift, const ull* __restrict__ selT,
                       int* __restrict__ hist){
  int i = blockIdx.x*256+threadIdx.x; if(i>=N) return;
  ull key = ek[i];
  if(shift+21 < 64){
    if((key >> (shift+21)) != ((*selT) >> (shift+21))) return;
  }
  atomicAdd(&hist[(int)((key>>shift)&0x1FFFFF)], 1);
}
__global__ void part21(const int* __restrict__ hist, int* __restrict__ partial){
  __shared__ int red[256];
  int b = blockIdx.x;
  int s=0;
  for(int i=threadIdx.x;i<1024;i+=256) s += hist[b*1024+i];
  red[threadIdx.x]=s; __syncthreads();
  for(int o=128;o;o>>=1){ if(threadIdx.x<(unsigned)o) red[threadIdx.x]+=red[threadIdx.x+o]; __syncthreads(); }
  if(threadIdx.x==0) partial[b]=red[0];
}
// find the bin containing the keff-th largest key; update selT (bin at `shift`) and selRB (count strictly above)
__global__ void findbin_g(const int* __restrict__ partial, const int* __restrict__ hist,
                          ull* __restrict__ selT, int* __restrict__ selRB, int k, int shift){
  __shared__ int ts[256];
  __shared__ int cstar, rbase;
  int t=threadIdx.x;
  int keff = k - *selRB;
  int s8[8]; int mysum=0;
  #pragma unroll
  for(int q=0;q<8;q++){ s8[q]=partial[t*8+q]; mysum+=s8[q]; }
  ts[t]=mysum; __syncthreads();
  for(int o=1;o<256;o<<=1){ int u=(t+o<256)? ts[t+o]:0; __syncthreads(); ts[t]+=u; __syncthreads(); }
  int after = (t<255)? ts[t+1] : 0;
  if(ts[t] >= keff && after < keff){
    int run = after;
    for(int q=7;q>=0;q--){
      if(run < keff && run + s8[q] >= keff){ cstar = t*8+q; rbase = run; }
      run += s8[q];
    }
  }
  __syncthreads();
  int cs=cstar, rb=rbase;
  int b4[4]; int ms=0;
  #pragma unroll
  for(int q=0;q<4;q++){ b4[q]=hist[cs*1024 + t*4 + q]; ms+=b4[q]; }
  ts[t]=ms; __syncthreads();
  for(int o=1;o<256;o<<=1){ int u=(t+o<256)? ts[t+o]:0; __syncthreads(); ts[t]+=u; __syncthreads(); }
  int after2 = (t<255)? ts[t+1] : 0;
  if(rb+ts[t] >= keff && rb+after2 < keff){
    int run = rb+after2;
    for(int q=3;q>=0;q--){
      if(run < keff && run + b4[q] >= keff){
        *selT |= ((ull)(cs*1024 + t*4 + q)) << shift;
        *selRB = (k - keff) + run;
      }
      run += b4[q];
    }
  }
}
// ----- bucketed exact ranking of candidates (key >= selT) -----
// bucket digit = complemented top-21 bits => ascending bucket = descending key.
__global__ void rank_hist(const ull* __restrict__ ek, int N, const ull* __restrict__ selT,
                          int* __restrict__ hist){
  int i = blockIdx.x*256+threadIdx.x; if(i>=N) return;
  ull key = ek[i]; if(key < *selT) return;
  int dg = (int)((~key >> 43) & 0x1FFFFF);
  atomicAdd(&hist[dg], 1);
}
// per-1024-bin-block exclusive scan + global block offset -> binstarts; last thread writes total
__global__ void binscan(const int* __restrict__ hist, const int* __restrict__ p2,
                        int* __restrict__ binstarts){
  __shared__ int ts[256];
  int b = blockIdx.x, t = threadIdx.x;
  int v[4]; int s=0;
  #pragma unroll
  for(int q=0;q<4;q++){ v[q]=s; s+=hist[b*1024 + t*4 + q]; }
  ts[t]=s; __syncthreads();
  int mine=s;
  for(int o=1;o<256;o<<=1){ int u=0; if(t>=(unsigned)o) u=ts[t-o]; __syncthreads(); ts[t]+=u; __syncthreads(); }
  int pre = p2[b] + ts[t] - mine;
  #pragma unroll
  for(int q=0;q<4;q++) binstarts[b*1024 + t*4 + q] = pre + v[q];
  if(b==2047 && t==255) binstarts[HBINS] = p2[b] + ts[255];
}
// scatter candidate (key,idx) into bucket-ordered member arrays (consumes hist counts)
__global__ void rank_fill(const ull* __restrict__ ek, int N, const ull* __restrict__ selT,
                          const int* __restrict__ binstarts, int* __restrict__ hist,
                          ull* __restrict__ mkeys, int* __restrict__ midx){
  int i = blockIdx.x*256+threadIdx.x; if(i>=N) return;
  ull key = ek[i]; if(key < *selT) return;
  int dg = (int)((~key >> 43) & 0x1FFFFF);
  int o = atomicSub(&hist[dg], 1) - 1;
  int p = binstarts[dg] + o;
  mkeys[p] = key; midx[p] = i;
}
// exact rank: bucket start + same-bucket (key desc, idx asc) pairwise over STREAMED inline keys
__global__ void rank_within(const int* __restrict__ binstarts,
                            const ull* __restrict__ mkeys, const int* __restrict__ midx,
                            int* __restrict__ rank, int Nmax){
  int m = blockIdx.x*256+threadIdx.x; if(m>=Nmax) return;
  int total = binstarts[HBINS]; if(m>=total) return;
  ull key = mkeys[m]; int ii = midx[m];
  int dg = (int)((~key >> 43) & 0x1FFFFF);
  int s = binstarts[dg], e = binstarts[dg+1];
  int cnt = 0;
  for(int j=s;j<e;j++){
    ull kj = mkeys[j];
    cnt += (kj > key) || (kj == key && midx[j] < ii);
  }
  rank[ii] = s + cnt;
}
__global__ void scatter_perm(const int* __restrict__ rank, int N, int k, int* __restrict__ perm){
  int i = blockIdx.x*256+threadIdx.x; if(i>=N) return;
  int r = rank[i]; if(r<k) perm[r]=i;
}
__global__ void pool_gather(const float* __restrict__ h, const double* __restrict__ score,
                            const int* __restrict__ perm, int k, float* __restrict__ outA){
  int idx = blockIdx.x*256+threadIdx.x; if(idx>=k*32) return;
  int r = idx>>5, g = (idx&31)*4;
  int p = perm[r]; float sc = (float)score[p];
  const float4 x = *(const float4*)(h + (size_t)p*128 + g);
  float4 o; o.x=x.x*sc; o.y=x.y*sc; o.z=x.z*sc; o.w=x.w*sc;
  *(float4*)(outA + (size_t)r*128 + g) = o;
}
__global__ void pos_gather(const float* __restrict__ posc, const int* __restrict__ perm, int k, float* __restrict__ posn){
  int idx = blockIdx.x*256+threadIdx.x; if(idx>=k*3) return;
  int r = idx/3, j = idx-r*3;
  posn[idx] = posc[perm[r]*3+j];
}

// ---------------- filter_adj ----------------
__global__ void filter_flags(const int* __restrict__ es, const int* __restrict__ ed, const int* pE, int Es,
                             const int* __restrict__ rank, int k, int* __restrict__ flags){
  int e = blockIdx.x*256+threadIdx.x; int E = getE(pE,Es); if(e>=E) return;
  flags[e] = (rank[es[e]]<k && rank[ed[e]]<k) ? 1 : 0;
}
__global__ void filter_write(const int* __restrict__ es, const int* __restrict__ ed, const int* pE, int Es,
                             const int* __restrict__ rank, int k, const int* __restrict__ scanout,
                             int* __restrict__ ns, int* __restrict__ nd){
  int e = blockIdx.x*256+threadIdx.x; int E = getE(pE,Es); if(e>=E) return;
  int rs = rank[es[e]], rd = rank[ed[e]];
  if(rs<k && rd<k){ int p = scanout[e]; ns[p]=rs; nd[p]=rd; }
}

// ---------------- output emit ----------------
__global__ void calc_offsets(const int* __restrict__ cnt, long long* __restrict__ offs){
  if(blockIdx.x==0 && threadIdx.x==0){
    long long E1 = cnt[C_E1], E2 = cnt[C_E2];
    long long o = (long long)KK2*128;
    offs[0]=0;
    offs[1]=o; o += 2*E2;
    offs[2]=o; o += 2*E1;
    offs[3]=o; o += 2*(long long)EE0;
    offs[4]=o; o += (long long)KK2*3;
    offs[5]=o; o += (long long)KK1*3;
    offs[6]=o; o += (long long)NN0*3;
    offs[7]=o; o += 3*E2;
    offs[8]=o; o += 3*E1;
    offs[9]=o;
  }
}
__global__ void emit_pe(const int* __restrict__ s, const int* __restrict__ d, const int* pE, int Es,
                        const long long* __restrict__ offs, int oi, float* __restrict__ out){
  int e = blockIdx.x*256+threadIdx.x; int E = getE(pE,Es); if(e>=E) return;
  long long o = offs[oi];
  out[o+e]   = (float)s[e];
  out[o+E+e] = (float)d[e];
}
__global__ void emit_pp(const float* __restrict__ p, int n, const long long* __restrict__ offs, int oi, float* __restrict__ out){
  int i = blockIdx.x*256+threadIdx.x; if(i>=n) return;
  out[offs[oi]+i] = p[i];
}
__global__ void emit_eas(const int* __restrict__ s, const int* __restrict__ d, const int* pE, int Es,
                         const float* __restrict__ pos, const long long* __restrict__ offs, int oi, float* __restrict__ out){
  int e = blockIdx.x*256+threadIdx.x; int E = getE(pE,Es); if(e>=E) return;
  long long o = offs[oi];
  int ss=s[e], dd=d[e];
  out[o+3*e+0] = pos[dd*3+0]-pos[ss*3+0];
  out[o+3*e+1] = pos[dd*3+1]-pos[ss*3+1];
  out[o+3*e+2] = pos[dd*3+2]-pos[ss*3+2];
}

// =======================================================================
extern "C" void kernel_launch(void* const* d_in, const int* in_sizes, int n_in,
                              void* d_out, int out_size, void* d_ws, size_t ws_size,
                              hipStream_t stream)
{
  const float* x    = (const float*)d_in[0];
  const float* yv   = (const float*)d_in[1];
  const float* pos0 = (const float*)d_in[2];
  const int*   ei   = (const int*)d_in[3];
  const float* Wl0  = (const float*)d_in[4];
  const float* Wr0  = (const float*)d_in[5];
  const float* We0  = (const float*)d_in[6];
  const float* a0   = (const float*)d_in[7];
  const float* b0   = (const float*)d_in[8];
  const float* Wls  = (const float*)d_in[9];
  const float* Wrs  = (const float*)d_in[10];
  const float* Wes  = (const float*)d_in[11];
  const float* atts = (const float*)d_in[12];
  const float* bs   = (const float*)d_in[13];
  const float* pWl  = (const float*)d_in[14];
  const float* pWr  = (const float*)d_in[15];
  const float* pWe  = (const float*)d_in[16];
  const float* pa   = (const float*)d_in[17];
  const float* pb   = (const float*)d_in[18];
  const float* linW = (const float*)d_in[19];
  const float* linb = (const float*)d_in[20];
  float* out = (float*)d_out;

  const int* eisrc = ei;
  const int* eidst = ei + EE0;

  char* base = (char*)d_ws; size_t off = 0;
  auto alloc = [&](size_t b)->void*{
    off = (off + 255) & ~(size_t)255;
    void* p = base + off; off += b; return p;
  };
  int*       cnt     = (int*)alloc(64*4);
  long long* offs    = (long long*)alloc(16*8);
  int*       bsums   = (int*)alloc(256*4);
  ull*       sel     = (ull*)alloc(2*8);
  int*       hist    = (int*)alloc((size_t)HBINS*4);
  int*       partial = (int*)alloc(2048*4);
  int*       partial2= (int*)alloc(2304*4);
  double*    xls     = (double*)alloc((size_t)NN0*8);
  double*    xrs     = (double*)alloc((size_t)NN0*8);
  double*    score   = (double*)alloc((size_t)NN0*8);
  ull*       ek      = (ull*)alloc((size_t)NN0*8);
  float*     loopatF = (float*)alloc((size_t)NN0*12);
  int*       rank    = (int*)alloc((size_t)NN0*4);
  int*       perm    = (int*)alloc((size_t)NN0*4);
  int*       cursor  = (int*)alloc((size_t)NN0*4);
  int*       ccnt    = (int*)alloc((size_t)NN0*4);
  int*       dstarts = (int*)alloc((size_t)(NN0+1)*4);
  int*       eord    = (int*)alloc((size_t)EE0*4);
  int*       insrc   = (int*)alloc((size_t)EE0*4);
  int*       flags   = (int*)alloc((size_t)EE0*4);
  int*       scanout = (int*)alloc((size_t)(EE0+1)*4);
  int*       eb0s    = (int*)alloc((size_t)EE0*4);
  int*       eb0d    = (int*)alloc((size_t)EE0*4);
  int*       eb1s    = (int*)alloc((size_t)EE0*4);
  int*       eb1d    = (int*)alloc((size_t)EE0*4);
  float*     pos1    = (float*)alloc((size_t)KK1*12);
  float*     pos2    = (float*)alloc((size_t)KK2*12);
  float*     A       = (float*)alloc((size_t)NN0*128*4);
  float*     B       = (float*)alloc((size_t)NN0*128*4);
  float*     h       = (float*)alloc((size_t)NN0*128*4);
  void*      uni     = alloc((size_t)(EE0+FLATMAX)*8);   // union: zbF (conv) / binstarts+mkeys+midx (ranking)
  if(off > ws_size) return;

  float*  zbF      = (float*)uni;
  int*    binstarts= (int*)uni;                          // HBINS+1 ints
  ull*    mkeys    = (ull*)((int*)uni + (HBINS + 256));  // up to NN0 ulls, 8B-aligned
  int*    midx     = (int*)(mkeys + NN0);                // up to NN0 ints
  ull*    selT  = sel;
  int*    selRB = (int*)(sel+1);

  hipMemsetAsync(cnt, 0, 64*4, stream);

  auto scan = [&](const int* in, int* sout, const int* pN, int Ns, int* total){
    int nb = CDIV(Ns+1, SCH);
    scan_p1<<<nb,256,0,stream>>>(in,pN,Ns,bsums);
    scan_p2<<<1,256,0,stream>>>(bsums,nb);
    scan_p3<<<nb,256,0,stream>>>(in,sout,pN,Ns,bsums,total);
  };

  auto build_csr_dst = [&](const int* es, const int* ed, const int* pE, int Emax, int N, const float* pcur){
    hipMemsetAsync(ccnt,0,(size_t)N*4,stream);
    count_src<<<CDIV(Emax,256),256,0,stream>>>(ed,pE,Emax,ccnt);
    scan(ccnt,dstarts,nullptr,N,nullptr);
    hipMemsetAsync(cursor,0,(size_t)N*4,stream);
    fill_eord<<<CDIV(Emax,256),256,0,stream>>>(es,ed,pE,Emax,dstarts,cursor,eord,insrc);
    loop_csr_f<<<CDIV(N,256),256,0,stream>>>(insrc,dstarts,pcur,loopatF,N);
  };

  auto feat_conv = [&](const float* Wl, const float* Wr, const float* We, const float* att, const float* bias,
                       const int* es, const int* ed, const int* pE, int Emax, int N, const float* pcur,
                       bool conv0mode){
    if(conv0mode)
      gemm_k<0,true><<<CDIV(N,32),256,0,stream>>>(x,pcur,yv,Wl,Wr,nullptr,A,B,N);
    else
      gemm_k<1,true><<<CDIV(N,32),256,0,stream>>>(h,pcur,nullptr,Wl,Wr,nullptr,A,B,N);
    long long wt = (long long)(Emax+N)*64;
    feat_logits<<<(int)CDIV(wt,256),256,0,stream>>>(es,ed,pE,Emax,N,A,B,pcur,We,att,loopatF,zbF);
    feat_acc_csr<<<CDIV(N*64,256),256,0,stream>>>(insrc,eord,dstarts,pE,Emax,A,zbF,bias,h,N);
  };

  auto pool = [&](int l, int N, int k, const int* es, const int* ed, const int* pE, int Emax,
                  const float* pcur, float* pnext, int* ns, int* nd, int eslot){
    // fused score GATv2 (fp64): candidates enumerated on-the-fly from dst-CSR (in ∪ in∘in)
    gemm_score<<<CDIV(N,8),256,0,stream>>>(h,pcur,pWl+l*131,pWr+l*131,xls,xrs,N);
    score_fused2<<<CDIV(N,4),256,0,stream>>>(insrc,dstarts,pcur,xls,xrs,pWe+l*3,pa+l,pb+l,score,N);
    // top-k: 2-round refine select (bits 63..43, then 42..22)
    enc_scores<<<CDIV(N,256),256,0,stream>>>(score,N,ek,rank);
    hipMemsetAsync(sel,0,16,stream);
    for(int r=0;r<2;r++){
      int sh = 43 - 21*r;
      hipMemsetAsync(hist,0,(size_t)HBINS*4,stream);
      hist_g<<<CDIV(N,256),256,0,stream>>>(ek,N,sh,selT,hist);
      part21<<<2048,256,0,stream>>>(hist,partial);
      findbin_g<<<1,256,0,stream>>>(partial,hist,selT,selRB,k,sh);
    }
    // bucketed exact ranking of candidates (inline-key streaming within bucket)
    hipMemsetAsync(hist,0,(size_t)HBINS*4,stream);
    rank_hist  <<<CDIV(N,256),256,0,stream>>>(ek,N,selT,hist);
    part21     <<<2048,256,0,stream>>>(hist,partial);
    scan(partial,partial2,nullptr,2048,nullptr);
    binscan    <<<2048,256,0,stream>>>(hist,partial2,binstarts);
    rank_fill  <<<CDIV(N,256),256,0,stream>>>(ek,N,selT,binstarts,hist,mkeys,midx);
    rank_within<<<CDIV(N,256),256,0,stream>>>(binstarts,mkeys,midx,rank,N);
    scatter_perm<<<CDIV(N,256),256,0,stream>>>(rank,N,k,perm);
    pool_gather<<<CDIV(k*32,256),256,0,stream>>>(h,score,perm,k,A);
    hipMemcpyAsync(h,A,(size_t)k*128*4,hipMemcpyDeviceToDevice,stream);
    pos_gather<<<CDIV(k*3,256),256,0,stream>>>(pcur,perm,k,pnext);
    filter_flags<<<CDIV(Emax,256),256,0,stream>>>(es,ed,pE,Emax,rank,k,flags);
    scan(flags,scanout,pE,Emax,cnt+eslot);
    filter_write<<<CDIV(Emax,256),256,0,stream>>>(es,ed,pE,Emax,rank,k,scanout,ns,nd);
  };

  // ================= pipeline =================
  build_csr_dst(eisrc,eidst,nullptr,EE0, NN0, pos0);
  feat_conv(Wl0,Wr0,We0,a0,b0, eisrc,eidst,nullptr,EE0, NN0, pos0, true);
  feat_conv(Wls+0*16768,Wrs+0*16768,Wes+0*384,atts+0*128,bs+0*128, eisrc,eidst,nullptr,EE0, NN0, pos0, false);
  pool(0, NN0, KK1, eisrc,eidst,nullptr,EE0, pos0,pos1, eb0s,eb0d, C_E1);
  build_csr_dst(eb0s,eb0d,cnt+C_E1,EE0, KK1, pos1);
  feat_conv(Wls+1*16768,Wrs+1*16768,Wes+1*384,atts+1*128,bs+1*128, eb0s,eb0d,cnt+C_E1,EE0, KK1, pos1, false);
  pool(1, KK1, KK2, eb0s,eb0d,cnt+C_E1,EE0, pos1,pos2, eb1s,eb1d, C_E2);
  build_csr_dst(eb1s,eb1d,cnt+C_E2,EE0, KK2, pos2);
  feat_conv(Wls+2*16768,Wrs+2*16768,Wes+2*384,atts+2*128,bs+2*128, eb1s,eb1d,cnt+C_E2,EE0, KK2, pos2, false);
  feat_conv(Wls+3*16768,Wrs+3*16768,Wes+3*384,atts+3*128,bs+3*128, eb1s,eb1d,cnt+C_E2,EE0, KK2, pos2, false);
  gemm_k<2,false><<<CDIV(KK2,32),256,0,stream>>>(h,nullptr,nullptr,linW,nullptr,linb,out,nullptr,KK2);

  calc_offsets<<<1,32,0,stream>>>(cnt,offs);
  emit_pe <<<CDIV(EE0,256),256,0,stream>>>(eb1s,eb1d,cnt+C_E2,EE0,offs,1,out);
  emit_pe <<<CDIV(EE0,256),256,0,stream>>>(eb0s,eb0d,cnt+C_E1,EE0,offs,2,out);
  emit_pe <<<CDIV(EE0,256),256,0,stream>>>(eisrc,eidst,nullptr,EE0,offs,3,out);
  emit_pp <<<CDIV(KK2*3,256),256,0,stream>>>(pos2,KK2*3,offs,4,out);
  emit_pp <<<CDIV(KK1*3,256),256,0,stream>>>(pos1,KK1*3,offs,5,out);
  emit_pp <<<CDIV(NN0*3,256),256,0,stream>>>(pos0,NN0*3,offs,6,out);
  emit_eas<<<CDIV(EE0,256),256,0,stream>>>(eb1s,eb1d,cnt+C_E2,EE0,pos2,offs,7,out);
  emit_eas<<<CDIV(EE0,256),256,0,stream>>>(eb0s,eb0d,cnt+C_E1,EE0,pos1,offs,8,out);
  emit_eas<<<CDIV(EE0,256),256,0,stream>>>(eisrc,eidst,nullptr,EE0,pos0,offs,9,out);
}

// Round 9
// 2114.114 us; speedup vs baseline: 1.0313x; 1.0006x over previous
//
#include <hip/hip_runtime.h>

typedef unsigned long long ull;

#define NN0 80000
#define EE0 480000
#define KK1 40000
#define KK2 20000
#define FLATMAX 8000000
#define SCH 4096
#define CDIV(a,b) (((a)+(b)-1)/(b))
#define HBINS (1<<21)
#define LSW 1024

// counter slots
#define C_E1 2
#define C_E2 3
#define C_M0 5
#define C_M1 6

__device__ __forceinline__ int getE(const int* p, int s){ if(!p) return s; int e=*p; return e<s? e : s; }
__device__ __forceinline__ float leakyf(float x){ return x>0.f? x : 0.2f*x; }
__device__ __forceinline__ double leakyd(double x){ return x>0.0? x : 0.2*x; }
__device__ __forceinline__ float eluf(float x){ return x>0.f? x : (expf(x)-1.f); }

__device__ __forceinline__ ull encd(double f){ ull u=(ull)__double_as_longlong(f); return (u>>63)? ~u : (u|0x8000000000000000ULL); }

// ---------------- GEMM: xl/xr projections ----------------
// 32 rows per block; input tile staged in LDS; each thread owns a 4row x 4col (x dual) register tile.
template<int MODE, bool DUAL>
__global__ void gemm_k(const float* __restrict__ F1, const float* __restrict__ pos,
                       const float* __restrict__ yv,
                       const float* __restrict__ W1, const float* __restrict__ W2,
                       const float* __restrict__ bias,
                       float* __restrict__ O1, float* __restrict__ O2, int N)
{
  const int K = MODE==0? 11 : (MODE==1? 131 : 128);
  __shared__ float lf[32][132];   // stride 132: float4-aligned rows, broadcast reads
  int t = threadIdx.x;
  int row0 = blockIdx.x*32;

  // ---- stage 32-row input tile into LDS (coalesced) ----
  if(MODE==0){
    for(int i=t;i<32*11;i+=256){
      int r=i/11, k=i-r*11; int row=row0+r;
      float f=0.f;
      if(row<N) f = (k<5)? F1[(size_t)row*5+k] : (k<8? pos[(size_t)row*3+(k-5)] : yv[0]);
      lf[r][k]=f;
    }
  } else {
    for(int i=t;i<32*32;i+=256){
      int r=i>>5, c4=i&31; int row=row0+r;
      float4 v; v.x=0.f;v.y=0.f;v.z=0.f;v.w=0.f;
      if(row<N) v = *(const float4*)(F1+(size_t)row*128+c4*4);
      *(float4*)(&lf[r][c4*4]) = v;
    }
    if(MODE==1){
      for(int i=t;i<32*3;i+=256){
        int r=i/3, d=i-r*3; int row=row0+r;
        lf[r][128+d] = (row<N)? pos[(size_t)row*3+d] : 0.f;
      }
    }
  }
  __syncthreads();

  int cg = t&31, rg = t>>5;      // 32 col-groups x 8 row-groups
  int g = cg*4;
  int rbase = rg*4;

  float acc1[4][4]; float acc2[4][4];
  #pragma unroll
  for(int rr=0;rr<4;rr++)
    #pragma unroll
    for(int c=0;c<4;c++){ acc1[rr][c]=0.f; acc2[rr][c]=0.f; }

  #pragma unroll 4
  for(int k=0;k<K;k++){
    float4 w = *(const float4*)(W1 + (size_t)k*128 + g);
    float4 v; v.x=0.f;v.y=0.f;v.z=0.f;v.w=0.f;
    if(DUAL) v = *(const float4*)(W2 + (size_t)k*128 + g);
    #pragma unroll
    for(int rr=0;rr<4;rr++){
      float f = lf[rbase+rr][k];
      acc1[rr][0]+=f*w.x; acc1[rr][1]+=f*w.y; acc1[rr][2]+=f*w.z; acc1[rr][3]+=f*w.w;
      if(DUAL){ acc2[rr][0]+=f*v.x; acc2[rr][1]+=f*v.y; acc2[rr][2]+=f*v.z; acc2[rr][3]+=f*v.w; }
    }
  }

  float4 bb; bb.x=0.f;bb.y=0.f;bb.z=0.f;bb.w=0.f;
  if(bias) bb = *(const float4*)(bias+g);
  #pragma unroll
  for(int rr=0;rr<4;rr++){
    int row = row0 + rbase + rr;
    if(row<N){
      float4 r1; r1.x=acc1[rr][0]+bb.x; r1.y=acc1[rr][1]+bb.y; r1.z=acc1[rr][2]+bb.z; r1.w=acc1[rr][3]+bb.w;
      *(float4*)(O1+(size_t)row*128+g) = r1;
      if(DUAL){
        float4 r2; r2.x=acc2[rr][0]; r2.y=acc2[rr][1]; r2.z=acc2[rr][2]; r2.w=acc2[rr][3];
        *(float4*)(O2+(size_t)row*128+g) = r2;
      }
    }
  }
}

// ---------------- multi-block exclusive scan ----------------
__global__ void scan_p1(const int* __restrict__ in, const int* pN, int Ns, int* __restrict__ bsums){
  __shared__ int red[256];
  int n = getE(pN,Ns);
  int base = blockIdx.x*SCH;
  int s=0;
  for(int i=base+threadIdx.x; i<base+SCH; i+=256) if(i<n) s+=in[i];
  red[threadIdx.x]=s; __syncthreads();
  for(int o=128;o;o>>=1){ if(threadIdx.x<(unsigned)o) red[threadIdx.x]+=red[threadIdx.x+o]; __syncthreads(); }
  if(threadIdx.x==0) bsums[blockIdx.x]=red[0];
}
__global__ void scan_p2(int* bsums, int nb){
  __shared__ int lds[256];
  int t=threadIdx.x;
  int v = (t<nb)? bsums[t] : 0;
  lds[t]=v; __syncthreads();
  for(int o=1;o<256;o<<=1){ int u=0; if(t>=o) u=lds[t-o]; __syncthreads(); lds[t]+=u; __syncthreads(); }
  if(t<nb) bsums[t]=lds[t]-v;
}
__global__ void scan_p3(const int* __restrict__ in, int* __restrict__ out, const int* pN, int Ns,
                        const int* __restrict__ bsums, int* total){
  __shared__ int tsum[256];
  int n = getE(pN,Ns);
  int base = blockIdx.x*SCH + threadIdx.x*16;
  int v[16]; int s=0;
  #pragma unroll
  for(int q=0;q<16;q++){ int i=base+q; int xv=(i<n)? in[i]:0; v[q]=s; s+=xv; }
  tsum[threadIdx.x]=s; __syncthreads();
  int mine=s;
  for(int o=1;o<256;o<<=1){ int u=0; if(threadIdx.x>=(unsigned)o) u=tsum[threadIdx.x-o]; __syncthreads(); tsum[threadIdx.x]+=u; __syncthreads(); }
  int pre = bsums[blockIdx.x] + tsum[threadIdx.x] - mine;
  #pragma unroll
  for(int q=0;q<16;q++){
    int i=base+q;
    if(i<=n){
      int val = pre+v[q];
      out[i]=val;
      if(i==n && total) *total=val;
    }
  }
}

// ---------------- CSR builders ----------------
__global__ void count_src(const int* __restrict__ es, const int* pE, int Es, int* cnts){
  int e = blockIdx.x*256+threadIdx.x; int E = getE(pE,Es); if(e>=E) return;
  atomicAdd(&cnts[es[e]], 1);
}
// dst-CSR: eord = edge id ordered by dst; insrc = source node ordered by dst
__global__ void fill_eord(const int* __restrict__ es, const int* __restrict__ ed, const int* pE, int Es,
                          const int* __restrict__ dstarts, int* cursor, int* eord, int* insrc){
  int e = blockIdx.x*256+threadIdx.x; int E = getE(pE,Es); if(e>=E) return;
  int d = ed[e];
  int p = dstarts[d] + atomicAdd(&cursor[d],1);
  eord[p] = e;
  insrc[p] = es[e];
}
__global__ void loop_csr_f(const int* __restrict__ insrc,
                           const int* __restrict__ dstarts, const float* __restrict__ pos,
                           float* __restrict__ loopat, int N)
{
  int d = blockIdx.x*256+threadIdx.x; if(d>=N) return;
  int r0=dstarts[d], r1=dstarts[d+1];
  float pd0=pos[d*3], pd1=pos[d*3+1], pd2=pos[d*3+2];
  float l0=0,l1=0,l2=0;
  for(int j=r0;j<r1;j++){
    int s = insrc[j];
    l0 += pd0-pos[s*3]; l1 += pd1-pos[s*3+1]; l2 += pd2-pos[s*3+2];
  }
  float inv = 1.f/fmaxf((float)(r1-r0), 1.f);
  loopat[d*3+0]=l0*inv; loopat[d*3+1]=l1*inv; loopat[d*3+2]=l2*inv;
}

// ---------------- feature GATv2 (fp32) ----------------
__global__ void feat_logits(const int* __restrict__ es, const int* __restrict__ ed, const int* pE, int Es, int N,
    const float* __restrict__ A, const float* __restrict__ B, const float* __restrict__ pos,
    const float* __restrict__ We, const float* __restrict__ att, const float* __restrict__ loopat,
    float* __restrict__ zb)
{
  int gid = blockIdx.x*blockDim.x + threadIdx.x;
  int w = gid>>6, lane = gid&63;
  int E = getE(pE,Es);
  if(w >= E+N) return;
  int s,d; float e0,e1,e2;
  if(w<E){ s=es[w]; d=ed[w]; e0=pos[d*3]-pos[s*3]; e1=pos[d*3+1]-pos[s*3+1]; e2=pos[d*3+2]-pos[s*3+2]; }
  else   { int n=w-E; s=n; d=n; e0=loopat[n*3]; e1=loopat[n*3+1]; e2=loopat[n*3+2]; }
  int c=lane, c2=lane+64;
  float m1 = A[(size_t)s*128+c ] + B[(size_t)d*128+c ] + e0*We[c ] + e1*We[128+c ] + e2*We[256+c ];
  float m2 = A[(size_t)s*128+c2] + B[(size_t)d*128+c2] + e0*We[c2] + e1*We[128+c2] + e2*We[256+c2];
  float p = leakyf(m1)*att[c] + leakyf(m2)*att[c2];
  for(int off=32; off; off>>=1) p += __shfl_down(p, off, 64);
  if(lane==0) zb[w]=p;
}

__global__ void feat_acc_csr(const int* __restrict__ insrc, const int* __restrict__ eord,
                             const int* __restrict__ dstarts, const int* pE, int Es,
                             const float* __restrict__ A, const float* __restrict__ zb,
                             const float* __restrict__ bias, float* __restrict__ h, int N)
{
  int w = (blockIdx.x*256+threadIdx.x)>>6;
  int lane = threadIdx.x&63;
  if(w>=N) return;
  int E = getE(pE,Es);
  int r0=dstarts[w], r1=dstarts[w+1];
  float mx = zb[E+w];
  for(int j=r0+lane; j<r1; j+=64) mx = fmaxf(mx, zb[eord[j]]);
  for(int o=32;o;o>>=1) mx = fmaxf(mx, __shfl_down(mx,o,64));
  mx = __shfl(mx, 0, 64);
  float denom = 0.f;
  float2 acc; acc.x=0.f; acc.y=0.f;
  for(int j=r0;j<r1;j++){
    int e = eord[j]; int s = insrc[j];
    float z = expf(zb[e]-mx);
    denom += z;
    float2 v = *(const float2*)(A + (size_t)s*128 + lane*2);
    acc.x += z*v.x; acc.y += z*v.y;
  }
  {
    float z = expf(zb[E+w]-mx);
    denom += z;
    float2 v = *(const float2*)(A + (size_t)w*128 + lane*2);
    acc.x += z*v.x; acc.y += z*v.y;
  }
  float inv = 1.f/denom;
  float2 bb = *(const float2*)(bias + lane*2);
  acc.x = eluf(acc.x*inv + bb.x); acc.y = eluf(acc.y*inv + bb.y);
  *(float2*)(h + (size_t)w*128 + lane*2) = acc;
}

// ---------------- score GATv2 (fp64) ----------------
// warp-cooperative: 32 lanes per node, coalesced reads of h, shfl-reduce.
__global__ void gemm_score(const float* __restrict__ h, const float* __restrict__ pos,
                           const float* __restrict__ pWl, const float* __restrict__ pWr,
                           double* __restrict__ xls, double* __restrict__ xrs, int N)
{
  int t = threadIdx.x;
  int lane = t&31;
  int n = blockIdx.x*8 + (t>>5);
  if(n>=N) return;
  double sl=0, sr=0;
  #pragma unroll
  for(int q=0;q<4;q++){
    int k = lane + q*32;
    double f = (double)h[(size_t)n*128+k];
    sl += f*(double)pWl[k]; sr += f*(double)pWr[k];
  }
  if(lane<3){
    double f = (double)pos[n*3+lane];
    sl += f*(double)pWl[128+lane]; sr += f*(double)pWr[128+lane];
  }
  for(int o=16;o;o>>=1){ sl += __shfl_down(sl,o,32); sr += __shfl_down(sr,o,32); }
  if(lane==0){ xls[n]=sl; xrs[n]=sr; }
}

// fused score GATv2 with ON-THE-FLY candidate enumeration from the dst-CSR:
// cand(w) = in(w) ∪ in(in(w)); one node per wave, 4 waves/block.
// Pass 1 caches lg and xls[s] in registers (4 candidates/lane, d<=256 covered;
// overflow path recomputes identically) -> pass 2 is pure register math.
__global__ void score_fused2(const int* __restrict__ insrc, const int* __restrict__ dstarts,
                             const float* __restrict__ pos,
                             const double* __restrict__ xls, const double* __restrict__ xrs,
                             const float* __restrict__ pWe, const float* __restrict__ paP,
                             const float* __restrict__ pbP,
                             double* __restrict__ score, int N)
{
  __shared__ int lsAll[4][LSW];
  int wv = threadIdx.x>>6;
  int lane = threadIdx.x&63;
  int w = blockIdx.x*4 + wv;
  bool active = (w<N);
  if(!active) w = N-1;           // clamp: safe reads, no writes
  int* ls = lsAll[wv];
  int r0=dstarts[w], r1=dstarts[w+1]; int din=r1-r0;
  // phase 1: 1-hop candidates
  for(int j=lane;j<din && j<LSW;j+=64) ls[j]=insrc[r0+j];
  __syncthreads();
  // phase 2 (lane-parallel): lane handles in-neighbor (base+lane); exclusive scan of lens -> offsets
  int off = din<LSW? din : LSW;
  for(int base=0; base<din && base<LSW; base+=64){
    int t = base + lane;
    int u0=0, len=0;
    if(t<din && t<LSW){
      int u = ls[t];
      u0 = dstarts[u]; len = dstarts[u+1]-u0;
    }
    int pre = len;
    #pragma unroll
    for(int o=1;o<64;o<<=1){ int v=__shfl_up(pre,o,64); if(lane>=o) pre+=v; }
    int tot = __shfl(pre, 63, 64);
    int myoff = off + pre - len;
    for(int j=0;j<len;j++){ int p=myoff+j; if(p<LSW) ls[p]=insrc[u0+j]; }
    off += tot;
  }
  int d = off<LSW? off : LSW;
  __syncthreads();

  float pd0=pos[w*3], pd1=pos[w*3+1], pd2=pos[w*3+2];
  double w0=(double)pWe[0], w1=(double)pWe[1], w2=(double)pWe[2], pa=(double)paP[0];
  double xrd=xrs[w];
  ull umask=0;
  double lgv[4], xv[4];
  double mx=-1e300, s0=0,s1=0,s2=0; int ucnt=0;
  // cached candidates (j = lane + it*64, it<4)
  #pragma unroll
  for(int it=0; it<4; it++){
    int j = lane + it*64;
    if(j<d){
      int s = ls[j];
      bool uniq = true;
      for(int q=0;q<j;q++) if(ls[q]==s){ uniq=false; break; }
      if(uniq){
        umask |= 1ULL<<it;
        ucnt++;
        double e0=(double)(pd0-pos[s*3]), e1=(double)(pd1-pos[s*3+1]), e2=(double)(pd2-pos[s*3+2]);
        s0+=e0; s1+=e1; s2+=e2;
        double xl = xls[s];
        double lg = leakyd(xl+xrd + e0*w0+e1*w1+e2*w2) * pa;
        lgv[it]=lg; xv[it]=xl;
        mx = fmax(mx, lg);
      }
    }
  }
  // overflow candidates (d>256): original recompute path
  int nb=4;
  for(int j=lane+256; j<d; j+=64, nb++){
    int s = ls[j];
    bool uniq = true;
    for(int q=0;q<j;q++) if(ls[q]==s){ uniq=false; break; }
    if(uniq){
      umask |= 1ULL<<nb;
      ucnt++;
      double e0=(double)(pd0-pos[s*3]), e1=(double)(pd1-pos[s*3+1]), e2=(double)(pd2-pos[s*3+2]);
      s0+=e0; s1+=e1; s2+=e2;
      double lg = leakyd(xls[s]+xrd + e0*w0+e1*w1+e2*w2) * pa;
      mx = fmax(mx, lg);
    }
  }
  for(int o=32;o;o>>=1){
    mx = fmax(mx, __shfl_down(mx,o,64));
    s0 += __shfl_down(s0,o,64);
    s1 += __shfl_down(s1,o,64);
    s2 += __shfl_down(s2,o,64);
    ucnt += __shfl_down(ucnt,o,64);
  }
  mx=__shfl(mx,0,64); s0=__shfl(s0,0,64); s1=__shfl(s1,0,64); s2=__shfl(s2,0,64); ucnt=__shfl(ucnt,0,64);
  double invd = 1.0/(double)(ucnt>0? ucnt : 1);
  double lg_self = leakyd(xls[w]+xrd + (s0*invd)*w0 + (s1*invd)*w1 + (s2*invd)*w2) * pa;
  mx = fmax(mx, lg_self);
  double den=0, acc=0;
  #pragma unroll
  for(int it=0; it<4; it++){
    if((umask>>it)&1ULL){
      double z = exp(lgv[it]-mx);
      den += z; acc += z*xv[it];
    }
  }
  nb=4;
  for(int j=lane+256; j<d; j+=64, nb++){
    if((umask>>nb)&1ULL){
      int s = ls[j];
      double e0=(double)(pd0-pos[s*3]), e1=(double)(pd1-pos[s*3+1]), e2=(double)(pd2-pos[s*3+2]);
      double lg = leakyd(xls[s]+xrd + e0*w0+e1*w1+e2*w2) * pa;
      double z = exp(lg-mx);
      den += z; acc += z*xls[s];
    }
  }
  for(int o=32;o;o>>=1){
    den += __shfl_down(den,o,64);
    acc += __shfl_down(acc,o,64);
  }
  if(lane==0 && active){
    double z = exp(lg_self-mx);
    den += z; acc += z*xls[w];
    score[w] = tanh(acc/den + (double)pbP[0]);
  }
}

// ---------------- top-k: 2-round 21-bit refine select + bucketed ranking ----------------
__global__ void enc_scores(const double* __restrict__ score, int N, ull* __restrict__ ek,
                           int* __restrict__ rank){
  int i = blockIdx.x*256+threadIdx.x; if(i>=N) return;
  ek[i] = encd(score[i]);
  rank[i] = 0x3f3f3f3f;
}
// histogram of 21-bit digit at `shift`, restricted to keys whose bits above shift+21 match selT
__global__ void hist_g(const ull* __restrict__ ek, int N, int shift, const ull* __restrict__ selT,
                       int* __restrict__ hist){
  int i = blockIdx.x*256+threadIdx.x; if(i>=N) return;
  ull key = ek[i];
  if(shift+21 < 64){
    if((key >> (shift+21)) != ((*selT) >> (shift+21))) return;
  }
  atomicAdd(&hist[(int)((key>>shift)&0x1FFFFF)], 1);
}
__global__ void part21(const int* __restrict__ hist, int* __restrict__ partial){
  __shared__ int red[256];
  int b = blockIdx.x;
  int s=0;
  for(int i=threadIdx.x;i<1024;i+=256) s += hist[b*1024+i];
  red[threadIdx.x]=s; __syncthreads();
  for(int o=128;o;o>>=1){ if(threadIdx.x<(unsigned)o) red[threadIdx.x]+=red[threadIdx.x+o]; __syncthreads(); }
  if(threadIdx.x==0) partial[b]=red[0];
}
// find the bin containing the keff-th largest key; update selT (bin at `shift`) and selRB (count strictly above)
__global__ void findbin_g(const int* __restrict__ partial, const int* __restrict__ hist,
                          ull* __restrict__ selT, int* __restrict__ selRB, int k, int shift){
  __shared__ int ts[256];
  __shared__ int cstar, rbase;
  int t=threadIdx.x;
  int keff = k - *selRB;
  int s8[8]; int mysum=0;
  #pragma unroll
  for(int q=0;q<8;q++){ s8[q]=partial[t*8+q]; mysum+=s8[q]; }
  ts[t]=mysum; __syncthreads();
  for(int o=1;o<256;o<<=1){ int u=(t+o<256)? ts[t+o]:0; __syncthreads(); ts[t]+=u; __syncthreads(); }
  int after = (t<255)? ts[t+1] : 0;
  if(ts[t] >= keff && after < keff){
    int run = after;
    for(int q=7;q>=0;q--){
      if(run < keff && run + s8[q] >= keff){ cstar = t*8+q; rbase = run; }
      run += s8[q];
    }
  }
  __syncthreads();
  int cs=cstar, rb=rbase;
  int b4[4]; int ms=0;
  #pragma unroll
  for(int q=0;q<4;q++){ b4[q]=hist[cs*1024 + t*4 + q]; ms+=b4[q]; }
  ts[t]=ms; __syncthreads();
  for(int o=1;o<256;o<<=1){ int u=(t+o<256)? ts[t+o]:0; __syncthreads(); ts[t]+=u; __syncthreads(); }
  int after2 = (t<255)? ts[t+1] : 0;
  if(rb+ts[t] >= keff && rb+after2 < keff){
    int run = rb+after2;
    for(int q=3;q>=0;q--){
      if(run < keff && run + b4[q] >= keff){
        *selT |= ((ull)(cs*1024 + t*4 + q)) << shift;
        *selRB = (k - keff) + run;
      }
      run += b4[q];
    }
  }
}
// ----- bucketed exact ranking of candidates (key >= selT) -----
// bucket digit = complemented top-21 bits => ascending bucket = descending key.
__global__ void rank_hist(const ull* __restrict__ ek, int N, const ull* __restrict__ selT,
                          int* __restrict__ hist){
  int i = blockIdx.x*256+threadIdx.x; if(i>=N) return;
  ull key = ek[i]; if(key < *selT) return;
  int dg = (int)((~key >> 43) & 0x1FFFFF);
  atomicAdd(&hist[dg], 1);
}
// per-1024-bin-block exclusive scan + global block offset -> binstarts; last thread writes total
__global__ void binscan(const int* __restrict__ hist, const int* __restrict__ p2,
                        int* __restrict__ binstarts){
  __shared__ int ts[256];
  int b = blockIdx.x, t = threadIdx.x;
  int v[4]; int s=0;
  #pragma unroll
  for(int q=0;q<4;q++){ v[q]=s; s+=hist[b*1024 + t*4 + q]; }
  ts[t]=s; __syncthreads();
  int mine=s;
  for(int o=1;o<256;o<<=1){ int u=0; if(t>=(unsigned)o) u=ts[t-o]; __syncthreads(); ts[t]+=u; __syncthreads(); }
  int pre = p2[b] + ts[t] - mine;
  #pragma unroll
  for(int q=0;q<4;q++) binstarts[b*1024 + t*4 + q] = pre + v[q];
  if(b==2047 && t==255) binstarts[HBINS] = p2[b] + ts[255];
}
// scatter candidate (key,idx) into bucket-ordered member arrays (consumes hist counts)
__global__ void rank_fill(const ull* __restrict__ ek, int N, const ull* __restrict__ selT,
                          const int* __restrict__ binstarts, int* __restrict__ hist,
                          ull* __restrict__ mkeys, int* __restrict__ midx){
  int i = blockIdx.x*256+threadIdx.x; if(i>=N) return;
  ull key = ek[i]; if(key < *selT) return;
  int dg = (int)((~key >> 43) & 0x1FFFFF);
  int o = atomicSub(&hist[dg], 1) - 1;
  int p = binstarts[dg] + o;
  mkeys[p] = key; midx[p] = i;
}
// exact rank: bucket start + same-bucket (key desc, idx asc) pairwise over STREAMED inline keys
__global__ void rank_within(const int* __restrict__ binstarts,
                            const ull* __restrict__ mkeys, const int* __restrict__ midx,
                            int* __restrict__ rank, int Nmax){
  int m = blockIdx.x*256+threadIdx.x; if(m>=Nmax) return;
  int total = binstarts[HBINS]; if(m>=total) return;
  ull key = mkeys[m]; int ii = midx[m];
  int dg = (int)((~key >> 43) & 0x1FFFFF);
  int s = binstarts[dg], e = binstarts[dg+1];
  int cnt = 0;
  for(int j=s;j<e;j++){
    ull kj = mkeys[j];
    cnt += (kj > key) || (kj == key && midx[j] < ii);
  }
  rank[ii] = s + cnt;
}
__global__ void scatter_perm(const int* __restrict__ rank, int N, int k, int* __restrict__ perm){
  int i = blockIdx.x*256+threadIdx.x; if(i>=N) return;
  int r = rank[i]; if(r<k) perm[r]=i;
}
__global__ void pool_gather(const float* __restrict__ h, const double* __restrict__ score,
                            const int* __restrict__ perm, int k, float* __restrict__ outA){
  int idx = blockIdx.x*256+threadIdx.x; if(idx>=k*32) return;
  int r = idx>>5, g = (idx&31)*4;
  int p = perm[r]; float sc = (float)score[p];
  const float4 x = *(const float4*)(h + (size_t)p*128 + g);
  float4 o; o.x=x.x*sc; o.y=x.y*sc; o.z=x.z*sc; o.w=x.w*sc;
  *(float4*)(outA + (size_t)r*128 + g) = o;
}
__global__ void pos_gather(const float* __restrict__ posc, const int* __restrict__ perm, int k, float* __restrict__ posn){
  int idx = blockIdx.x*256+threadIdx.x; if(idx>=k*3) return;
  int r = idx/3, j = idx-r*3;
  posn[idx] = posc[perm[r]*3+j];
}

// ---------------- filter_adj ----------------
__global__ void filter_flags(const int* __restrict__ es, const int* __restrict__ ed, const int* pE, int Es,
                             const int* __restrict__ rank, int k, int* __restrict__ flags){
  int e = blockIdx.x*256+threadIdx.x; int E = getE(pE,Es); if(e>=E) return;
  flags[e] = (rank[es[e]]<k && rank[ed[e]]<k) ? 1 : 0;
}
__global__ void filter_write(const int* __restrict__ es, const int* __restrict__ ed, const int* pE, int Es,
                             const int* __restrict__ rank, int k, const int* __restrict__ scanout,
                             int* __restrict__ ns, int* __restrict__ nd){
  int e = blockIdx.x*256+threadIdx.x; int E = getE(pE,Es); if(e>=E) return;
  int rs = rank[es[e]], rd = rank[ed[e]];
  if(rs<k && rd<k){ int p = scanout[e]; ns[p]=rs; nd[p]=rd; }
}

// ---------------- output emit ----------------
__global__ void calc_offsets(const int* __restrict__ cnt, long long* __restrict__ offs){
  if(blockIdx.x==0 && threadIdx.x==0){
    long long E1 = cnt[C_E1], E2 = cnt[C_E2];
    long long o = (long long)KK2*128;
    offs[0]=0;
    offs[1]=o; o += 2*E2;
    offs[2]=o; o += 2*E1;
    offs[3]=o; o += 2*(long long)EE0;
    offs[4]=o; o += (long long)KK2*3;
    offs[5]=o; o += (long long)KK1*3;
    offs[6]=o; o += (long long)NN0*3;
    offs[7]=o; o += 3*E2;
    offs[8]=o; o += 3*E1;
    offs[9]=o;
  }
}
__global__ void emit_pe(const int* __restrict__ s, const int* __restrict__ d, const int* pE, int Es,
                        const long long* __restrict__ offs, int oi, float* __restrict__ out){
  int e = blockIdx.x*256+threadIdx.x; int E = getE(pE,Es); if(e>=E) return;
  long long o = offs[oi];
  out[o+e]   = (float)s[e];
  out[o+E+e] = (float)d[e];
}
__global__ void emit_pp(const float* __restrict__ p, int n, const long long* __restrict__ offs, int oi, float* __restrict__ out){
  int i = blockIdx.x*256+threadIdx.x; if(i>=n) return;
  out[offs[oi]+i] = p[i];
}
__global__ void emit_eas(const int* __restrict__ s, const int* __restrict__ d, const int* pE, int Es,
                         const float* __restrict__ pos, const long long* __restrict__ offs, int oi, float* __restrict__ out){
  int e = blockIdx.x*256+threadIdx.x; int E = getE(pE,Es); if(e>=E) return;
  long long o = offs[oi];
  int ss=s[e], dd=d[e];
  out[o+3*e+0] = pos[dd*3+0]-pos[ss*3+0];
  out[o+3*e+1] = pos[dd*3+1]-pos[ss*3+1];
  out[o+3*e+2] = pos[dd*3+2]-pos[ss*3+2];
}

// =======================================================================
extern "C" void kernel_launch(void* const* d_in, const int* in_sizes, int n_in,
                              void* d_out, int out_size, void* d_ws, size_t ws_size,
                              hipStream_t stream)
{
  const float* x    = (const float*)d_in[0];
  const float* yv   = (const float*)d_in[1];
  const float* pos0 = (const float*)d_in[2];
  const int*   ei   = (const int*)d_in[3];
  const float* Wl0  = (const float*)d_in[4];
  const float* Wr0  = (const float*)d_in[5];
  const float* We0  = (const float*)d_in[6];
  const float* a0   = (const float*)d_in[7];
  const float* b0   = (const float*)d_in[8];
  const float* Wls  = (const float*)d_in[9];
  const float* Wrs  = (const float*)d_in[10];
  const float* Wes  = (const float*)d_in[11];
  const float* atts = (const float*)d_in[12];
  const float* bs   = (const float*)d_in[13];
  const float* pWl  = (const float*)d_in[14];
  const float* pWr  = (const float*)d_in[15];
  const float* pWe  = (const float*)d_in[16];
  const float* pa   = (const float*)d_in[17];
  const float* pb   = (const float*)d_in[18];
  const float* linW = (const float*)d_in[19];
  const float* linb = (const float*)d_in[20];
  float* out = (float*)d_out;

  const int* eisrc = ei;
  const int* eidst = ei + EE0;

  char* base = (char*)d_ws; size_t off = 0;
  auto alloc = [&](size_t b)->void*{
    off = (off + 255) & ~(size_t)255;
    void* p = base + off; off += b; return p;
  };
  int*       cnt     = (int*)alloc(64*4);
  long long* offs    = (long long*)alloc(16*8);
  int*       bsums   = (int*)alloc(256*4);
  ull*       sel     = (ull*)alloc(2*8);
  int*       hist    = (int*)alloc((size_t)HBINS*4);
  int*       partial = (int*)alloc(2048*4);
  int*       partial2= (int*)alloc(2304*4);
  double*    xls     = (double*)alloc((size_t)NN0*8);
  double*    xrs     = (double*)alloc((size_t)NN0*8);
  double*    score   = (double*)alloc((size_t)NN0*8);
  ull*       ek      = (ull*)alloc((size_t)NN0*8);
  float*     loopatF = (float*)alloc((size_t)NN0*12);
  int*       rank    = (int*)alloc((size_t)NN0*4);
  int*       perm    = (int*)alloc((size_t)NN0*4);
  int*       cursor  = (int*)alloc((size_t)NN0*4);
  int*       ccnt    = (int*)alloc((size_t)NN0*4);
  int*       dstarts = (int*)alloc((size_t)(NN0+1)*4);
  int*       eord    = (int*)alloc((size_t)EE0*4);
  int*       insrc   = (int*)alloc((size_t)EE0*4);
  int*       flags   = (int*)alloc((size_t)EE0*4);
  int*       scanout = (int*)alloc((size_t)(EE0+1)*4);
  int*       eb0s    = (int*)alloc((size_t)EE0*4);
  int*       eb0d    = (int*)alloc((size_t)EE0*4);
  int*       eb1s    = (int*)alloc((size_t)EE0*4);
  int*       eb1d    = (int*)alloc((size_t)EE0*4);
  float*     pos1    = (float*)alloc((size_t)KK1*12);
  float*     pos2    = (float*)alloc((size_t)KK2*12);
  float*     A       = (float*)alloc((size_t)NN0*128*4);
  float*     B       = (float*)alloc((size_t)NN0*128*4);
  float*     h       = (float*)alloc((size_t)NN0*128*4);
  void*      uni     = alloc((size_t)(EE0+FLATMAX)*8);   // union: zbF (conv) / binstarts+mkeys+midx (ranking)
  if(off > ws_size) return;

  float*  zbF      = (float*)uni;
  int*    binstarts= (int*)uni;                          // HBINS+1 ints
  ull*    mkeys    = (ull*)((int*)uni + (HBINS + 256));  // up to NN0 ulls, 8B-aligned
  int*    midx     = (int*)(mkeys + NN0);                // up to NN0 ints
  ull*    selT  = sel;
  int*    selRB = (int*)(sel+1);

  hipMemsetAsync(cnt, 0, 64*4, stream);

  auto scan = [&](const int* in, int* sout, const int* pN, int Ns, int* total){
    int nb = CDIV(Ns+1, SCH);
    scan_p1<<<nb,256,0,stream>>>(in,pN,Ns,bsums);
    scan_p2<<<1,256,0,stream>>>(bsums,nb);
    scan_p3<<<nb,256,0,stream>>>(in,sout,pN,Ns,bsums,total);
  };

  auto build_csr_dst = [&](const int* es, const int* ed, const int* pE, int Emax, int N, const float* pcur){
    hipMemsetAsync(ccnt,0,(size_t)N*4,stream);
    count_src<<<CDIV(Emax,256),256,0,stream>>>(ed,pE,Emax,ccnt);
    scan(ccnt,dstarts,nullptr,N,nullptr);
    hipMemsetAsync(cursor,0,(size_t)N*4,stream);
    fill_eord<<<CDIV(Emax,256),256,0,stream>>>(es,ed,pE,Emax,dstarts,cursor,eord,insrc);
    loop_csr_f<<<CDIV(N,256),256,0,stream>>>(insrc,dstarts,pcur,loopatF,N);
  };

  auto feat_conv = [&](const float* Wl, const float* Wr, const float* We, const float* att, const float* bias,
                       const int* es, const int* ed, const int* pE, int Emax, int N, const float* pcur,
                       bool conv0mode){
    if(conv0mode)
      gemm_k<0,true><<<CDIV(N,32),256,0,stream>>>(x,pcur,yv,Wl,Wr,nullptr,A,B,N);
    else
      gemm_k<1,true><<<CDIV(N,32),256,0,stream>>>(h,pcur,nullptr,Wl,Wr,nullptr,A,B,N);
    long long wt = (long long)(Emax+N)*64;
    feat_logits<<<(int)CDIV(wt,256),256,0,stream>>>(es,ed,pE,Emax,N,A,B,pcur,We,att,loopatF,zbF);
    feat_acc_csr<<<CDIV(N*64,256),256,0,stream>>>(insrc,eord,dstarts,pE,Emax,A,zbF,bias,h,N);
  };

  auto pool = [&](int l, int N, int k, const int* es, const int* ed, const int* pE, int Emax,
                  const float* pcur, float* pnext, int* ns, int* nd, int eslot){
    // fused score GATv2 (fp64): candidates enumerated on-the-fly from dst-CSR (in ∪ in∘in)
    gemm_score<<<CDIV(N,8),256,0,stream>>>(h,pcur,pWl+l*131,pWr+l*131,xls,xrs,N);
    score_fused2<<<CDIV(N,4),256,0,stream>>>(insrc,dstarts,pcur,xls,xrs,pWe+l*3,pa+l,pb+l,score,N);
    // top-k: 2-round refine select (bits 63..43, then 42..22)
    enc_scores<<<CDIV(N,256),256,0,stream>>>(score,N,ek,rank);
    hipMemsetAsync(sel,0,16,stream);
    for(int r=0;r<2;r++){
      int sh = 43 - 21*r;
      hipMemsetAsync(hist,0,(size_t)HBINS*4,stream);
      hist_g<<<CDIV(N,256),256,0,stream>>>(ek,N,sh,selT,hist);
      part21<<<2048,256,0,stream>>>(hist,partial);
      findbin_g<<<1,256,0,stream>>>(partial,hist,selT,selRB,k,sh);
    }
    // bucketed exact ranking of candidates (inline-key streaming within bucket)
    hipMemsetAsync(hist,0,(size_t)HBINS*4,stream);
    rank_hist  <<<CDIV(N,256),256,0,stream>>>(ek,N,selT,hist);
    part21     <<<2048,256,0,stream>>>(hist,partial);
    scan(partial,partial2,nullptr,2048,nullptr);
    binscan    <<<2048,256,0,stream>>>(hist,partial2,binstarts);
    rank_fill  <<<CDIV(N,256),256,0,stream>>>(ek,N,selT,binstarts,hist,mkeys,midx);
    rank_within<<<CDIV(N,256),256,0,stream>>>(binstarts,mkeys,midx,rank,N);
    scatter_perm<<<CDIV(N,256),256,0,stream>>>(rank,N,k,perm);
    pool_gather<<<CDIV(k*32,256),256,0,stream>>>(h,score,perm,k,A);
    hipMemcpyAsync(h,A,(size_t)k*128*4,hipMemcpyDeviceToDevice,stream);
    pos_gather<<<CDIV(k*3,256),256,0,stream>>>(pcur,perm,k,pnext);
    filter_flags<<<CDIV(Emax,256),256,0,stream>>>(es,ed,pE,Emax,rank,k,flags);
    scan(flags,scanout,pE,Emax,cnt+eslot);
    filter_write<<<CDIV(Emax,256),256,0,stream>>>(es,ed,pE,Emax,rank,k,scanout,ns,nd);
  };

  // ================= pipeline =================
  build_csr_dst(eisrc,eidst,nullptr,EE0, NN0, pos0);
  feat_conv(Wl0,Wr0,We0,a0,b0, eisrc,eidst,nullptr,EE0, NN0, pos0, true);
  feat_conv(Wls+0*16768,Wrs+0*16768,Wes+0*384,atts+0*128,bs+0*128, eisrc,eidst,nullptr,EE0, NN0, pos0, false);
  pool(0, NN0, KK1, eisrc,eidst,nullptr,EE0, pos0,pos1, eb0s,eb0d, C_E1);
  build_csr_dst(eb0s,eb0d,cnt+C_E1,EE0, KK1, pos1);
  feat_conv(Wls+1*16768,Wrs+1*16768,Wes+1*384,atts+1*128,bs+1*128, eb0s,eb0d,cnt+C_E1,EE0, KK1, pos1, false);
  pool(1, KK1, KK2, eb0s,eb0d,cnt+C_E1,EE0, pos1,pos2, eb1s,eb1d, C_E2);
  build_csr_dst(eb1s,eb1d,cnt+C_E2,EE0, KK2, pos2);
  feat_conv(Wls+2*16768,Wrs+2*16768,Wes+2*384,atts+2*128,bs+2*128, eb1s,eb1d,cnt+C_E2,EE0, KK2, pos2, false);
  feat_conv(Wls+3*16768,Wrs+3*16768,Wes+3*384,atts+3*128,bs+3*128, eb1s,eb1d,cnt+C_E2,EE0, KK2, pos2, false);
  gemm_k<2,false><<<CDIV(KK2,32),256,0,stream>>>(h,nullptr,nullptr,linW,nullptr,linb,out,nullptr,KK2);

  calc_offsets<<<1,32,0,stream>>>(cnt,offs);
  emit_pe <<<CDIV(EE0,256),256,0,stream>>>(eb1s,eb1d,cnt+C_E2,EE0,offs,1,out);
  emit_pe <<<CDIV(EE0,256),256,0,stream>>>(eb0s,eb0d,cnt+C_E1,EE0,offs,2,out);
  emit_pe <<<CDIV(EE0,256),256,0,stream>>>(eisrc,eidst,nullptr,EE0,offs,3,out);
  emit_pp <<<CDIV(KK2*3,256),256,0,stream>>>(pos2,KK2*3,offs,4,out);
  emit_pp <<<CDIV(KK1*3,256),256,0,stream>>>(pos1,KK1*3,offs,5,out);
  emit_pp <<<CDIV(NN0*3,256),256,0,stream>>>(pos0,NN0*3,offs,6,out);
  emit_eas<<<CDIV(EE0,256),256,0,stream>>>(eb1s,eb1d,cnt+C_E2,EE0,pos2,offs,7,out);
  emit_eas<<<CDIV(EE0,256),256,0,stream>>>(eb0s,eb0d,cnt+C_E1,EE0,pos1,offs,8,out);
  emit_eas<<<CDIV(EE0,256),256,0,stream>>>(eisrc,eidst,nullptr,EE0,pos0,offs,9,out);
}

// Round 10
// 1805.216 us; speedup vs baseline: 1.2078x; 1.1711x over previous
//
#include <hip/hip_runtime.h>

typedef unsigned long long ull;

#define NN0 80000
#define EE0 480000
#define KK1 40000
#define KK2 20000
#define FLATMAX 8000000
#define SCH 4096
#define CDIV(a,b) (((a)+(b)-1)/(b))
#define HBINS (1<<21)
#define LSW 1024
#define FCAP 512

// counter slots
#define C_E1 2
#define C_E2 3
#define C_M0 5
#define C_M1 6

__device__ __forceinline__ int getE(const int* p, int s){ if(!p) return s; int e=*p; return e<s? e : s; }
__device__ __forceinline__ float leakyf(float x){ return x>0.f? x : 0.2f*x; }
__device__ __forceinline__ double leakyd(double x){ return x>0.0? x : 0.2*x; }
__device__ __forceinline__ float eluf(float x){ return x>0.f? x : (expf(x)-1.f); }

__device__ __forceinline__ ull encd(double f){ ull u=(ull)__double_as_longlong(f); return (u>>63)? ~u : (u|0x8000000000000000ULL); }

// ---------------- GEMM: xl/xr projections ----------------
// 32 rows per block; input tile staged in LDS; each thread owns a 4row x 4col (x dual) register tile.
template<int MODE, bool DUAL>
__global__ void gemm_k(const float* __restrict__ F1, const float* __restrict__ pos,
                       const float* __restrict__ yv,
                       const float* __restrict__ W1, const float* __restrict__ W2,
                       const float* __restrict__ bias,
                       float* __restrict__ O1, float* __restrict__ O2, int N)
{
  const int K = MODE==0? 11 : (MODE==1? 131 : 128);
  __shared__ float lf[32][132];   // stride 132: float4-aligned rows, broadcast reads
  int t = threadIdx.x;
  int row0 = blockIdx.x*32;

  // ---- stage 32-row input tile into LDS (coalesced) ----
  if(MODE==0){
    for(int i=t;i<32*11;i+=256){
      int r=i/11, k=i-r*11; int row=row0+r;
      float f=0.f;
      if(row<N) f = (k<5)? F1[(size_t)row*5+k] : (k<8? pos[(size_t)row*3+(k-5)] : yv[0]);
      lf[r][k]=f;
    }
  } else {
    for(int i=t;i<32*32;i+=256){
      int r=i>>5, c4=i&31; int row=row0+r;
      float4 v; v.x=0.f;v.y=0.f;v.z=0.f;v.w=0.f;
      if(row<N) v = *(const float4*)(F1+(size_t)row*128+c4*4);
      *(float4*)(&lf[r][c4*4]) = v;
    }
    if(MODE==1){
      for(int i=t;i<32*3;i+=256){
        int r=i/3, d=i-r*3; int row=row0+r;
        lf[r][128+d] = (row<N)? pos[(size_t)row*3+d] : 0.f;
      }
    }
  }
  __syncthreads();

  int cg = t&31, rg = t>>5;      // 32 col-groups x 8 row-groups
  int g = cg*4;
  int rbase = rg*4;

  float acc1[4][4]; float acc2[4][4];
  #pragma unroll
  for(int rr=0;rr<4;rr++)
    #pragma unroll
    for(int c=0;c<4;c++){ acc1[rr][c]=0.f; acc2[rr][c]=0.f; }

  #pragma unroll 4
  for(int k=0;k<K;k++){
    float4 w = *(const float4*)(W1 + (size_t)k*128 + g);
    float4 v; v.x=0.f;v.y=0.f;v.z=0.f;v.w=0.f;
    if(DUAL) v = *(const float4*)(W2 + (size_t)k*128 + g);
    #pragma unroll
    for(int rr=0;rr<4;rr++){
      float f = lf[rbase+rr][k];
      acc1[rr][0]+=f*w.x; acc1[rr][1]+=f*w.y; acc1[rr][2]+=f*w.z; acc1[rr][3]+=f*w.w;
      if(DUAL){ acc2[rr][0]+=f*v.x; acc2[rr][1]+=f*v.y; acc2[rr][2]+=f*v.z; acc2[rr][3]+=f*v.w; }
    }
  }

  float4 bb; bb.x=0.f;bb.y=0.f;bb.z=0.f;bb.w=0.f;
  if(bias) bb = *(const float4*)(bias+g);
  #pragma unroll
  for(int rr=0;rr<4;rr++){
    int row = row0 + rbase + rr;
    if(row<N){
      float4 r1; r1.x=acc1[rr][0]+bb.x; r1.y=acc1[rr][1]+bb.y; r1.z=acc1[rr][2]+bb.z; r1.w=acc1[rr][3]+bb.w;
      *(float4*)(O1+(size_t)row*128+g) = r1;
      if(DUAL){
        float4 r2; r2.x=acc2[rr][0]; r2.y=acc2[rr][1]; r2.z=acc2[rr][2]; r2.w=acc2[rr][3];
        *(float4*)(O2+(size_t)row*128+g) = r2;
      }
    }
  }
}

// ---------------- multi-block exclusive scan ----------------
__global__ void scan_p1(const int* __restrict__ in, const int* pN, int Ns, int* __restrict__ bsums){
  __shared__ int red[256];
  int n = getE(pN,Ns);
  int base = blockIdx.x*SCH;
  int s=0;
  for(int i=base+threadIdx.x; i<base+SCH; i+=256) if(i<n) s+=in[i];
  red[threadIdx.x]=s; __syncthreads();
  for(int o=128;o;o>>=1){ if(threadIdx.x<(unsigned)o) red[threadIdx.x]+=red[threadIdx.x+o]; __syncthreads(); }
  if(threadIdx.x==0) bsums[blockIdx.x]=red[0];
}
__global__ void scan_p2(int* bsums, int nb){
  __shared__ int lds[256];
  int t=threadIdx.x;
  int v = (t<nb)? bsums[t] : 0;
  lds[t]=v; __syncthreads();
  for(int o=1;o<256;o<<=1){ int u=0; if(t>=o) u=lds[t-o]; __syncthreads(); lds[t]+=u; __syncthreads(); }
  if(t<nb) bsums[t]=lds[t]-v;
}
__global__ void scan_p3(const int* __restrict__ in, int* __restrict__ out, const int* pN, int Ns,
                        const int* __restrict__ bsums, int* total){
  __shared__ int tsum[256];
  int n = getE(pN,Ns);
  int base = blockIdx.x*SCH + threadIdx.x*16;
  int v[16]; int s=0;
  #pragma unroll
  for(int q=0;q<16;q++){ int i=base+q; int xv=(i<n)? in[i]:0; v[q]=s; s+=xv; }
  tsum[threadIdx.x]=s; __syncthreads();
  int mine=s;
  for(int o=1;o<256;o<<=1){ int u=0; if(threadIdx.x>=(unsigned)o) u=tsum[threadIdx.x-o]; __syncthreads(); tsum[threadIdx.x]+=u; __syncthreads(); }
  int pre = bsums[blockIdx.x] + tsum[threadIdx.x] - mine;
  #pragma unroll
  for(int q=0;q<16;q++){
    int i=base+q;
    if(i<=n){
      int val = pre+v[q];
      out[i]=val;
      if(i==n && total) *total=val;
    }
  }
}

// ---------------- CSR builders ----------------
__global__ void count_src(const int* __restrict__ es, const int* pE, int Es, int* cnts){
  int e = blockIdx.x*256+threadIdx.x; int E = getE(pE,Es); if(e>=E) return;
  atomicAdd(&cnts[es[e]], 1);
}
// dst-CSR: insrc = source node ordered by dst
__global__ void fill_eord(const int* __restrict__ es, const int* __restrict__ ed, const int* pE, int Es,
                          const int* __restrict__ dstarts, int* cursor, int* insrc){
  int e = blockIdx.x*256+threadIdx.x; int E = getE(pE,Es); if(e>=E) return;
  int d = ed[e];
  int p = dstarts[d] + atomicAdd(&cursor[d],1);
  insrc[p] = es[e];
}

// ---------------- FUSED feature GATv2 (fp32): logits + softmax-accumulate ----------------
// one wave per node, 4 waves/block. Lane c handles channels (c, c+64) — identical mapping,
// reduction tree, and serial j-order as the previous feat_logits/feat_acc_csr pair,
// so h is bit-identical. Logits cached in per-wave LDS (din<=FCAP; overflow recomputes).
__global__ void feat_fused(const int* __restrict__ insrc, const int* __restrict__ dstarts,
                           const float* __restrict__ A, const float* __restrict__ B,
                           const float* __restrict__ pos,
                           const float* __restrict__ We, const float* __restrict__ att,
                           const float* __restrict__ bias, float* __restrict__ h, int N)
{
  __shared__ float lgAll[4][FCAP];
  int wv = threadIdx.x>>6, lane = threadIdx.x&63;
  int w = blockIdx.x*4 + wv;
  bool active = (w<N);
  if(!active) w = N-1;            // clamp: safe reads, no writes
  float* lg = lgAll[wv];
  int r0=dstarts[w], r1=dstarts[w+1]; int din=r1-r0;
  int c=lane, c2=lane+64;
  float B0 = B[(size_t)w*128+c], B1 = B[(size_t)w*128+c2];
  float We0c=We[c], We1c=We[128+c], We2c=We[256+c];
  float We0d=We[c2], We1d=We[128+c2], We2d=We[256+c2];
  float attc=att[c], attd=att[c2];
  float pw0=pos[w*3], pw1=pos[w*3+1], pw2=pos[w*3+2];

  // pass A: per-edge logits (serial j, wave-parallel channels) + loopat accumulation
  float l0=0,l1=0,l2=0;
  for(int j=0;j<din;j++){
    int s = insrc[r0+j];
    float e0=pw0-pos[s*3], e1=pw1-pos[s*3+1], e2=pw2-pos[s*3+2];
    l0+=e0; l1+=e1; l2+=e2;
    float a0=A[(size_t)s*128+c], a1=A[(size_t)s*128+c2];
    float m1 = a0 + B0 + e0*We0c + e1*We1c + e2*We2c;
    float m2 = a1 + B1 + e0*We0d + e1*We1d + e2*We2d;
    float p = leakyf(m1)*attc + leakyf(m2)*attd;
    for(int o=32;o;o>>=1) p += __shfl_down(p,o,64);
    if(lane==0 && j<FCAP) lg[j]=p;
  }
  // self logit (loopat = mean of accumulated edge vectors, same order/rounding as loop_csr_f)
  float inv = 1.f/fmaxf((float)din, 1.f);
  float q0=l0*inv, q1=l1*inv, q2=l2*inv;
  float a0w=A[(size_t)w*128+c], a1w=A[(size_t)w*128+c2];
  float pself;
  {
    float m1 = a0w + B0 + q0*We0c + q1*We1c + q2*We2c;
    float m2 = a1w + B1 + q0*We0d + q1*We1d + q2*We2d;
    float p = leakyf(m1)*attc + leakyf(m2)*attd;
    for(int o=32;o;o>>=1) p += __shfl_down(p,o,64);
    pself = __shfl(p,0,64);
  }
  // max (exact, order-free): strided over cached logits + tree reduce
  float mx = pself;
  int dc = din<FCAP? din : FCAP;
  for(int j=lane;j<dc;j+=64) mx = fmaxf(mx, lg[j]);
  for(int o=32;o;o>>=1) mx = fmaxf(mx, __shfl_down(mx,o,64));
  mx = __shfl(mx,0,64);
  // overflow logits (din>FCAP): serial recompute (identical formula -> identical bits)
  for(int j=FCAP;j<din;j++){
    int s = insrc[r0+j];
    float e0=pw0-pos[s*3], e1=pw1-pos[s*3+1], e2=pw2-pos[s*3+2];
    float a0=A[(size_t)s*128+c], a1=A[(size_t)s*128+c2];
    float m1 = a0 + B0 + e0*We0c + e1*We1c + e2*We2c;
    float m2 = a1 + B1 + e0*We0d + e1*We1d + e2*We2d;
    float p = leakyf(m1)*attc + leakyf(m2)*attd;
    for(int o=32;o;o>>=1) p += __shfl_down(p,o,64);
    p = __shfl(p,0,64);
    mx = fmaxf(mx, p);
  }

  // pass B: softmax-weighted accumulation (serial j, same order as old feat_acc_csr)
  float denom=0.f, acc0=0.f, acc1=0.f;
  for(int j=0;j<din;j++){
    int s = insrc[r0+j];
    float lgj;
    if(j<FCAP) lgj = lg[j];
    else {
      float e0=pw0-pos[s*3], e1=pw1-pos[s*3+1], e2=pw2-pos[s*3+2];
      float a0=A[(size_t)s*128+c], a1=A[(size_t)s*128+c2];
      float m1 = a0 + B0 + e0*We0c + e1*We1c + e2*We2c;
      float m2 = a1 + B1 + e0*We0d + e1*We1d + e2*We2d;
      float p = leakyf(m1)*attc + leakyf(m2)*attd;
      for(int o=32;o;o>>=1) p += __shfl_down(p,o,64);
      lgj = __shfl(p,0,64);
    }
    float z = expf(lgj - mx);
    denom += z;
    acc0 += z*A[(size_t)s*128+c];
    acc1 += z*A[(size_t)s*128+c2];
  }
  {
    float z = expf(pself - mx);
    denom += z;
    acc0 += z*a0w; acc1 += z*a1w;
  }
  float iv = 1.f/denom;
  float b0v=bias[c], b1v=bias[c2];
  acc0 = eluf(acc0*iv + b0v); acc1 = eluf(acc1*iv + b1v);
  if(active){
    h[(size_t)w*128+c ] = acc0;
    h[(size_t)w*128+c2] = acc1;
  }
}

// ---------------- score GATv2 (fp64) ----------------
// warp-cooperative: 32 lanes per node, coalesced reads of h, shfl-reduce.
__global__ void gemm_score(const float* __restrict__ h, const float* __restrict__ pos,
                           const float* __restrict__ pWl, const float* __restrict__ pWr,
                           double* __restrict__ xls, double* __restrict__ xrs, int N)
{
  int t = threadIdx.x;
  int lane = t&31;
  int n = blockIdx.x*8 + (t>>5);
  if(n>=N) return;
  double sl=0, sr=0;
  #pragma unroll
  for(int q=0;q<4;q++){
    int k = lane + q*32;
    double f = (double)h[(size_t)n*128+k];
    sl += f*(double)pWl[k]; sr += f*(double)pWr[k];
  }
  if(lane<3){
    double f = (double)pos[n*3+lane];
    sl += f*(double)pWl[128+lane]; sr += f*(double)pWr[128+lane];
  }
  for(int o=16;o;o>>=1){ sl += __shfl_down(sl,o,32); sr += __shfl_down(sr,o,32); }
  if(lane==0){ xls[n]=sl; xrs[n]=sr; }
}

// fused score GATv2 with ON-THE-FLY candidate enumeration from the dst-CSR:
// cand(w) = in(w) ∪ in(in(w)); one node per wave, 4 waves/block.
// Pass 1 caches lg and xls[s] in registers (4 candidates/lane, d<=256 covered;
// overflow path recomputes identically) -> pass 2 is pure register math.
__global__ void score_fused2(const int* __restrict__ insrc, const int* __restrict__ dstarts,
                             const float* __restrict__ pos,
                             const double* __restrict__ xls, const double* __restrict__ xrs,
                             const float* __restrict__ pWe, const float* __restrict__ paP,
                             const float* __restrict__ pbP,
                             double* __restrict__ score, int N)
{
  __shared__ int lsAll[4][LSW];
  int wv = threadIdx.x>>6;
  int lane = threadIdx.x&63;
  int w = blockIdx.x*4 + wv;
  bool active = (w<N);
  if(!active) w = N-1;           // clamp: safe reads, no writes
  int* ls = lsAll[wv];
  int r0=dstarts[w], r1=dstarts[w+1]; int din=r1-r0;
  // phase 1: 1-hop candidates
  for(int j=lane;j<din && j<LSW;j+=64) ls[j]=insrc[r0+j];
  __syncthreads();
  // phase 2 (lane-parallel): lane handles in-neighbor (base+lane); exclusive scan of lens -> offsets
  int off = din<LSW? din : LSW;
  for(int base=0; base<din && base<LSW; base+=64){
    int t = base + lane;
    int u0=0, len=0;
    if(t<din && t<LSW){
      int u = ls[t];
      u0 = dstarts[u]; len = dstarts[u+1]-u0;
    }
    int pre = len;
    #pragma unroll
    for(int o=1;o<64;o<<=1){ int v=__shfl_up(pre,o,64); if(lane>=o) pre+=v; }
    int tot = __shfl(pre, 63, 64);
    int myoff = off + pre - len;
    for(int j=0;j<len;j++){ int p=myoff+j; if(p<LSW) ls[p]=insrc[u0+j]; }
    off += tot;
  }
  int d = off<LSW? off : LSW;
  __syncthreads();

  float pd0=pos[w*3], pd1=pos[w*3+1], pd2=pos[w*3+2];
  double w0=(double)pWe[0], w1=(double)pWe[1], w2=(double)pWe[2], pa=(double)paP[0];
  double xrd=xrs[w];
  ull umask=0;
  double lgv[4], xv[4];
  double mx=-1e300, s0=0,s1=0,s2=0; int ucnt=0;
  // cached candidates (j = lane + it*64, it<4)
  #pragma unroll
  for(int it=0; it<4; it++){
    int j = lane + it*64;
    if(j<d){
      int s = ls[j];
      bool uniq = true;
      for(int q=0;q<j;q++) if(ls[q]==s){ uniq=false; break; }
      if(uniq){
        umask |= 1ULL<<it;
        ucnt++;
        double e0=(double)(pd0-pos[s*3]), e1=(double)(pd1-pos[s*3+1]), e2=(double)(pd2-pos[s*3+2]);
        s0+=e0; s1+=e1; s2+=e2;
        double xl = xls[s];
        double lg = leakyd(xl+xrd + e0*w0+e1*w1+e2*w2) * pa;
        lgv[it]=lg; xv[it]=xl;
        mx = fmax(mx, lg);
      }
    }
  }
  // overflow candidates (d>256): original recompute path
  int nb=4;
  for(int j=lane+256; j<d; j+=64, nb++){
    int s = ls[j];
    bool uniq = true;
    for(int q=0;q<j;q++) if(ls[q]==s){ uniq=false; break; }
    if(uniq){
      umask |= 1ULL<<nb;
      ucnt++;
      double e0=(double)(pd0-pos[s*3]), e1=(double)(pd1-pos[s*3+1]), e2=(double)(pd2-pos[s*3+2]);
      s0+=e0; s1+=e1; s2+=e2;
      double lg = leakyd(xls[s]+xrd + e0*w0+e1*w1+e2*w2) * pa;
      mx = fmax(mx, lg);
    }
  }
  for(int o=32;o;o>>=1){
    mx = fmax(mx, __shfl_down(mx,o,64));
    s0 += __shfl_down(s0,o,64);
    s1 += __shfl_down(s1,o,64);
    s2 += __shfl_down(s2,o,64);
    ucnt += __shfl_down(ucnt,o,64);
  }
  mx=__shfl(mx,0,64); s0=__shfl(s0,0,64); s1=__shfl(s1,0,64); s2=__shfl(s2,0,64); ucnt=__shfl(ucnt,0,64);
  double invd = 1.0/(double)(ucnt>0? ucnt : 1);
  double lg_self = leakyd(xls[w]+xrd + (s0*invd)*w0 + (s1*invd)*w1 + (s2*invd)*w2) * pa;
  mx = fmax(mx, lg_self);
  double den=0, acc=0;
  #pragma unroll
  for(int it=0; it<4; it++){
    if((umask>>it)&1ULL){
      double z = exp(lgv[it]-mx);
      den += z; acc += z*xv[it];
    }
  }
  nb=4;
  for(int j=lane+256; j<d; j+=64, nb++){
    if((umask>>nb)&1ULL){
      int s = ls[j];
      double e0=(double)(pd0-pos[s*3]), e1=(double)(pd1-pos[s*3+1]), e2=(double)(pd2-pos[s*3+2]);
      double lg = leakyd(xls[s]+xrd + e0*w0+e1*w1+e2*w2) * pa;
      double z = exp(lg-mx);
      den += z; acc += z*xls[s];
    }
  }
  for(int o=32;o;o>>=1){
    den += __shfl_down(den,o,64);
    acc += __shfl_down(acc,o,64);
  }
  if(lane==0 && active){
    double z = exp(lg_self-mx);
    den += z; acc += z*xls[w];
    score[w] = tanh(acc/den + (double)pbP[0]);
  }
}

// ---------------- top-k: 2-round 21-bit refine select + bucketed ranking ----------------
__global__ void enc_scores(const double* __restrict__ score, int N, ull* __restrict__ ek,
                           int* __restrict__ rank){
  int i = blockIdx.x*256+threadIdx.x; if(i>=N) return;
  ek[i] = encd(score[i]);
  rank[i] = 0x3f3f3f3f;
}
// histogram of 21-bit digit at `shift`, restricted to keys whose bits above shift+21 match selT
__global__ void hist_g(const ull* __restrict__ ek, int N, int shift, const ull* __restrict__ selT,
                       int* __restrict__ hist){
  int i = blockIdx.x*256+threadIdx.x; if(i>=N) return;
  ull key = ek[i];
  if(shift+21 < 64){
    if((key >> (shift+21)) != ((*selT) >> (shift+21))) return;
  }
  atomicAdd(&hist[(int)((key>>shift)&0x1FFFFF)], 1);
}
__global__ void part21(const int* __restrict__ hist, int* __restrict__ partial){
  __shared__ int red[256];
  int b = blockIdx.x;
  int s=0;
  for(int i=threadIdx.x;i<1024;i+=256) s += hist[b*1024+i];
  red[threadIdx.x]=s; __syncthreads();
  for(int o=128;o;o>>=1){ if(threadIdx.x<(unsigned)o) red[threadIdx.x]+=red[threadIdx.x+o]; __syncthreads(); }
  if(threadIdx.x==0) partial[b]=red[0];
}
// find the bin containing the keff-th largest key; update selT (bin at `shift`) and selRB (count strictly above)
__global__ void findbin_g(const int* __restrict__ partial, const int* __restrict__ hist,
                          ull* __restrict__ selT, int* __restrict__ selRB, int k, int shift){
  __shared__ int ts[256];
  __shared__ int cstar, rbase;
  int t=threadIdx.x;
  int keff = k - *selRB;
  int s8[8]; int mysum=0;
  #pragma unroll
  for(int q=0;q<8;q++){ s8[q]=partial[t*8+q]; mysum+=s8[q]; }
  ts[t]=mysum; __syncthreads();
  for(int o=1;o<256;o<<=1){ int u=(t+o<256)? ts[t+o]:0; __syncthreads(); ts[t]+=u; __syncthreads(); }
  int after = (t<255)? ts[t+1] : 0;
  if(ts[t] >= keff && after < keff){
    int run = after;
    for(int q=7;q>=0;q--){
      if(run < keff && run + s8[q] >= keff){ cstar = t*8+q; rbase = run; }
      run += s8[q];
    }
  }
  __syncthreads();
  int cs=cstar, rb=rbase;
  int b4[4]; int ms=0;
  #pragma unroll
  for(int q=0;q<4;q++){ b4[q]=hist[cs*1024 + t*4 + q]; ms+=b4[q]; }
  ts[t]=ms; __syncthreads();
  for(int o=1;o<256;o<<=1){ int u=(t+o<256)? ts[t+o]:0; __syncthreads(); ts[t]+=u; __syncthreads(); }
  int after2 = (t<255)? ts[t+1] : 0;
  if(rb+ts[t] >= keff && rb+after2 < keff){
    int run = rb+after2;
    for(int q=3;q>=0;q--){
      if(run < keff && run + b4[q] >= keff){
        *selT |= ((ull)(cs*1024 + t*4 + q)) << shift;
        *selRB = (k - keff) + run;
      }
      run += b4[q];
    }
  }
}
// ----- bucketed exact ranking of candidates (key >= selT) -----
// bucket digit = complemented top-21 bits => ascending bucket = descending key.
__global__ void rank_hist(const ull* __restrict__ ek, int N, const ull* __restrict__ selT,
                          int* __restrict__ hist){
  int i = blockIdx.x*256+threadIdx.x; if(i>=N) return;
  ull key = ek[i]; if(key < *selT) return;
  int dg = (int)((~key >> 43) & 0x1FFFFF);
  atomicAdd(&hist[dg], 1);
}
// per-1024-bin-block exclusive scan + global block offset -> binstarts; last thread writes total
__global__ void binscan(const int* __restrict__ hist, const int* __restrict__ p2,
                        int* __restrict__ binstarts){
  __shared__ int ts[256];
  int b = blockIdx.x, t = threadIdx.x;
  int v[4]; int s=0;
  #pragma unroll
  for(int q=0;q<4;q++){ v[q]=s; s+=hist[b*1024 + t*4 + q]; }
  ts[t]=s; __syncthreads();
  int mine=s;
  for(int o=1;o<256;o<<=1){ int u=0; if(t>=(unsigned)o) u=ts[t-o]; __syncthreads(); ts[t]+=u; __syncthreads(); }
  int pre = p2[b] + ts[t] - mine;
  #pragma unroll
  for(int q=0;q<4;q++) binstarts[b*1024 + t*4 + q] = pre + v[q];
  if(b==2047 && t==255) binstarts[HBINS] = p2[b] + ts[255];
}
// scatter candidate (key,idx) into bucket-ordered member arrays (consumes hist counts)
__global__ void rank_fill(const ull* __restrict__ ek, int N, const ull* __restrict__ selT,
                          const int* __restrict__ binstarts, int* __restrict__ hist,
                          ull* __restrict__ mkeys, int* __restrict__ midx){
  int i = blockIdx.x*256+threadIdx.x; if(i>=N) return;
  ull key = ek[i]; if(key < *selT) return;
  int dg = (int)((~key >> 43) & 0x1FFFFF);
  int o = atomicSub(&hist[dg], 1) - 1;
  int p = binstarts[dg] + o;
  mkeys[p] = key; midx[p] = i;
}
// exact rank: bucket start + same-bucket (key desc, idx asc) pairwise over STREAMED inline keys
__global__ void rank_within(const int* __restrict__ binstarts,
                            const ull* __restrict__ mkeys, const int* __restrict__ midx,
                            int* __restrict__ rank, int Nmax){
  int m = blockIdx.x*256+threadIdx.x; if(m>=Nmax) return;
  int total = binstarts[HBINS]; if(m>=total) return;
  ull key = mkeys[m]; int ii = midx[m];
  int dg = (int)((~key >> 43) & 0x1FFFFF);
  int s = binstarts[dg], e = binstarts[dg+1];
  int cnt = 0;
  for(int j=s;j<e;j++){
    ull kj = mkeys[j];
    cnt += (kj > key) || (kj == key && midx[j] < ii);
  }
  rank[ii] = s + cnt;
}
__global__ void scatter_perm(const int* __restrict__ rank, int N, int k, int* __restrict__ perm){
  int i = blockIdx.x*256+threadIdx.x; if(i>=N) return;
  int r = rank[i]; if(r<k) perm[r]=i;
}
__global__ void pool_gather(const float* __restrict__ h, const double* __restrict__ score,
                            const int* __restrict__ perm, int k, float* __restrict__ outA){
  int idx = blockIdx.x*256+threadIdx.x; if(idx>=k*32) return;
  int r = idx>>5, g = (idx&31)*4;
  int p = perm[r]; float sc = (float)score[p];
  const float4 x = *(const float4*)(h + (size_t)p*128 + g);
  float4 o; o.x=x.x*sc; o.y=x.y*sc; o.z=x.z*sc; o.w=x.w*sc;
  *(float4*)(outA + (size_t)r*128 + g) = o;
}
__global__ void pos_gather(const float* __restrict__ posc, const int* __restrict__ perm, int k, float* __restrict__ posn){
  int idx = blockIdx.x*256+threadIdx.x; if(idx>=k*3) return;
  int r = idx/3, j = idx-r*3;
  posn[idx] = posc[perm[r]*3+j];
}

// ---------------- filter_adj ----------------
__global__ void filter_flags(const int* __restrict__ es, const int* __restrict__ ed, const int* pE, int Es,
                             const int* __restrict__ rank, int k, int* __restrict__ flags){
  int e = blockIdx.x*256+threadIdx.x; int E = getE(pE,Es); if(e>=E) return;
  flags[e] = (rank[es[e]]<k && rank[ed[e]]<k) ? 1 : 0;
}
__global__ void filter_write(const int* __restrict__ es, const int* __restrict__ ed, const int* pE, int Es,
                             const int* __restrict__ rank, int k, const int* __restrict__ scanout,
                             int* __restrict__ ns, int* __restrict__ nd){
  int e = blockIdx.x*256+threadIdx.x; int E = getE(pE,Es); if(e>=E) return;
  int rs = rank[es[e]], rd = rank[ed[e]];
  if(rs<k && rd<k){ int p = scanout[e]; ns[p]=rs; nd[p]=rd; }
}

// ---------------- output emit ----------------
__global__ void calc_offsets(const int* __restrict__ cnt, long long* __restrict__ offs){
  if(blockIdx.x==0 && threadIdx.x==0){
    long long E1 = cnt[C_E1], E2 = cnt[C_E2];
    long long o = (long long)KK2*128;
    offs[0]=0;
    offs[1]=o; o += 2*E2;
    offs[2]=o; o += 2*E1;
    offs[3]=o; o += 2*(long long)EE0;
    offs[4]=o; o += (long long)KK2*3;
    offs[5]=o; o += (long long)KK1*3;
    offs[6]=o; o += (long long)NN0*3;
    offs[7]=o; o += 3*E2;
    offs[8]=o; o += 3*E1;
    offs[9]=o;
  }
}
__global__ void emit_pe(const int* __restrict__ s, const int* __restrict__ d, const int* pE, int Es,
                        const long long* __restrict__ offs, int oi, float* __restrict__ out){
  int e = blockIdx.x*256+threadIdx.x; int E = getE(pE,Es); if(e>=E) return;
  long long o = offs[oi];
  out[o+e]   = (float)s[e];
  out[o+E+e] = (float)d[e];
}
__global__ void emit_pp(const float* __restrict__ p, int n, const long long* __restrict__ offs, int oi, float* __restrict__ out){
  int i = blockIdx.x*256+threadIdx.x; if(i>=n) return;
  out[offs[oi]+i] = p[i];
}
__global__ void emit_eas(const int* __restrict__ s, const int* __restrict__ d, const int* pE, int Es,
                         const float* __restrict__ pos, const long long* __restrict__ offs, int oi, float* __restrict__ out){
  int e = blockIdx.x*256+threadIdx.x; int E = getE(pE,Es); if(e>=E) return;
  long long o = offs[oi];
  int ss=s[e], dd=d[e];
  out[o+3*e+0] = pos[dd*3+0]-pos[ss*3+0];
  out[o+3*e+1] = pos[dd*3+1]-pos[ss*3+1];
  out[o+3*e+2] = pos[dd*3+2]-pos[ss*3+2];
}

// =======================================================================
extern "C" void kernel_launch(void* const* d_in, const int* in_sizes, int n_in,
                              void* d_out, int out_size, void* d_ws, size_t ws_size,
                              hipStream_t stream)
{
  const float* x    = (const float*)d_in[0];
  const float* yv   = (const float*)d_in[1];
  const float* pos0 = (const float*)d_in[2];
  const int*   ei   = (const int*)d_in[3];
  const float* Wl0  = (const float*)d_in[4];
  const float* Wr0  = (const float*)d_in[5];
  const float* We0  = (const float*)d_in[6];
  const float* a0   = (const float*)d_in[7];
  const float* b0   = (const float*)d_in[8];
  const float* Wls  = (const float*)d_in[9];
  const float* Wrs  = (const float*)d_in[10];
  const float* Wes  = (const float*)d_in[11];
  const float* atts = (const float*)d_in[12];
  const float* bs   = (const float*)d_in[13];
  const float* pWl  = (const float*)d_in[14];
  const float* pWr  = (const float*)d_in[15];
  const float* pWe  = (const float*)d_in[16];
  const float* pa   = (const float*)d_in[17];
  const float* pb   = (const float*)d_in[18];
  const float* linW = (const float*)d_in[19];
  const float* linb = (const float*)d_in[20];
  float* out = (float*)d_out;

  const int* eisrc = ei;
  const int* eidst = ei + EE0;

  char* base = (char*)d_ws; size_t off = 0;
  auto alloc = [&](size_t b)->void*{
    off = (off + 255) & ~(size_t)255;
    void* p = base + off; off += b; return p;
  };
  int*       cnt     = (int*)alloc(64*4);
  long long* offs    = (long long*)alloc(16*8);
  int*       bsums   = (int*)alloc(256*4);
  ull*       sel     = (ull*)alloc(2*8);
  int*       hist    = (int*)alloc((size_t)HBINS*4);
  int*       partial = (int*)alloc(2048*4);
  int*       partial2= (int*)alloc(2304*4);
  double*    xls     = (double*)alloc((size_t)NN0*8);
  double*    xrs     = (double*)alloc((size_t)NN0*8);
  double*    score   = (double*)alloc((size_t)NN0*8);
  ull*       ek      = (ull*)alloc((size_t)NN0*8);
  int*       rank    = (int*)alloc((size_t)NN0*4);
  int*       perm    = (int*)alloc((size_t)NN0*4);
  int*       cursor  = (int*)alloc((size_t)NN0*4);
  int*       ccnt    = (int*)alloc((size_t)NN0*4);
  int*       dstarts = (int*)alloc((size_t)(NN0+1)*4);
  int*       insrc   = (int*)alloc((size_t)EE0*4);
  int*       flags   = (int*)alloc((size_t)EE0*4);
  int*       scanout = (int*)alloc((size_t)(EE0+1)*4);
  int*       eb0s    = (int*)alloc((size_t)EE0*4);
  int*       eb0d    = (int*)alloc((size_t)EE0*4);
  int*       eb1s    = (int*)alloc((size_t)EE0*4);
  int*       eb1d    = (int*)alloc((size_t)EE0*4);
  float*     pos1    = (float*)alloc((size_t)KK1*12);
  float*     pos2    = (float*)alloc((size_t)KK2*12);
  float*     A       = (float*)alloc((size_t)NN0*128*4);
  float*     B       = (float*)alloc((size_t)NN0*128*4);
  float*     h       = (float*)alloc((size_t)NN0*128*4);
  void*      uni     = alloc((size_t)(EE0+FLATMAX)*8);   // union: binstarts+mkeys+midx (ranking)
  if(off > ws_size) return;

  int*    binstarts= (int*)uni;                          // HBINS+1 ints
  ull*    mkeys    = (ull*)((int*)uni + (HBINS + 256));  // up to NN0 ulls, 8B-aligned
  int*    midx     = (int*)(mkeys + NN0);                // up to NN0 ints
  ull*    selT  = sel;
  int*    selRB = (int*)(sel+1);

  hipMemsetAsync(cnt, 0, 64*4, stream);

  auto scan = [&](const int* in, int* sout, const int* pN, int Ns, int* total){
    int nb = CDIV(Ns+1, SCH);
    scan_p1<<<nb,256,0,stream>>>(in,pN,Ns,bsums);
    scan_p2<<<1,256,0,stream>>>(bsums,nb);
    scan_p3<<<nb,256,0,stream>>>(in,sout,pN,Ns,bsums,total);
  };

  auto build_csr_dst = [&](const int* es, const int* ed, const int* pE, int Emax, int N){
    hipMemsetAsync(ccnt,0,(size_t)N*4,stream);
    count_src<<<CDIV(Emax,256),256,0,stream>>>(ed,pE,Emax,ccnt);
    scan(ccnt,dstarts,nullptr,N,nullptr);
    hipMemsetAsync(cursor,0,(size_t)N*4,stream);
    fill_eord<<<CDIV(Emax,256),256,0,stream>>>(es,ed,pE,Emax,dstarts,cursor,insrc);
  };

  auto feat_conv = [&](const float* Wl, const float* Wr, const float* We, const float* att, const float* bias,
                       int N, const float* pcur, bool conv0mode){
    if(conv0mode)
      gemm_k<0,true><<<CDIV(N,32),256,0,stream>>>(x,pcur,yv,Wl,Wr,nullptr,A,B,N);
    else
      gemm_k<1,true><<<CDIV(N,32),256,0,stream>>>(h,pcur,nullptr,Wl,Wr,nullptr,A,B,N);
    feat_fused<<<CDIV(N,4),256,0,stream>>>(insrc,dstarts,A,B,pcur,We,att,bias,h,N);
  };

  auto pool = [&](int l, int N, int k, const int* es, const int* ed, const int* pE, int Emax,
                  const float* pcur, float* pnext, int* ns, int* nd, int eslot){
    // fused score GATv2 (fp64): candidates enumerated on-the-fly from dst-CSR (in ∪ in∘in)
    gemm_score<<<CDIV(N,8),256,0,stream>>>(h,pcur,pWl+l*131,pWr+l*131,xls,xrs,N);
    score_fused2<<<CDIV(N,4),256,0,stream>>>(insrc,dstarts,pcur,xls,xrs,pWe+l*3,pa+l,pb+l,score,N);
    // top-k: 2-round refine select (bits 63..43, then 42..22)
    enc_scores<<<CDIV(N,256),256,0,stream>>>(score,N,ek,rank);
    hipMemsetAsync(sel,0,16,stream);
    for(int r=0;r<2;r++){
      int sh = 43 - 21*r;
      hipMemsetAsync(hist,0,(size_t)HBINS*4,stream);
      hist_g<<<CDIV(N,256),256,0,stream>>>(ek,N,sh,selT,hist);
      part21<<<2048,256,0,stream>>>(hist,partial);
      findbin_g<<<1,256,0,stream>>>(partial,hist,selT,selRB,k,sh);
    }
    // bucketed exact ranking of candidates (inline-key streaming within bucket)
    hipMemsetAsync(hist,0,(size_t)HBINS*4,stream);
    rank_hist  <<<CDIV(N,256),256,0,stream>>>(ek,N,selT,hist);
    part21     <<<2048,256,0,stream>>>(hist,partial);
    scan(partial,partial2,nullptr,2048,nullptr);
    binscan    <<<2048,256,0,stream>>>(hist,partial2,binstarts);
    rank_fill  <<<CDIV(N,256),256,0,stream>>>(ek,N,selT,binstarts,hist,mkeys,midx);
    rank_within<<<CDIV(N,256),256,0,stream>>>(binstarts,mkeys,midx,rank,N);
    scatter_perm<<<CDIV(N,256),256,0,stream>>>(rank,N,k,perm);
    pool_gather<<<CDIV(k*32,256),256,0,stream>>>(h,score,perm,k,A);
    hipMemcpyAsync(h,A,(size_t)k*128*4,hipMemcpyDeviceToDevice,stream);
    pos_gather<<<CDIV(k*3,256),256,0,stream>>>(pcur,perm,k,pnext);
    filter_flags<<<CDIV(Emax,256),256,0,stream>>>(es,ed,pE,Emax,rank,k,flags);
    scan(flags,scanout,pE,Emax,cnt+eslot);
    filter_write<<<CDIV(Emax,256),256,0,stream>>>(es,ed,pE,Emax,rank,k,scanout,ns,nd);
  };

  // ================= pipeline =================
  build_csr_dst(eisrc,eidst,nullptr,EE0, NN0);
  feat_conv(Wl0,Wr0,We0,a0,b0, NN0, pos0, true);
  feat_conv(Wls+0*16768,Wrs+0*16768,Wes+0*384,atts+0*128,bs+0*128, NN0, pos0, false);
  pool(0, NN0, KK1, eisrc,eidst,nullptr,EE0, pos0,pos1, eb0s,eb0d, C_E1);
  build_csr_dst(eb0s,eb0d,cnt+C_E1,EE0, KK1);
  feat_conv(Wls+1*16768,Wrs+1*16768,Wes+1*384,atts+1*128,bs+1*128, KK1, pos1, false);
  pool(1, KK1, KK2, eb0s,eb0d,cnt+C_E1,EE0, pos1,pos2, eb1s,eb1d, C_E2);
  build_csr_dst(eb1s,eb1d,cnt+C_E2,EE0, KK2);
  feat_conv(Wls+2*16768,Wrs+2*16768,Wes+2*384,atts+2*128,bs+2*128, KK2, pos2, false);
  feat_conv(Wls+3*16768,Wrs+3*16768,Wes+3*384,atts+3*128,bs+3*128, KK2, pos2, false);
  gemm_k<2,false><<<CDIV(KK2,32),256,0,stream>>>(h,nullptr,nullptr,linW,nullptr,linb,out,nullptr,KK2);

  calc_offsets<<<1,32,0,stream>>>(cnt,offs);
  emit_pe <<<CDIV(EE0,256),256,0,stream>>>(eb1s,eb1d,cnt+C_E2,EE0,offs,1,out);
  emit_pe <<<CDIV(EE0,256),256,0,stream>>>(eb0s,eb0d,cnt+C_E1,EE0,offs,2,out);
  emit_pe <<<CDIV(EE0,256),256,0,stream>>>(eisrc,eidst,nullptr,EE0,offs,3,out);
  emit_pp <<<CDIV(KK2*3,256),256,0,stream>>>(pos2,KK2*3,offs,4,out);
  emit_pp <<<CDIV(KK1*3,256),256,0,stream>>>(pos1,KK1*3,offs,5,out);
  emit_pp <<<CDIV(NN0*3,256),256,0,stream>>>(pos0,NN0*3,offs,6,out);
  emit_eas<<<CDIV(EE0,256),256,0,stream>>>(eb1s,eb1d,cnt+C_E2,EE0,pos2,offs,7,out);
  emit_eas<<<CDIV(EE0,256),256,0,stream>>>(eb0s,eb0d,cnt+C_E1,EE0,pos1,offs,8,out);
  emit_eas<<<CDIV(EE0,256),256,0,stream>>>(eisrc,eidst,nullptr,EE0,pos0,offs,9,out);
}

// Round 11
// 1801.724 us; speedup vs baseline: 1.2102x; 1.0019x over previous
//
#include <hip/hip_runtime.h>

typedef unsigned long long ull;

#define NN0 80000
#define EE0 480000
#define KK1 40000
#define KK2 20000
#define FLATMAX 8000000
#define SCH 4096
#define CDIV(a,b) (((a)+(b)-1)/(b))
#define HBINS (1<<21)
#define LSW 1024
#define FCAP 512

// counter slots
#define C_E1 2
#define C_E2 3
#define C_M0 5
#define C_M1 6

__device__ __forceinline__ int getE(const int* p, int s){ if(!p) return s; int e=*p; return e<s? e : s; }
__device__ __forceinline__ float leakyf(float x){ return x>0.f? x : 0.2f*x; }
__device__ __forceinline__ double leakyd(double x){ return x>0.0? x : 0.2*x; }
__device__ __forceinline__ float eluf(float x){ return x>0.f? x : (expf(x)-1.f); }

__device__ __forceinline__ ull encd(double f){ ull u=(ull)__double_as_longlong(f); return (u>>63)? ~u : (u|0x8000000000000000ULL); }

// ---------------- GEMM: xl/xr projections ----------------
template<int MODE, bool DUAL>
__global__ void gemm_k(const float* __restrict__ F1, const float* __restrict__ pos,
                       const float* __restrict__ yv,
                       const float* __restrict__ W1, const float* __restrict__ W2,
                       const float* __restrict__ bias,
                       float* __restrict__ O1, float* __restrict__ O2, int N)
{
  const int K = MODE==0? 11 : (MODE==1? 131 : 128);
  __shared__ float lf[32][132];
  int t = threadIdx.x;
  int row0 = blockIdx.x*32;

  if(MODE==0){
    for(int i=t;i<32*11;i+=256){
      int r=i/11, k=i-r*11; int row=row0+r;
      float f=0.f;
      if(row<N) f = (k<5)? F1[(size_t)row*5+k] : (k<8? pos[(size_t)row*3+(k-5)] : yv[0]);
      lf[r][k]=f;
    }
  } else {
    for(int i=t;i<32*32;i+=256){
      int r=i>>5, c4=i&31; int row=row0+r;
      float4 v; v.x=0.f;v.y=0.f;v.z=0.f;v.w=0.f;
      if(row<N) v = *(const float4*)(F1+(size_t)row*128+c4*4);
      *(float4*)(&lf[r][c4*4]) = v;
    }
    if(MODE==1){
      for(int i=t;i<32*3;i+=256){
        int r=i/3, d=i-r*3; int row=row0+r;
        lf[r][128+d] = (row<N)? pos[(size_t)row*3+d] : 0.f;
      }
    }
  }
  __syncthreads();

  int cg = t&31, rg = t>>5;
  int g = cg*4;
  int rbase = rg*4;

  float acc1[4][4]; float acc2[4][4];
  #pragma unroll
  for(int rr=0;rr<4;rr++)
    #pragma unroll
    for(int c=0;c<4;c++){ acc1[rr][c]=0.f; acc2[rr][c]=0.f; }

  #pragma unroll 4
  for(int k=0;k<K;k++){
    float4 w = *(const float4*)(W1 + (size_t)k*128 + g);
    float4 v; v.x=0.f;v.y=0.f;v.z=0.f;v.w=0.f;
    if(DUAL) v = *(const float4*)(W2 + (size_t)k*128 + g);
    #pragma unroll
    for(int rr=0;rr<4;rr++){
      float f = lf[rbase+rr][k];
      acc1[rr][0]+=f*w.x; acc1[rr][1]+=f*w.y; acc1[rr][2]+=f*w.z; acc1[rr][3]+=f*w.w;
      if(DUAL){ acc2[rr][0]+=f*v.x; acc2[rr][1]+=f*v.y; acc2[rr][2]+=f*v.z; acc2[rr][3]+=f*v.w; }
    }
  }

  float4 bb; bb.x=0.f;bb.y=0.f;bb.z=0.f;bb.w=0.f;
  if(bias) bb = *(const float4*)(bias+g);
  #pragma unroll
  for(int rr=0;rr<4;rr++){
    int row = row0 + rbase + rr;
    if(row<N){
      float4 r1; r1.x=acc1[rr][0]+bb.x; r1.y=acc1[rr][1]+bb.y; r1.z=acc1[rr][2]+bb.z; r1.w=acc1[rr][3]+bb.w;
      *(float4*)(O1+(size_t)row*128+g) = r1;
      if(DUAL){
        float4 r2; r2.x=acc2[rr][0]; r2.y=acc2[rr][1]; r2.z=acc2[rr][2]; r2.w=acc2[rr][3];
        *(float4*)(O2+(size_t)row*128+g) = r2;
      }
    }
  }
}

// ---------------- multi-block exclusive scan (generic) ----------------
__global__ void scan_p1(const int* __restrict__ in, const int* pN, int Ns, int* __restrict__ bsums){
  __shared__ int red[256];
  int n = getE(pN,Ns);
  int base = blockIdx.x*SCH;
  int s=0;
  for(int i=base+threadIdx.x; i<base+SCH; i+=256) if(i<n) s+=in[i];
  red[threadIdx.x]=s; __syncthreads();
  for(int o=128;o;o>>=1){ if(threadIdx.x<(unsigned)o) red[threadIdx.x]+=red[threadIdx.x+o]; __syncthreads(); }
  if(threadIdx.x==0) bsums[blockIdx.x]=red[0];
}
__global__ void scan_p2(int* bsums, int nb){
  __shared__ int lds[256];
  int t=threadIdx.x;
  int v = (t<nb)? bsums[t] : 0;
  lds[t]=v; __syncthreads();
  for(int o=1;o<256;o<<=1){ int u=0; if(t>=o) u=lds[t-o]; __syncthreads(); lds[t]+=u; __syncthreads(); }
  if(t<nb) bsums[t]=lds[t]-v;
}
__global__ void scan_p3(const int* __restrict__ in, int* __restrict__ out, const int* pN, int Ns,
                        const int* __restrict__ bsums, int* total){
  __shared__ int tsum[256];
  int n = getE(pN,Ns);
  int base = blockIdx.x*SCH + threadIdx.x*16;
  int v[16]; int s=0;
  #pragma unroll
  for(int q=0;q<16;q++){ int i=base+q; int xv=(i<n)? in[i]:0; v[q]=s; s+=xv; }
  tsum[threadIdx.x]=s; __syncthreads();
  int mine=s;
  for(int o=1;o<256;o<<=1){ int u=0; if(threadIdx.x>=(unsigned)o) u=tsum[threadIdx.x-o]; __syncthreads(); tsum[threadIdx.x]+=u; __syncthreads(); }
  int pre = bsums[blockIdx.x] + tsum[threadIdx.x] - mine;
  #pragma unroll
  for(int q=0;q<16;q++){
    int i=base+q;
    if(i<=n){
      int val = pre+v[q];
      out[i]=val;
      if(i==n && total) *total=val;
    }
  }
}

// ---------------- fused filter_adj scan: flags computed inline from rank ----------------
__global__ void fscan_p1(const int* __restrict__ es, const int* __restrict__ ed, const int* pE, int Es,
                         const int* __restrict__ rank, int k, int* __restrict__ bsums){
  __shared__ int red[256];
  int n = getE(pE,Es);
  int base = blockIdx.x*SCH;
  int s=0;
  for(int i=base+threadIdx.x; i<base+SCH; i+=256)
    if(i<n) s += (rank[es[i]]<k && rank[ed[i]]<k) ? 1 : 0;
  red[threadIdx.x]=s; __syncthreads();
  for(int o=128;o;o>>=1){ if(threadIdx.x<(unsigned)o) red[threadIdx.x]+=red[threadIdx.x+o]; __syncthreads(); }
  if(threadIdx.x==0) bsums[blockIdx.x]=red[0];
}
__global__ void fscan_p3(const int* __restrict__ es, const int* __restrict__ ed, const int* pE, int Es,
                         const int* __restrict__ rank, int k, const int* __restrict__ bsums,
                         int* __restrict__ ns, int* __restrict__ nd, int* total){
  __shared__ int tsum[256];
  int n = getE(pE,Es);
  int base = blockIdx.x*SCH + threadIdx.x*16;
  int v[16]; int rs[16], rd[16]; unsigned fm=0; int s=0;
  #pragma unroll
  for(int q=0;q<16;q++){
    int i=base+q; int xv=0;
    if(i<n){
      int a=rank[es[i]], b=rank[ed[i]];
      rs[q]=a; rd[q]=b;
      if(a<k && b<k){ xv=1; fm |= 1u<<q; }
    }
    v[q]=s; s+=xv;
  }
  tsum[threadIdx.x]=s; __syncthreads();
  int mine=s;
  for(int o=1;o<256;o<<=1){ int u=0; if(threadIdx.x>=(unsigned)o) u=tsum[threadIdx.x-o]; __syncthreads(); tsum[threadIdx.x]+=u; __syncthreads(); }
  int pre = bsums[blockIdx.x] + tsum[threadIdx.x] - mine;
  #pragma unroll
  for(int q=0;q<16;q++){
    int i=base+q;
    if(i<n && ((fm>>q)&1u)){
      int p = pre+v[q];
      ns[p]=rs[q]; nd[p]=rd[q];
    }
    if(i==n && total) *total = pre+v[q];
  }
}

// ---------------- CSR builders ----------------
__global__ void count_src(const int* __restrict__ es, const int* pE, int Es, int* cnts){
  int e = blockIdx.x*256+threadIdx.x; int E = getE(pE,Es); if(e>=E) return;
  atomicAdd(&cnts[es[e]], 1);
}
__global__ void fill_eord(const int* __restrict__ es, const int* __restrict__ ed, const int* pE, int Es,
                          const int* __restrict__ dstarts, int* cursor, int* insrc){
  int e = blockIdx.x*256+threadIdx.x; int E = getE(pE,Es); if(e>=E) return;
  int d = ed[e];
  int p = dstarts[d] + atomicAdd(&cursor[d],1);
  insrc[p] = es[e];
}

// ---------------- FUSED feature GATv2 (fp32): logits + softmax-accumulate ----------------
__global__ void feat_fused(const int* __restrict__ insrc, const int* __restrict__ dstarts,
                           const float* __restrict__ A, const float* __restrict__ B,
                           const float* __restrict__ pos,
                           const float* __restrict__ We, const float* __restrict__ att,
                           const float* __restrict__ bias, float* __restrict__ h, int N)
{
  __shared__ float lgAll[4][FCAP];
  int wv = threadIdx.x>>6, lane = threadIdx.x&63;
  int w = blockIdx.x*4 + wv;
  bool active = (w<N);
  if(!active) w = N-1;
  float* lg = lgAll[wv];
  int r0=dstarts[w], r1=dstarts[w+1]; int din=r1-r0;
  int c=lane, c2=lane+64;
  float B0 = B[(size_t)w*128+c], B1 = B[(size_t)w*128+c2];
  float We0c=We[c], We1c=We[128+c], We2c=We[256+c];
  float We0d=We[c2], We1d=We[128+c2], We2d=We[256+c2];
  float attc=att[c], attd=att[c2];
  float pw0=pos[w*3], pw1=pos[w*3+1], pw2=pos[w*3+2];

  float l0=0,l1=0,l2=0;
  for(int j=0;j<din;j++){
    int s = insrc[r0+j];
    float e0=pw0-pos[s*3], e1=pw1-pos[s*3+1], e2=pw2-pos[s*3+2];
    l0+=e0; l1+=e1; l2+=e2;
    float a0=A[(size_t)s*128+c], a1=A[(size_t)s*128+c2];
    float m1 = a0 + B0 + e0*We0c + e1*We1c + e2*We2c;
    float m2 = a1 + B1 + e0*We0d + e1*We1d + e2*We2d;
    float p = leakyf(m1)*attc + leakyf(m2)*attd;
    for(int o=32;o;o>>=1) p += __shfl_down(p,o,64);
    if(lane==0 && j<FCAP) lg[j]=p;
  }
  float inv = 1.f/fmaxf((float)din, 1.f);
  float q0=l0*inv, q1=l1*inv, q2=l2*inv;
  float a0w=A[(size_t)w*128+c], a1w=A[(size_t)w*128+c2];
  float pself;
  {
    float m1 = a0w + B0 + q0*We0c + q1*We1c + q2*We2c;
    float m2 = a1w + B1 + q0*We0d + q1*We1d + q2*We2d;
    float p = leakyf(m1)*attc + leakyf(m2)*attd;
    for(int o=32;o;o>>=1) p += __shfl_down(p,o,64);
    pself = __shfl(p,0,64);
  }
  float mx = pself;
  int dc = din<FCAP? din : FCAP;
  for(int j=lane;j<dc;j+=64) mx = fmaxf(mx, lg[j]);
  for(int o=32;o;o>>=1) mx = fmaxf(mx, __shfl_down(mx,o,64));
  mx = __shfl(mx,0,64);
  for(int j=FCAP;j<din;j++){
    int s = insrc[r0+j];
    float e0=pw0-pos[s*3], e1=pw1-pos[s*3+1], e2=pw2-pos[s*3+2];
    float a0=A[(size_t)s*128+c], a1=A[(size_t)s*128+c2];
    float m1 = a0 + B0 + e0*We0c + e1*We1c + e2*We2c;
    float m2 = a1 + B1 + e0*We0d + e1*We1d + e2*We2d;
    float p = leakyf(m1)*attc + leakyf(m2)*attd;
    for(int o=32;o;o>>=1) p += __shfl_down(p,o,64);
    p = __shfl(p,0,64);
    mx = fmaxf(mx, p);
  }

  float denom=0.f, acc0=0.f, acc1=0.f;
  for(int j=0;j<din;j++){
    int s = insrc[r0+j];
    float lgj;
    if(j<FCAP) lgj = lg[j];
    else {
      float e0=pw0-pos[s*3], e1=pw1-pos[s*3+1], e2=pw2-pos[s*3+2];
      float a0=A[(size_t)s*128+c], a1=A[(size_t)s*128+c2];
      float m1 = a0 + B0 + e0*We0c + e1*We1c + e2*We2c;
      float m2 = a1 + B1 + e0*We0d + e1*We1d + e2*We2d;
      float p = leakyf(m1)*attc + leakyf(m2)*attd;
      for(int o=32;o;o>>=1) p += __shfl_down(p,o,64);
      lgj = __shfl(p,0,64);
    }
    float z = expf(lgj - mx);
    denom += z;
    acc0 += z*A[(size_t)s*128+c];
    acc1 += z*A[(size_t)s*128+c2];
  }
  {
    float z = expf(pself - mx);
    denom += z;
    acc0 += z*a0w; acc1 += z*a1w;
  }
  float iv = 1.f/denom;
  float b0v=bias[c], b1v=bias[c2];
  acc0 = eluf(acc0*iv + b0v); acc1 = eluf(acc1*iv + b1v);
  if(active){
    h[(size_t)w*128+c ] = acc0;
    h[(size_t)w*128+c2] = acc1;
  }
}

// ---------------- score GATv2 (fp64) ----------------
__global__ void gemm_score(const float* __restrict__ h, const float* __restrict__ pos,
                           const float* __restrict__ pWl, const float* __restrict__ pWr,
                           double* __restrict__ xls, double* __restrict__ xrs, int N)
{
  int t = threadIdx.x;
  int lane = t&31;
  int n = blockIdx.x*8 + (t>>5);
  if(n>=N) return;
  double sl=0, sr=0;
  #pragma unroll
  for(int q=0;q<4;q++){
    int k = lane + q*32;
    double f = (double)h[(size_t)n*128+k];
    sl += f*(double)pWl[k]; sr += f*(double)pWr[k];
  }
  if(lane<3){
    double f = (double)pos[n*3+lane];
    sl += f*(double)pWl[128+lane]; sr += f*(double)pWr[128+lane];
  }
  for(int o=16;o;o>>=1){ sl += __shfl_down(sl,o,32); sr += __shfl_down(sr,o,32); }
  if(lane==0){ xls[n]=sl; xrs[n]=sr; }
}

// fused score GATv2 (writes score AND encoded key ek directly)
__global__ void score_fused2(const int* __restrict__ insrc, const int* __restrict__ dstarts,
                             const float* __restrict__ pos,
                             const double* __restrict__ xls, const double* __restrict__ xrs,
                             const float* __restrict__ pWe, const float* __restrict__ paP,
                             const float* __restrict__ pbP,
                             double* __restrict__ score, ull* __restrict__ ek, int N)
{
  __shared__ int lsAll[4][LSW];
  int wv = threadIdx.x>>6;
  int lane = threadIdx.x&63;
  int w = blockIdx.x*4 + wv;
  bool active = (w<N);
  if(!active) w = N-1;
  int* ls = lsAll[wv];
  int r0=dstarts[w], r1=dstarts[w+1]; int din=r1-r0;
  for(int j=lane;j<din && j<LSW;j+=64) ls[j]=insrc[r0+j];
  __syncthreads();
  int off = din<LSW? din : LSW;
  for(int base=0; base<din && base<LSW; base+=64){
    int t = base + lane;
    int u0=0, len=0;
    if(t<din && t<LSW){
      int u = ls[t];
      u0 = dstarts[u]; len = dstarts[u+1]-u0;
    }
    int pre = len;
    #pragma unroll
    for(int o=1;o<64;o<<=1){ int v=__shfl_up(pre,o,64); if(lane>=o) pre+=v; }
    int tot = __shfl(pre, 63, 64);
    int myoff = off + pre - len;
    for(int j=0;j<len;j++){ int p=myoff+j; if(p<LSW) ls[p]=insrc[u0+j]; }
    off += tot;
  }
  int d = off<LSW? off : LSW;
  __syncthreads();

  float pd0=pos[w*3], pd1=pos[w*3+1], pd2=pos[w*3+2];
  double w0=(double)pWe[0], w1=(double)pWe[1], w2=(double)pWe[2], pa=(double)paP[0];
  double xrd=xrs[w];
  ull umask=0;
  double lgv[4], xv[4];
  double mx=-1e300, s0=0,s1=0,s2=0; int ucnt=0;
  #pragma unroll
  for(int it=0; it<4; it++){
    int j = lane + it*64;
    if(j<d){
      int s = ls[j];
      bool uniq = true;
      for(int q=0;q<j;q++) if(ls[q]==s){ uniq=false; break; }
      if(uniq){
        umask |= 1ULL<<it;
        ucnt++;
        double e0=(double)(pd0-pos[s*3]), e1=(double)(pd1-pos[s*3+1]), e2=(double)(pd2-pos[s*3+2]);
        s0+=e0; s1+=e1; s2+=e2;
        double xl = xls[s];
        double lg = leakyd(xl+xrd + e0*w0+e1*w1+e2*w2) * pa;
        lgv[it]=lg; xv[it]=xl;
        mx = fmax(mx, lg);
      }
    }
  }
  int nb=4;
  for(int j=lane+256; j<d; j+=64, nb++){
    int s = ls[j];
    bool uniq = true;
    for(int q=0;q<j;q++) if(ls[q]==s){ uniq=false; break; }
    if(uniq){
      umask |= 1ULL<<nb;
      ucnt++;
      double e0=(double)(pd0-pos[s*3]), e1=(double)(pd1-pos[s*3+1]), e2=(double)(pd2-pos[s*3+2]);
      s0+=e0; s1+=e1; s2+=e2;
      double lg = leakyd(xls[s]+xrd + e0*w0+e1*w1+e2*w2) * pa;
      mx = fmax(mx, lg);
    }
  }
  for(int o=32;o;o>>=1){
    mx = fmax(mx, __shfl_down(mx,o,64));
    s0 += __shfl_down(s0,o,64);
    s1 += __shfl_down(s1,o,64);
    s2 += __shfl_down(s2,o,64);
    ucnt += __shfl_down(ucnt,o,64);
  }
  mx=__shfl(mx,0,64); s0=__shfl(s0,0,64); s1=__shfl(s1,0,64); s2=__shfl(s2,0,64); ucnt=__shfl(ucnt,0,64);
  double invd = 1.0/(double)(ucnt>0? ucnt : 1);
  double lg_self = leakyd(xls[w]+xrd + (s0*invd)*w0 + (s1*invd)*w1 + (s2*invd)*w2) * pa;
  mx = fmax(mx, lg_self);
  double den=0, acc=0;
  #pragma unroll
  for(int it=0; it<4; it++){
    if((umask>>it)&1ULL){
      double z = exp(lgv[it]-mx);
      den += z; acc += z*xv[it];
    }
  }
  nb=4;
  for(int j=lane+256; j<d; j+=64, nb++){
    if((umask>>nb)&1ULL){
      int s = ls[j];
      double e0=(double)(pd0-pos[s*3]), e1=(double)(pd1-pos[s*3+1]), e2=(double)(pd2-pos[s*3+2]);
      double lg = leakyd(xls[s]+xrd + e0*w0+e1*w1+e2*w2) * pa;
      double z = exp(lg-mx);
      den += z; acc += z*xls[s];
    }
  }
  for(int o=32;o;o>>=1){
    den += __shfl_down(den,o,64);
    acc += __shfl_down(acc,o,64);
  }
  if(lane==0 && active){
    double z = exp(lg_self-mx);
    den += z; acc += z*xls[w];
    double sc = tanh(acc/den + (double)pbP[0]);
    score[w] = sc;
    ek[w] = encd(sc);
  }
}

// ---------------- top-k: 2-round 21-bit refine select + bucketed ranking ----------------
__global__ void hist_g(const ull* __restrict__ ek, int N, int shift, const ull* __restrict__ selT,
                       int* __restrict__ hist){
  int i = blockIdx.x*256+threadIdx.x; if(i>=N) return;
  ull key = ek[i];
  if(shift+21 < 64){
    if((key >> (shift+21)) != ((*selT) >> (shift+21))) return;
  }
  atomicAdd(&hist[(int)((key>>shift)&0x1FFFFF)], 1);
}
__global__ void part21(const int* __restrict__ hist, int* __restrict__ partial){
  __shared__ int red[256];
  int b = blockIdx.x;
  int s=0;
  for(int i=threadIdx.x;i<1024;i+=256) s += hist[b*1024+i];
  red[threadIdx.x]=s; __syncthreads();
  for(int o=128;o;o>>=1){ if(threadIdx.x<(unsigned)o) red[threadIdx.x]+=red[threadIdx.x+o]; __syncthreads(); }
  if(threadIdx.x==0) partial[b]=red[0];
}
__global__ void findbin_g(const int* __restrict__ partial, const int* __restrict__ hist,
                          ull* __restrict__ selT, int* __restrict__ selRB, int k, int shift){
  __shared__ int ts[256];
  __shared__ int cstar, rbase;
  int t=threadIdx.x;
  int keff = k - *selRB;
  int s8[8]; int mysum=0;
  #pragma unroll
  for(int q=0;q<8;q++){ s8[q]=partial[t*8+q]; mysum+=s8[q]; }
  ts[t]=mysum; __syncthreads();
  for(int o=1;o<256;o<<=1){ int u=(t+o<256)? ts[t+o]:0; __syncthreads(); ts[t]+=u; __syncthreads(); }
  int after = (t<255)? ts[t+1] : 0;
  if(ts[t] >= keff && after < keff){
    int run = after;
    for(int q=7;q>=0;q--){
      if(run < keff && run + s8[q] >= keff){ cstar = t*8+q; rbase = run; }
      run += s8[q];
    }
  }
  __syncthreads();
  int cs=cstar, rb=rbase;
  int b4[4]; int ms=0;
  #pragma unroll
  for(int q=0;q<4;q++){ b4[q]=hist[cs*1024 + t*4 + q]; ms+=b4[q]; }
  ts[t]=ms; __syncthreads();
  for(int o=1;o<256;o<<=1){ int u=(t+o<256)? ts[t+o]:0; __syncthreads(); ts[t]+=u; __syncthreads(); }
  int after2 = (t<255)? ts[t+1] : 0;
  if(rb+ts[t] >= keff && rb+after2 < keff){
    int run = rb+after2;
    for(int q=3;q>=0;q--){
      if(run < keff && run + b4[q] >= keff){
        *selT |= ((ull)(cs*1024 + t*4 + q)) << shift;
        *selRB = (k - keff) + run;
      }
      run += b4[q];
    }
  }
}
__global__ void rank_hist(const ull* __restrict__ ek, int N, const ull* __restrict__ selT,
                          int* __restrict__ hist){
  int i = blockIdx.x*256+threadIdx.x; if(i>=N) return;
  ull key = ek[i]; if(key < *selT) return;
  int dg = (int)((~key >> 43) & 0x1FFFFF);
  atomicAdd(&hist[dg], 1);
}
__global__ void binscan(const int* __restrict__ hist, const int* __restrict__ p2,
                        int* __restrict__ binstarts){
  __shared__ int ts[256];
  int b = blockIdx.x, t = threadIdx.x;
  int v[4]; int s=0;
  #pragma unroll
  for(int q=0;q<4;q++){ v[q]=s; s+=hist[b*1024 + t*4 + q]; }
  ts[t]=s; __syncthreads();
  int mine=s;
  for(int o=1;o<256;o<<=1){ int u=0; if(t>=(unsigned)o) u=ts[t-o]; __syncthreads(); ts[t]+=u; __syncthreads(); }
  int pre = p2[b] + ts[t] - mine;
  #pragma unroll
  for(int q=0;q<4;q++) binstarts[b*1024 + t*4 + q] = pre + v[q];
  if(b==2047 && t==255) binstarts[HBINS] = p2[b] + ts[255];
}
__global__ void rank_fill(const ull* __restrict__ ek, int N, const ull* __restrict__ selT,
                          const int* __restrict__ binstarts, int* __restrict__ hist,
                          ull* __restrict__ mkeys, int* __restrict__ midx){
  int i = blockIdx.x*256+threadIdx.x; if(i>=N) return;
  ull key = ek[i]; if(key < *selT) return;
  int dg = (int)((~key >> 43) & 0x1FFFFF);
  int o = atomicSub(&hist[dg], 1) - 1;
  int p = binstarts[dg] + o;
  mkeys[p] = key; midx[p] = i;
}
__global__ void rank_within(const int* __restrict__ binstarts,
                            const ull* __restrict__ mkeys, const int* __restrict__ midx,
                            int* __restrict__ rank, int Nmax){
  int m = blockIdx.x*256+threadIdx.x; if(m>=Nmax) return;
  int total = binstarts[HBINS]; if(m>=total) return;
  ull key = mkeys[m]; int ii = midx[m];
  int dg = (int)((~key >> 43) & 0x1FFFFF);
  int s = binstarts[dg], e = binstarts[dg+1];
  int cnt = 0;
  for(int j=s;j<e;j++){
    ull kj = mkeys[j];
    cnt += (kj > key) || (kj == key && midx[j] < ii);
  }
  rank[ii] = s + cnt;
}
__global__ void scatter_perm(const int* __restrict__ rank, int N, int k, int* __restrict__ perm){
  int i = blockIdx.x*256+threadIdx.x; if(i>=N) return;
  int r = rank[i]; if(r<k) perm[r]=i;
}
__global__ void pool_gather(const float* __restrict__ h, const double* __restrict__ score,
                            const int* __restrict__ perm, int k, float* __restrict__ outA){
  int idx = blockIdx.x*256+threadIdx.x; if(idx>=k*32) return;
  int r = idx>>5, g = (idx&31)*4;
  int p = perm[r]; float sc = (float)score[p];
  const float4 x = *(const float4*)(h + (size_t)p*128 + g);
  float4 o; o.x=x.x*sc; o.y=x.y*sc; o.z=x.z*sc; o.w=x.w*sc;
  *(float4*)(outA + (size_t)r*128 + g) = o;
}
__global__ void pos_gather(const float* __restrict__ posc, const int* __restrict__ perm, int k, float* __restrict__ posn){
  int idx = blockIdx.x*256+threadIdx.x; if(idx>=k*3) return;
  int r = idx/3, j = idx-r*3;
  posn[idx] = posc[perm[r]*3+j];
}

// ---------------- output emit (fused over 3 levels via blockIdx.y) ----------------
__global__ void calc_offsets(const int* __restrict__ cnt, long long* __restrict__ offs){
  if(blockIdx.x==0 && threadIdx.x==0){
    long long E1 = cnt[C_E1], E2 = cnt[C_E2];
    long long o = (long long)KK2*128;
    offs[0]=0;
    offs[1]=o; o += 2*E2;
    offs[2]=o; o += 2*E1;
    offs[3]=o; o += 2*(long long)EE0;
    offs[4]=o; o += (long long)KK2*3;
    offs[5]=o; o += (long long)KK1*3;
    offs[6]=o; o += (long long)NN0*3;
    offs[7]=o; o += 3*E2;
    offs[8]=o; o += 3*E1;
    offs[9]=o;
  }
}
__global__ void emit3_pe(const int* __restrict__ s2, const int* __restrict__ d2, const int* pE2,
                         const int* __restrict__ s1, const int* __restrict__ d1, const int* pE1,
                         const int* __restrict__ s0, const int* __restrict__ d0,
                         const long long* __restrict__ offs, float* __restrict__ out){
  int e = blockIdx.x*256+threadIdx.x;
  int L = blockIdx.y;
  const int* s; const int* d; int E; int oi;
  if(L==0){ s=s2; d=d2; E=getE(pE2,EE0); oi=1; }
  else if(L==1){ s=s1; d=d1; E=getE(pE1,EE0); oi=2; }
  else { s=s0; d=d0; E=EE0; oi=3; }
  if(e>=E) return;
  long long o = offs[oi];
  out[o+e]   = (float)s[e];
  out[o+E+e] = (float)d[e];
}
__global__ void emit3_pp(const float* __restrict__ p2, const float* __restrict__ p1,
                         const float* __restrict__ p0,
                         const long long* __restrict__ offs, float* __restrict__ out){
  int i = blockIdx.x*256+threadIdx.x;
  int L = blockIdx.y;
  const float* p; int n; int oi;
  if(L==0){ p=p2; n=KK2*3; oi=4; }
  else if(L==1){ p=p1; n=KK1*3; oi=5; }
  else { p=p0; n=NN0*3; oi=6; }
  if(i>=n) return;
  out[offs[oi]+i] = p[i];
}
__global__ void emit3_eas(const int* __restrict__ s2, const int* __restrict__ d2, const int* pE2, const float* __restrict__ q2,
                          const int* __restrict__ s1, const int* __restrict__ d1, const int* pE1, const float* __restrict__ q1,
                          const int* __restrict__ s0, const int* __restrict__ d0, const float* __restrict__ q0,
                          const long long* __restrict__ offs, float* __restrict__ out){
  int e = blockIdx.x*256+threadIdx.x;
  int L = blockIdx.y;
  const int* s; const int* d; const float* pos; int E; int oi;
  if(L==0){ s=s2; d=d2; pos=q2; E=getE(pE2,EE0); oi=7; }
  else if(L==1){ s=s1; d=d1; pos=q1; E=getE(pE1,EE0); oi=8; }
  else { s=s0; d=d0; pos=q0; E=EE0; oi=9; }
  if(e>=E) return;
  long long o = offs[oi];
  int ss=s[e], dd=d[e];
  out[o+3*e+0] = pos[dd*3+0]-pos[ss*3+0];
  out[o+3*e+1] = pos[dd*3+1]-pos[ss*3+1];
  out[o+3*e+2] = pos[dd*3+2]-pos[ss*3+2];
}

// =======================================================================
extern "C" void kernel_launch(void* const* d_in, const int* in_sizes, int n_in,
                              void* d_out, int out_size, void* d_ws, size_t ws_size,
                              hipStream_t stream)
{
  const float* x    = (const float*)d_in[0];
  const float* yv   = (const float*)d_in[1];
  const float* pos0 = (const float*)d_in[2];
  const int*   ei   = (const int*)d_in[3];
  const float* Wl0  = (const float*)d_in[4];
  const float* Wr0  = (const float*)d_in[5];
  const float* We0  = (const float*)d_in[6];
  const float* a0   = (const float*)d_in[7];
  const float* b0   = (const float*)d_in[8];
  const float* Wls  = (const float*)d_in[9];
  const float* Wrs  = (const float*)d_in[10];
  const float* Wes  = (const float*)d_in[11];
  const float* atts = (const float*)d_in[12];
  const float* bs   = (const float*)d_in[13];
  const float* pWl  = (const float*)d_in[14];
  const float* pWr  = (const float*)d_in[15];
  const float* pWe  = (const float*)d_in[16];
  const float* pa   = (const float*)d_in[17];
  const float* pb   = (const float*)d_in[18];
  const float* linW = (const float*)d_in[19];
  const float* linb = (const float*)d_in[20];
  float* out = (float*)d_out;

  const int* eisrc = ei;
  const int* eidst = ei + EE0;

  char* base = (char*)d_ws; size_t off = 0;
  auto alloc = [&](size_t b)->void*{
    off = (off + 255) & ~(size_t)255;
    void* p = base + off; off += b; return p;
  };
  int*       cnt     = (int*)alloc(64*4);
  long long* offs    = (long long*)alloc(16*8);
  int*       bsums   = (int*)alloc(256*4);
  ull*       sel     = (ull*)alloc(2*8);
  int*       hist    = (int*)alloc((size_t)HBINS*4);
  int*       partial = (int*)alloc(2048*4);
  int*       partial2= (int*)alloc(2304*4);
  double*    xls     = (double*)alloc((size_t)NN0*8);
  double*    xrs     = (double*)alloc((size_t)NN0*8);
  double*    score   = (double*)alloc((size_t)NN0*8);
  ull*       ek      = (ull*)alloc((size_t)NN0*8);
  int*       rank    = (int*)alloc((size_t)NN0*4);
  int*       perm    = (int*)alloc((size_t)NN0*4);
  int*       cursor  = (int*)alloc((size_t)NN0*4);
  int*       ccnt    = (int*)alloc((size_t)NN0*4);
  int*       dstarts = (int*)alloc((size_t)(NN0+1)*4);
  int*       insrc   = (int*)alloc((size_t)EE0*4);
  int*       eb0s    = (int*)alloc((size_t)EE0*4);
  int*       eb0d    = (int*)alloc((size_t)EE0*4);
  int*       eb1s    = (int*)alloc((size_t)EE0*4);
  int*       eb1d    = (int*)alloc((size_t)EE0*4);
  float*     pos1    = (float*)alloc((size_t)KK1*12);
  float*     pos2    = (float*)alloc((size_t)KK2*12);
  float*     A       = (float*)alloc((size_t)NN0*128*4);
  float*     B       = (float*)alloc((size_t)NN0*128*4);
  float*     h       = (float*)alloc((size_t)NN0*128*4);
  void*      uni     = alloc((size_t)(EE0+FLATMAX)*8);   // union: binstarts+mkeys+midx (ranking)
  if(off > ws_size) return;

  int*    binstarts= (int*)uni;
  ull*    mkeys    = (ull*)((int*)uni + (HBINS + 256));
  int*    midx     = (int*)(mkeys + NN0);
  ull*    selT  = sel;
  int*    selRB = (int*)(sel+1);

  hipMemsetAsync(cnt, 0, 64*4, stream);
  hipMemsetAsync(hist, 0, (size_t)HBINS*4, stream);   // upfront; rank_fill restores zeros each pool

  auto scan = [&](const int* in, int* sout, const int* pN, int Ns, int* total){
    int nb = CDIV(Ns+1, SCH);
    scan_p1<<<nb,256,0,stream>>>(in,pN,Ns,bsums);
    scan_p2<<<1,256,0,stream>>>(bsums,nb);
    scan_p3<<<nb,256,0,stream>>>(in,sout,pN,Ns,bsums,total);
  };

  auto build_csr_dst = [&](const int* es, const int* ed, const int* pE, int Emax, int N){
    hipMemsetAsync(ccnt,0,(size_t)N*4,stream);
    count_src<<<CDIV(Emax,256),256,0,stream>>>(ed,pE,Emax,ccnt);
    scan(ccnt,dstarts,nullptr,N,nullptr);
    hipMemsetAsync(cursor,0,(size_t)N*4,stream);
    fill_eord<<<CDIV(Emax,256),256,0,stream>>>(es,ed,pE,Emax,dstarts,cursor,insrc);
  };

  auto feat_conv = [&](const float* Wl, const float* Wr, const float* We, const float* att, const float* bias,
                       int N, const float* pcur, bool conv0mode){
    if(conv0mode)
      gemm_k<0,true><<<CDIV(N,32),256,0,stream>>>(x,pcur,yv,Wl,Wr,nullptr,A,B,N);
    else
      gemm_k<1,true><<<CDIV(N,32),256,0,stream>>>(h,pcur,nullptr,Wl,Wr,nullptr,A,B,N);
    feat_fused<<<CDIV(N,4),256,0,stream>>>(insrc,dstarts,A,B,pcur,We,att,bias,h,N);
  };

  auto pool = [&](int l, int N, int k, const int* es, const int* ed, const int* pE, int Emax,
                  const float* pcur, float* pnext, int* ns, int* nd, int eslot){
    hipMemsetAsync(rank, 0x3f, (size_t)N*4, stream);     // rank init (0x3f3f3f3f)
    gemm_score<<<CDIV(N,8),256,0,stream>>>(h,pcur,pWl+l*131,pWr+l*131,xls,xrs,N);
    score_fused2<<<CDIV(N,4),256,0,stream>>>(insrc,dstarts,pcur,xls,xrs,pWe+l*3,pa+l,pb+l,score,ek,N);
    // top-k: 2-round refine select (hist is all-zero entering round 0)
    hipMemsetAsync(sel,0,16,stream);
    for(int r=0;r<2;r++){
      int sh = 43 - 21*r;
      if(r>0) hipMemsetAsync(hist,0,(size_t)HBINS*4,stream);
      hist_g<<<CDIV(N,256),256,0,stream>>>(ek,N,sh,selT,hist);
      part21<<<2048,256,0,stream>>>(hist,partial);
      findbin_g<<<1,256,0,stream>>>(partial,hist,selT,selRB,k,sh);
    }
    // bucketed exact ranking (rank_fill consumes hist back to all-zero)
    hipMemsetAsync(hist,0,(size_t)HBINS*4,stream);
    rank_hist  <<<CDIV(N,256),256,0,stream>>>(ek,N,selT,hist);
    part21     <<<2048,256,0,stream>>>(hist,partial);
    scan(partial,partial2,nullptr,2048,nullptr);
    binscan    <<<2048,256,0,stream>>>(hist,partial2,binstarts);
    rank_fill  <<<CDIV(N,256),256,0,stream>>>(ek,N,selT,binstarts,hist,mkeys,midx);
    rank_within<<<CDIV(N,256),256,0,stream>>>(binstarts,mkeys,midx,rank,N);
    scatter_perm<<<CDIV(N,256),256,0,stream>>>(rank,N,k,perm);
    pool_gather<<<CDIV(k*32,256),256,0,stream>>>(h,score,perm,k,A);
    hipMemcpyAsync(h,A,(size_t)k*128*4,hipMemcpyDeviceToDevice,stream);
    pos_gather<<<CDIV(k*3,256),256,0,stream>>>(pcur,perm,k,pnext);
    // fused filter_adj scan (flags inline, direct ns/nd write)
    {
      int nb = CDIV(Emax+1, SCH);
      fscan_p1<<<nb,256,0,stream>>>(es,ed,pE,Emax,rank,k,bsums);
      scan_p2<<<1,256,0,stream>>>(bsums,nb);
      fscan_p3<<<nb,256,0,stream>>>(es,ed,pE,Emax,rank,k,bsums,ns,nd,cnt+eslot);
    }
  };

  // ================= pipeline =================
  build_csr_dst(eisrc,eidst,nullptr,EE0, NN0);
  feat_conv(Wl0,Wr0,We0,a0,b0, NN0, pos0, true);
  feat_conv(Wls+0*16768,Wrs+0*16768,Wes+0*384,atts+0*128,bs+0*128, NN0, pos0, false);
  pool(0, NN0, KK1, eisrc,eidst,nullptr,EE0, pos0,pos1, eb0s,eb0d, C_E1);
  build_csr_dst(eb0s,eb0d,cnt+C_E1,EE0, KK1);
  feat_conv(Wls+1*16768,Wrs+1*16768,Wes+1*384,atts+1*128,bs+1*128, KK1, pos1, false);
  pool(1, KK1, KK2, eb0s,eb0d,cnt+C_E1,EE0, pos1,pos2, eb1s,eb1d, C_E2);
  build_csr_dst(eb1s,eb1d,cnt+C_E2,EE0, KK2);
  feat_conv(Wls+2*16768,Wrs+2*16768,Wes+2*384,atts+2*128,bs+2*128, KK2, pos2, false);
  feat_conv(Wls+3*16768,Wrs+3*16768,Wes+3*384,atts+3*128,bs+3*128, KK2, pos2, false);
  gemm_k<2,false><<<CDIV(KK2,32),256,0,stream>>>(h,nullptr,nullptr,linW,nullptr,linb,out,nullptr,KK2);

  calc_offsets<<<1,32,0,stream>>>(cnt,offs);
  {
    dim3 g(CDIV(EE0,256),3);
    emit3_pe <<<g,256,0,stream>>>(eb1s,eb1d,cnt+C_E2, eb0s,eb0d,cnt+C_E1, eisrc,eidst, offs,out);
    emit3_eas<<<g,256,0,stream>>>(eb1s,eb1d,cnt+C_E2,pos2, eb0s,eb0d,cnt+C_E1,pos1, eisrc,eidst,pos0, offs,out);
  }
  {
    dim3 g(CDIV(NN0*3,256),3);
    emit3_pp <<<g,256,0,stream>>>(pos2,pos1,pos0,offs,out);
  }
}

// Round 12
// 1760.021 us; speedup vs baseline: 1.2388x; 1.0237x over previous
//
#include <hip/hip_runtime.h>

typedef unsigned long long ull;

#define NN0 80000
#define EE0 480000
#define KK1 40000
#define KK2 20000
#define FLATMAX 8000000
#define SCH 4096
#define CDIV(a,b) (((a)+(b)-1)/(b))
#define HBINS (1<<21)
#define LSW 1024
#define FCAP 512
#define JCAP 8

// counter slots
#define C_E1 2
#define C_E2 3
#define C_M0 5
#define C_M1 6

__device__ __forceinline__ int getE(const int* p, int s){ if(!p) return s; int e=*p; return e<s? e : s; }
__device__ __forceinline__ float leakyf(float x){ return x>0.f? x : 0.2f*x; }
__device__ __forceinline__ double leakyd(double x){ return x>0.0? x : 0.2*x; }
__device__ __forceinline__ float eluf(float x){ return x>0.f? x : (expf(x)-1.f); }

__device__ __forceinline__ ull encd(double f){ ull u=(ull)__double_as_longlong(f); return (u>>63)? ~u : (u|0x8000000000000000ULL); }

// ---------------- GEMM: xl/xr projections ----------------
template<int MODE, bool DUAL>
__global__ void gemm_k(const float* __restrict__ F1, const float* __restrict__ pos,
                       const float* __restrict__ yv,
                       const float* __restrict__ W1, const float* __restrict__ W2,
                       const float* __restrict__ bias,
                       float* __restrict__ O1, float* __restrict__ O2, int N)
{
  const int K = MODE==0? 11 : (MODE==1? 131 : 128);
  __shared__ float lf[32][132];
  int t = threadIdx.x;
  int row0 = blockIdx.x*32;

  if(MODE==0){
    for(int i=t;i<32*11;i+=256){
      int r=i/11, k=i-r*11; int row=row0+r;
      float f=0.f;
      if(row<N) f = (k<5)? F1[(size_t)row*5+k] : (k<8? pos[(size_t)row*3+(k-5)] : yv[0]);
      lf[r][k]=f;
    }
  } else {
    for(int i=t;i<32*32;i+=256){
      int r=i>>5, c4=i&31; int row=row0+r;
      float4 v; v.x=0.f;v.y=0.f;v.z=0.f;v.w=0.f;
      if(row<N) v = *(const float4*)(F1+(size_t)row*128+c4*4);
      *(float4*)(&lf[r][c4*4]) = v;
    }
    if(MODE==1){
      for(int i=t;i<32*3;i+=256){
        int r=i/3, d=i-r*3; int row=row0+r;
        lf[r][128+d] = (row<N)? pos[(size_t)row*3+d] : 0.f;
      }
    }
  }
  __syncthreads();

  int cg = t&31, rg = t>>5;
  int g = cg*4;
  int rbase = rg*4;

  float acc1[4][4]; float acc2[4][4];
  #pragma unroll
  for(int rr=0;rr<4;rr++)
    #pragma unroll
    for(int c=0;c<4;c++){ acc1[rr][c]=0.f; acc2[rr][c]=0.f; }

  #pragma unroll 4
  for(int k=0;k<K;k++){
    float4 w = *(const float4*)(W1 + (size_t)k*128 + g);
    float4 v; v.x=0.f;v.y=0.f;v.z=0.f;v.w=0.f;
    if(DUAL) v = *(const float4*)(W2 + (size_t)k*128 + g);
    #pragma unroll
    for(int rr=0;rr<4;rr++){
      float f = lf[rbase+rr][k];
      acc1[rr][0]+=f*w.x; acc1[rr][1]+=f*w.y; acc1[rr][2]+=f*w.z; acc1[rr][3]+=f*w.w;
      if(DUAL){ acc2[rr][0]+=f*v.x; acc2[rr][1]+=f*v.y; acc2[rr][2]+=f*v.z; acc2[rr][3]+=f*v.w; }
    }
  }

  float4 bb; bb.x=0.f;bb.y=0.f;bb.z=0.f;bb.w=0.f;
  if(bias) bb = *(const float4*)(bias+g);
  #pragma unroll
  for(int rr=0;rr<4;rr++){
    int row = row0 + rbase + rr;
    if(row<N){
      float4 r1; r1.x=acc1[rr][0]+bb.x; r1.y=acc1[rr][1]+bb.y; r1.z=acc1[rr][2]+bb.z; r1.w=acc1[rr][3]+bb.w;
      *(float4*)(O1+(size_t)row*128+g) = r1;
      if(DUAL){
        float4 r2; r2.x=acc2[rr][0]; r2.y=acc2[rr][1]; r2.z=acc2[rr][2]; r2.w=acc2[rr][3];
        *(float4*)(O2+(size_t)row*128+g) = r2;
      }
    }
  }
}

// ---------------- multi-block exclusive scan (generic) ----------------
__global__ void scan_p1(const int* __restrict__ in, const int* pN, int Ns, int* __restrict__ bsums){
  __shared__ int red[256];
  int n = getE(pN,Ns);
  int base = blockIdx.x*SCH;
  int s=0;
  for(int i=base+threadIdx.x; i<base+SCH; i+=256) if(i<n) s+=in[i];
  red[threadIdx.x]=s; __syncthreads();
  for(int o=128;o;o>>=1){ if(threadIdx.x<(unsigned)o) red[threadIdx.x]+=red[threadIdx.x+o]; __syncthreads(); }
  if(threadIdx.x==0) bsums[blockIdx.x]=red[0];
}
__global__ void scan_p2(int* bsums, int nb){
  __shared__ int lds[256];
  int t=threadIdx.x;
  int v = (t<nb)? bsums[t] : 0;
  lds[t]=v; __syncthreads();
  for(int o=1;o<256;o<<=1){ int u=0; if(t>=o) u=lds[t-o]; __syncthreads(); lds[t]+=u; __syncthreads(); }
  if(t<nb) bsums[t]=lds[t]-v;
}
__global__ void scan_p3(const int* __restrict__ in, int* __restrict__ out, const int* pN, int Ns,
                        const int* __restrict__ bsums, int* total){
  __shared__ int tsum[256];
  int n = getE(pN,Ns);
  int base = blockIdx.x*SCH + threadIdx.x*16;
  int v[16]; int s=0;
  #pragma unroll
  for(int q=0;q<16;q++){ int i=base+q; int xv=(i<n)? in[i]:0; v[q]=s; s+=xv; }
  tsum[threadIdx.x]=s; __syncthreads();
  int mine=s;
  for(int o=1;o<256;o<<=1){ int u=0; if(threadIdx.x>=(unsigned)o) u=tsum[threadIdx.x-o]; __syncthreads(); tsum[threadIdx.x]+=u; __syncthreads(); }
  int pre = bsums[blockIdx.x] + tsum[threadIdx.x] - mine;
  #pragma unroll
  for(int q=0;q<16;q++){
    int i=base+q;
    if(i<=n){
      int val = pre+v[q];
      out[i]=val;
      if(i==n && total) *total=val;
    }
  }
}

// ---------------- fused filter_adj scan: flags computed inline from rank ----------------
__global__ void fscan_p1(const int* __restrict__ es, const int* __restrict__ ed, const int* pE, int Es,
                         const int* __restrict__ rank, int k, int* __restrict__ bsums){
  __shared__ int red[256];
  int n = getE(pE,Es);
  int base = blockIdx.x*SCH;
  int s=0;
  for(int i=base+threadIdx.x; i<base+SCH; i+=256)
    if(i<n) s += (rank[es[i]]<k && rank[ed[i]]<k) ? 1 : 0;
  red[threadIdx.x]=s; __syncthreads();
  for(int o=128;o;o>>=1){ if(threadIdx.x<(unsigned)o) red[threadIdx.x]+=red[threadIdx.x+o]; __syncthreads(); }
  if(threadIdx.x==0) bsums[blockIdx.x]=red[0];
}
__global__ void fscan_p3(const int* __restrict__ es, const int* __restrict__ ed, const int* pE, int Es,
                         const int* __restrict__ rank, int k, const int* __restrict__ bsums,
                         int* __restrict__ ns, int* __restrict__ nd, int* total){
  __shared__ int tsum[256];
  int n = getE(pE,Es);
  int base = blockIdx.x*SCH + threadIdx.x*16;
  int v[16]; int rs[16], rd[16]; unsigned fm=0; int s=0;
  #pragma unroll
  for(int q=0;q<16;q++){
    int i=base+q; int xv=0;
    if(i<n){
      int a=rank[es[i]], b=rank[ed[i]];
      rs[q]=a; rd[q]=b;
      if(a<k && b<k){ xv=1; fm |= 1u<<q; }
    }
    v[q]=s; s+=xv;
  }
  tsum[threadIdx.x]=s; __syncthreads();
  int mine=s;
  for(int o=1;o<256;o<<=1){ int u=0; if(threadIdx.x>=(unsigned)o) u=tsum[threadIdx.x-o]; __syncthreads(); tsum[threadIdx.x]+=u; __syncthreads(); }
  int pre = bsums[blockIdx.x] + tsum[threadIdx.x] - mine;
  #pragma unroll
  for(int q=0;q<16;q++){
    int i=base+q;
    if(i<n && ((fm>>q)&1u)){
      int p = pre+v[q];
      ns[p]=rs[q]; nd[p]=rd[q];
    }
    if(i==n && total) *total = pre+v[q];
  }
}

// ---------------- CSR builders ----------------
__global__ void count_src(const int* __restrict__ es, const int* pE, int Es, int* cnts){
  int e = blockIdx.x*256+threadIdx.x; int E = getE(pE,Es); if(e>=E) return;
  atomicAdd(&cnts[es[e]], 1);
}
__global__ void fill_eord(const int* __restrict__ es, const int* __restrict__ ed, const int* pE, int Es,
                          const int* __restrict__ dstarts, int* cursor, int* insrc){
  int e = blockIdx.x*256+threadIdx.x; int E = getE(pE,Es); if(e>=E) return;
  int d = ed[e];
  int p = dstarts[d] + atomicAdd(&cursor[d],1);
  insrc[p] = es[e];
}

// ---------------- FUSED feature GATv2 (fp32): logits + softmax-accumulate ----------------
// One wave per node, 4 waves/block. A-row values for the first JCAP in-edges are
// register-cached in pass A (static unroll indices) so pass B avoids re-gathering A.
// Serial j-order of every accumulation is preserved -> h bit-identical.
__global__ void feat_fused(const int* __restrict__ insrc, const int* __restrict__ dstarts,
                           const float* __restrict__ A, const float* __restrict__ B,
                           const float* __restrict__ pos,
                           const float* __restrict__ We, const float* __restrict__ att,
                           const float* __restrict__ bias, float* __restrict__ h, int N)
{
  __shared__ float lgAll[4][FCAP];
  int wv = threadIdx.x>>6, lane = threadIdx.x&63;
  int w = blockIdx.x*4 + wv;
  bool active = (w<N);
  if(!active) w = N-1;
  float* lg = lgAll[wv];
  int r0=dstarts[w], r1=dstarts[w+1]; int din=r1-r0;
  int c=lane, c2=lane+64;
  float B0 = B[(size_t)w*128+c], B1 = B[(size_t)w*128+c2];
  float We0c=We[c], We1c=We[128+c], We2c=We[256+c];
  float We0d=We[c2], We1d=We[128+c2], We2d=We[256+c2];
  float attc=att[c], attd=att[c2];
  float pw0=pos[w*3], pw1=pos[w*3+1], pw2=pos[w*3+2];

  float ra0[JCAP], ra1[JCAP];
  float l0=0,l1=0,l2=0;
  // pass A: serial j (blocked by JCAP for static reg-cache indices)
  for(int jb=0;jb<din;jb+=JCAP){
    #pragma unroll
    for(int u=0;u<JCAP;u++){
      int j=jb+u;
      if(j<din){
        int s = insrc[r0+j];
        float e0=pw0-pos[s*3], e1=pw1-pos[s*3+1], e2=pw2-pos[s*3+2];
        l0+=e0; l1+=e1; l2+=e2;
        float a0=A[(size_t)s*128+c], a1=A[(size_t)s*128+c2];
        if(jb==0){ ra0[u]=a0; ra1[u]=a1; }
        float m1 = a0 + B0 + e0*We0c + e1*We1c + e2*We2c;
        float m2 = a1 + B1 + e0*We0d + e1*We1d + e2*We2d;
        float p = leakyf(m1)*attc + leakyf(m2)*attd;
        for(int o=32;o;o>>=1) p += __shfl_down(p,o,64);
        if(lane==0 && j<FCAP) lg[j]=p;
      }
    }
  }
  float inv = 1.f/fmaxf((float)din, 1.f);
  float q0=l0*inv, q1=l1*inv, q2=l2*inv;
  float a0w=A[(size_t)w*128+c], a1w=A[(size_t)w*128+c2];
  float pself;
  {
    float m1 = a0w + B0 + q0*We0c + q1*We1c + q2*We2c;
    float m2 = a1w + B1 + q0*We0d + q1*We1d + q2*We2d;
    float p = leakyf(m1)*attc + leakyf(m2)*attd;
    for(int o=32;o;o>>=1) p += __shfl_down(p,o,64);
    pself = __shfl(p,0,64);
  }
  float mx = pself;
  int dc = din<FCAP? din : FCAP;
  for(int j=lane;j<dc;j+=64) mx = fmaxf(mx, lg[j]);
  for(int o=32;o;o>>=1) mx = fmaxf(mx, __shfl_down(mx,o,64));
  mx = __shfl(mx,0,64);
  for(int j=FCAP;j<din;j++){
    int s = insrc[r0+j];
    float e0=pw0-pos[s*3], e1=pw1-pos[s*3+1], e2=pw2-pos[s*3+2];
    float a0=A[(size_t)s*128+c], a1=A[(size_t)s*128+c2];
    float m1 = a0 + B0 + e0*We0c + e1*We1c + e2*We2c;
    float m2 = a1 + B1 + e0*We0d + e1*We1d + e2*We2d;
    float p = leakyf(m1)*attc + leakyf(m2)*attd;
    for(int o=32;o;o>>=1) p += __shfl_down(p,o,64);
    p = __shfl(p,0,64);
    mx = fmaxf(mx, p);
  }

  // pass B: serial j (same order); cached A values for j<JCAP, reload otherwise
  float denom=0.f, acc0=0.f, acc1=0.f;
  for(int jb=0;jb<din;jb+=JCAP){
    #pragma unroll
    for(int u=0;u<JCAP;u++){
      int j=jb+u;
      if(j<din){
        float a0,a1; int s=-1;
        if(jb==0){ a0=ra0[u]; a1=ra1[u]; }
        else {
          s = insrc[r0+j];
          a0=A[(size_t)s*128+c]; a1=A[(size_t)s*128+c2];
        }
        float lgj;
        if(j<FCAP) lgj = lg[j];
        else {
          float e0=pw0-pos[s*3], e1=pw1-pos[s*3+1], e2=pw2-pos[s*3+2];
          float m1 = a0 + B0 + e0*We0c + e1*We1c + e2*We2c;
          float m2 = a1 + B1 + e0*We0d + e1*We1d + e2*We2d;
          float p = leakyf(m1)*attc + leakyf(m2)*attd;
          for(int o=32;o;o>>=1) p += __shfl_down(p,o,64);
          lgj = __shfl(p,0,64);
        }
        float z = expf(lgj - mx);
        denom += z;
        acc0 += z*a0;
        acc1 += z*a1;
      }
    }
  }
  {
    float z = expf(pself - mx);
    denom += z;
    acc0 += z*a0w; acc1 += z*a1w;
  }
  float iv = 1.f/denom;
  float b0v=bias[c], b1v=bias[c2];
  acc0 = eluf(acc0*iv + b0v); acc1 = eluf(acc1*iv + b1v);
  if(active){
    h[(size_t)w*128+c ] = acc0;
    h[(size_t)w*128+c2] = acc1;
  }
}

// ---------------- score GATv2 (fp64) ----------------
__global__ void gemm_score(const float* __restrict__ h, const float* __restrict__ pos,
                           const float* __restrict__ pWl, const float* __restrict__ pWr,
                           double* __restrict__ xls, double* __restrict__ xrs, int N)
{
  int t = threadIdx.x;
  int lane = t&31;
  int n = blockIdx.x*8 + (t>>5);
  if(n>=N) return;
  double sl=0, sr=0;
  #pragma unroll
  for(int q=0;q<4;q++){
    int k = lane + q*32;
    double f = (double)h[(size_t)n*128+k];
    sl += f*(double)pWl[k]; sr += f*(double)pWr[k];
  }
  if(lane<3){
    double f = (double)pos[n*3+lane];
    sl += f*(double)pWl[128+lane]; sr += f*(double)pWr[128+lane];
  }
  for(int o=16;o;o>>=1){ sl += __shfl_down(sl,o,32); sr += __shfl_down(sr,o,32); }
  if(lane==0){ xls[n]=sl; xrs[n]=sr; }
}

// fused score GATv2 (writes score AND encoded key ek directly)
__global__ void score_fused2(const int* __restrict__ insrc, const int* __restrict__ dstarts,
                             const float* __restrict__ pos,
                             const double* __restrict__ xls, const double* __restrict__ xrs,
                             const float* __restrict__ pWe, const float* __restrict__ paP,
                             const float* __restrict__ pbP,
                             double* __restrict__ score, ull* __restrict__ ek, int N)
{
  __shared__ int lsAll[4][LSW];
  int wv = threadIdx.x>>6;
  int lane = threadIdx.x&63;
  int w = blockIdx.x*4 + wv;
  bool active = (w<N);
  if(!active) w = N-1;
  int* ls = lsAll[wv];
  int r0=dstarts[w], r1=dstarts[w+1]; int din=r1-r0;
  for(int j=lane;j<din && j<LSW;j+=64) ls[j]=insrc[r0+j];
  __syncthreads();
  int off = din<LSW? din : LSW;
  for(int base=0; base<din && base<LSW; base+=64){
    int t = base + lane;
    int u0=0, len=0;
    if(t<din && t<LSW){
      int u = ls[t];
      u0 = dstarts[u]; len = dstarts[u+1]-u0;
    }
    int pre = len;
    #pragma unroll
    for(int o=1;o<64;o<<=1){ int v=__shfl_up(pre,o,64); if(lane>=o) pre+=v; }
    int tot = __shfl(pre, 63, 64);
    int myoff = off + pre - len;
    for(int j=0;j<len;j++){ int p=myoff+j; if(p<LSW) ls[p]=insrc[u0+j]; }
    off += tot;
  }
  int d = off<LSW? off : LSW;
  __syncthreads();

  float pd0=pos[w*3], pd1=pos[w*3+1], pd2=pos[w*3+2];
  double w0=(double)pWe[0], w1=(double)pWe[1], w2=(double)pWe[2], pa=(double)paP[0];
  double xrd=xrs[w];
  ull umask=0;
  double lgv[4], xv[4];
  double mx=-1e300, s0=0,s1=0,s2=0; int ucnt=0;
  #pragma unroll
  for(int it=0; it<4; it++){
    int j = lane + it*64;
    if(j<d){
      int s = ls[j];
      bool uniq = true;
      for(int q=0;q<j;q++) if(ls[q]==s){ uniq=false; break; }
      if(uniq){
        umask |= 1ULL<<it;
        ucnt++;
        double e0=(double)(pd0-pos[s*3]), e1=(double)(pd1-pos[s*3+1]), e2=(double)(pd2-pos[s*3+2]);
        s0+=e0; s1+=e1; s2+=e2;
        double xl = xls[s];
        double lg = leakyd(xl+xrd + e0*w0+e1*w1+e2*w2) * pa;
        lgv[it]=lg; xv[it]=xl;
        mx = fmax(mx, lg);
      }
    }
  }
  int nb=4;
  for(int j=lane+256; j<d; j+=64, nb++){
    int s = ls[j];
    bool uniq = true;
    for(int q=0;q<j;q++) if(ls[q]==s){ uniq=false; break; }
    if(uniq){
      umask |= 1ULL<<nb;
      ucnt++;
      double e0=(double)(pd0-pos[s*3]), e1=(double)(pd1-pos[s*3+1]), e2=(double)(pd2-pos[s*3+2]);
      s0+=e0; s1+=e1; s2+=e2;
      double lg = leakyd(xls[s]+xrd + e0*w0+e1*w1+e2*w2) * pa;
      mx = fmax(mx, lg);
    }
  }
  for(int o=32;o;o>>=1){
    mx = fmax(mx, __shfl_down(mx,o,64));
    s0 += __shfl_down(s0,o,64);
    s1 += __shfl_down(s1,o,64);
    s2 += __shfl_down(s2,o,64);
    ucnt += __shfl_down(ucnt,o,64);
  }
  mx=__shfl(mx,0,64); s0=__shfl(s0,0,64); s1=__shfl(s1,0,64); s2=__shfl(s2,0,64); ucnt=__shfl(ucnt,0,64);
  double invd = 1.0/(double)(ucnt>0? ucnt : 1);
  double lg_self = leakyd(xls[w]+xrd + (s0*invd)*w0 + (s1*invd)*w1 + (s2*invd)*w2) * pa;
  mx = fmax(mx, lg_self);
  double den=0, acc=0;
  #pragma unroll
  for(int it=0; it<4; it++){
    if((umask>>it)&1ULL){
      double z = exp(lgv[it]-mx);
      den += z; acc += z*xv[it];
    }
  }
  nb=4;
  for(int j=lane+256; j<d; j+=64, nb++){
    if((umask>>nb)&1ULL){
      int s = ls[j];
      double e0=(double)(pd0-pos[s*3]), e1=(double)(pd1-pos[s*3+1]), e2=(double)(pd2-pos[s*3+2]);
      double lg = leakyd(xls[s]+xrd + e0*w0+e1*w1+e2*w2) * pa;
      double z = exp(lg-mx);
      den += z; acc += z*xls[s];
    }
  }
  for(int o=32;o;o>>=1){
    den += __shfl_down(den,o,64);
    acc += __shfl_down(acc,o,64);
  }
  if(lane==0 && active){
    double z = exp(lg_self-mx);
    den += z; acc += z*xls[w];
    double sc = tanh(acc/den + (double)pbP[0]);
    score[w] = sc;
    ek[w] = encd(sc);
  }
}

// ---------------- top-k: 2-round 21-bit refine select + bucketed ranking ----------------
__global__ void hist_g(const ull* __restrict__ ek, int N, int shift, const ull* __restrict__ selT,
                       int* __restrict__ hist){
  int i = blockIdx.x*256+threadIdx.x; if(i>=N) return;
  ull key = ek[i];
  if(shift+21 < 64){
    if((key >> (shift+21)) != ((*selT) >> (shift+21))) return;
  }
  atomicAdd(&hist[(int)((key>>shift)&0x1FFFFF)], 1);
}
__global__ void part21(const int* __restrict__ hist, int* __restrict__ partial){
  __shared__ int red[256];
  int b = blockIdx.x;
  int s=0;
  for(int i=threadIdx.x;i<1024;i+=256) s += hist[b*1024+i];
  red[threadIdx.x]=s; __syncthreads();
  for(int o=128;o;o>>=1){ if(threadIdx.x<(unsigned)o) red[threadIdx.x]+=red[threadIdx.x+o]; __syncthreads(); }
  if(threadIdx.x==0) partial[b]=red[0];
}
__global__ void findbin_g(const int* __restrict__ partial, const int* __restrict__ hist,
                          ull* __restrict__ selT, int* __restrict__ selRB, int k, int shift){
  __shared__ int ts[256];
  __shared__ int cstar, rbase;
  int t=threadIdx.x;
  int keff = k - *selRB;
  int s8[8]; int mysum=0;
  #pragma unroll
  for(int q=0;q<8;q++){ s8[q]=partial[t*8+q]; mysum+=s8[q]; }
  ts[t]=mysum; __syncthreads();
  for(int o=1;o<256;o<<=1){ int u=(t+o<256)? ts[t+o]:0; __syncthreads(); ts[t]+=u; __syncthreads(); }
  int after = (t<255)? ts[t+1] : 0;
  if(ts[t] >= keff && after < keff){
    int run = after;
    for(int q=7;q>=0;q--){
      if(run < keff && run + s8[q] >= keff){ cstar = t*8+q; rbase = run; }
      run += s8[q];
    }
  }
  __syncthreads();
  int cs=cstar, rb=rbase;
  int b4[4]; int ms=0;
  #pragma unroll
  for(int q=0;q<4;q++){ b4[q]=hist[cs*1024 + t*4 + q]; ms+=b4[q]; }
  ts[t]=ms; __syncthreads();
  for(int o=1;o<256;o<<=1){ int u=(t+o<256)? ts[t+o]:0; __syncthreads(); ts[t]+=u; __syncthreads(); }
  int after2 = (t<255)? ts[t+1] : 0;
  if(rb+ts[t] >= keff && rb+after2 < keff){
    int run = rb+after2;
    for(int q=3;q>=0;q--){
      if(run < keff && run + b4[q] >= keff){
        *selT |= ((ull)(cs*1024 + t*4 + q)) << shift;
        *selRB = (k - keff) + run;
      }
      run += b4[q];
    }
  }
}
__global__ void rank_hist(const ull* __restrict__ ek, int N, const ull* __restrict__ selT,
                          int* __restrict__ hist){
  int i = blockIdx.x*256+threadIdx.x; if(i>=N) return;
  ull key = ek[i]; if(key < *selT) return;
  int dg = (int)((~key >> 43) & 0x1FFFFF);
  atomicAdd(&hist[dg], 1);
}
__global__ void binscan(const int* __restrict__ hist, const int* __restrict__ p2,
                        int* __restrict__ binstarts){
  __shared__ int ts[256];
  int b = blockIdx.x, t = threadIdx.x;
  int v[4]; int s=0;
  #pragma unroll
  for(int q=0;q<4;q++){ v[q]=s; s+=hist[b*1024 + t*4 + q]; }
  ts[t]=s; __syncthreads();
  int mine=s;
  for(int o=1;o<256;o<<=1){ int u=0; if(t>=(unsigned)o) u=ts[t-o]; __syncthreads(); ts[t]+=u; __syncthreads(); }
  int pre = p2[b] + ts[t] - mine;
  #pragma unroll
  for(int q=0;q<4;q++) binstarts[b*1024 + t*4 + q] = pre + v[q];
  if(b==2047 && t==255) binstarts[HBINS] = p2[b] + ts[255];
}
__global__ void rank_fill(const ull* __restrict__ ek, int N, const ull* __restrict__ selT,
                          const int* __restrict__ binstarts, int* __restrict__ hist,
                          ull* __restrict__ mkeys, int* __restrict__ midx){
  int i = blockIdx.x*256+threadIdx.x; if(i>=N) return;
  ull key = ek[i]; if(key < *selT) return;
  int dg = (int)((~key >> 43) & 0x1FFFFF);
  int o = atomicSub(&hist[dg], 1) - 1;
  int p = binstarts[dg] + o;
  mkeys[p] = key; midx[p] = i;
}
__global__ void rank_within(const int* __restrict__ binstarts,
                            const ull* __restrict__ mkeys, const int* __restrict__ midx,
                            int* __restrict__ rank, int Nmax){
  int m = blockIdx.x*256+threadIdx.x; if(m>=Nmax) return;
  int total = binstarts[HBINS]; if(m>=total) return;
  ull key = mkeys[m]; int ii = midx[m];
  int dg = (int)((~key >> 43) & 0x1FFFFF);
  int s = binstarts[dg], e = binstarts[dg+1];
  int cnt = 0;
  for(int j=s;j<e;j++){
    ull kj = mkeys[j];
    cnt += (kj > key) || (kj == key && midx[j] < ii);
  }
  rank[ii] = s + cnt;
}
__global__ void scatter_perm(const int* __restrict__ rank, int N, int k, int* __restrict__ perm){
  int i = blockIdx.x*256+threadIdx.x; if(i>=N) return;
  int r = rank[i]; if(r<k) perm[r]=i;
}
__global__ void pool_gather(const float* __restrict__ h, const double* __restrict__ score,
                            const int* __restrict__ perm, int k, float* __restrict__ outA){
  int idx = blockIdx.x*256+threadIdx.x; if(idx>=k*32) return;
  int r = idx>>5, g = (idx&31)*4;
  int p = perm[r]; float sc = (float)score[p];
  const float4 x = *(const float4*)(h + (size_t)p*128 + g);
  float4 o; o.x=x.x*sc; o.y=x.y*sc; o.z=x.z*sc; o.w=x.w*sc;
  *(float4*)(outA + (size_t)r*128 + g) = o;
}
__global__ void pos_gather(const float* __restrict__ posc, const int* __restrict__ perm, int k, float* __restrict__ posn){
  int idx = blockIdx.x*256+threadIdx.x; if(idx>=k*3) return;
  int r = idx/3, j = idx-r*3;
  posn[idx] = posc[perm[r]*3+j];
}

// ---------------- output emit (fused over 3 levels via blockIdx.y) ----------------
__global__ void calc_offsets(const int* __restrict__ cnt, long long* __restrict__ offs){
  if(blockIdx.x==0 && threadIdx.x==0){
    long long E1 = cnt[C_E1], E2 = cnt[C_E2];
    long long o = (long long)KK2*128;
    offs[0]=0;
    offs[1]=o; o += 2*E2;
    offs[2]=o; o += 2*E1;
    offs[3]=o; o += 2*(long long)EE0;
    offs[4]=o; o += (long long)KK2*3;
    offs[5]=o; o += (long long)KK1*3;
    offs[6]=o; o += (long long)NN0*3;
    offs[7]=o; o += 3*E2;
    offs[8]=o; o += 3*E1;
    offs[9]=o;
  }
}
__global__ void emit3_pe(const int* __restrict__ s2, const int* __restrict__ d2, const int* pE2,
                         const int* __restrict__ s1, const int* __restrict__ d1, const int* pE1,
                         const int* __restrict__ s0, const int* __restrict__ d0,
                         const long long* __restrict__ offs, float* __restrict__ out){
  int e = blockIdx.x*256+threadIdx.x;
  int L = blockIdx.y;
  const int* s; const int* d; int E; int oi;
  if(L==0){ s=s2; d=d2; E=getE(pE2,EE0); oi=1; }
  else if(L==1){ s=s1; d=d1; E=getE(pE1,EE0); oi=2; }
  else { s=s0; d=d0; E=EE0; oi=3; }
  if(e>=E) return;
  long long o = offs[oi];
  out[o+e]   = (float)s[e];
  out[o+E+e] = (float)d[e];
}
__global__ void emit3_pp(const float* __restrict__ p2, const float* __restrict__ p1,
                         const float* __restrict__ p0,
                         const long long* __restrict__ offs, float* __restrict__ out){
  int i = blockIdx.x*256+threadIdx.x;
  int L = blockIdx.y;
  const float* p; int n; int oi;
  if(L==0){ p=p2; n=KK2*3; oi=4; }
  else if(L==1){ p=p1; n=KK1*3; oi=5; }
  else { p=p0; n=NN0*3; oi=6; }
  if(i>=n) return;
  out[offs[oi]+i] = p[i];
}
__global__ void emit3_eas(const int* __restrict__ s2, const int* __restrict__ d2, const int* pE2, const float* __restrict__ q2,
                          const int* __restrict__ s1, const int* __restrict__ d1, const int* pE1, const float* __restrict__ q1,
                          const int* __restrict__ s0, const int* __restrict__ d0, const float* __restrict__ q0,
                          const long long* __restrict__ offs, float* __restrict__ out){
  int e = blockIdx.x*256+threadIdx.x;
  int L = blockIdx.y;
  const int* s; const int* d; const float* pos; int E; int oi;
  if(L==0){ s=s2; d=d2; pos=q2; E=getE(pE2,EE0); oi=7; }
  else if(L==1){ s=s1; d=d1; pos=q1; E=getE(pE1,EE0); oi=8; }
  else { s=s0; d=d0; pos=q0; E=EE0; oi=9; }
  if(e>=E) return;
  long long o = offs[oi];
  int ss=s[e], dd=d[e];
  out[o+3*e+0] = pos[dd*3+0]-pos[ss*3+0];
  out[o+3*e+1] = pos[dd*3+1]-pos[ss*3+1];
  out[o+3*e+2] = pos[dd*3+2]-pos[ss*3+2];
}

// =======================================================================
extern "C" void kernel_launch(void* const* d_in, const int* in_sizes, int n_in,
                              void* d_out, int out_size, void* d_ws, size_t ws_size,
                              hipStream_t stream)
{
  const float* x    = (const float*)d_in[0];
  const float* yv   = (const float*)d_in[1];
  const float* pos0 = (const float*)d_in[2];
  const int*   ei   = (const int*)d_in[3];
  const float* Wl0  = (const float*)d_in[4];
  const float* Wr0  = (const float*)d_in[5];
  const float* We0  = (const float*)d_in[6];
  const float* a0   = (const float*)d_in[7];
  const float* b0   = (const float*)d_in[8];
  const float* Wls  = (const float*)d_in[9];
  const float* Wrs  = (const float*)d_in[10];
  const float* Wes  = (const float*)d_in[11];
  const float* atts = (const float*)d_in[12];
  const float* bs   = (const float*)d_in[13];
  const float* pWl  = (const float*)d_in[14];
  const float* pWr  = (const float*)d_in[15];
  const float* pWe  = (const float*)d_in[16];
  const float* pa   = (const float*)d_in[17];
  const float* pb   = (const float*)d_in[18];
  const float* linW = (const float*)d_in[19];
  const float* linb = (const float*)d_in[20];
  float* out = (float*)d_out;

  const int* eisrc = ei;
  const int* eidst = ei + EE0;

  char* base = (char*)d_ws; size_t off = 0;
  auto alloc = [&](size_t b)->void*{
    off = (off + 255) & ~(size_t)255;
    void* p = base + off; off += b; return p;
  };
  int*       cnt     = (int*)alloc(64*4);
  long long* offs    = (long long*)alloc(16*8);
  int*       bsums   = (int*)alloc(256*4);
  ull*       sel     = (ull*)alloc(2*8);
  int*       hist    = (int*)alloc((size_t)HBINS*4);
  int*       partial = (int*)alloc(2048*4);
  int*       partial2= (int*)alloc(2304*4);
  double*    xls     = (double*)alloc((size_t)NN0*8);
  double*    xrs     = (double*)alloc((size_t)NN0*8);
  double*    score   = (double*)alloc((size_t)NN0*8);
  ull*       ek      = (ull*)alloc((size_t)NN0*8);
  int*       rank    = (int*)alloc((size_t)NN0*4);
  int*       perm    = (int*)alloc((size_t)NN0*4);
  int*       cursor  = (int*)alloc((size_t)NN0*4);
  int*       ccnt    = (int*)alloc((size_t)NN0*4);
  int*       dstarts = (int*)alloc((size_t)(NN0+1)*4);
  int*       insrc   = (int*)alloc((size_t)EE0*4);
  int*       eb0s    = (int*)alloc((size_t)EE0*4);
  int*       eb0d    = (int*)alloc((size_t)EE0*4);
  int*       eb1s    = (int*)alloc((size_t)EE0*4);
  int*       eb1d    = (int*)alloc((size_t)EE0*4);
  float*     pos1    = (float*)alloc((size_t)KK1*12);
  float*     pos2    = (float*)alloc((size_t)KK2*12);
  float*     A       = (float*)alloc((size_t)NN0*128*4);
  float*     B       = (float*)alloc((size_t)NN0*128*4);
  float*     h       = (float*)alloc((size_t)NN0*128*4);
  void*      uni     = alloc((size_t)(EE0+FLATMAX)*8);   // union: binstarts+mkeys+midx (ranking)
  if(off > ws_size) return;

  int*    binstarts= (int*)uni;
  ull*    mkeys    = (ull*)((int*)uni + (HBINS + 256));
  int*    midx     = (int*)(mkeys + NN0);
  ull*    selT  = sel;
  int*    selRB = (int*)(sel+1);

  hipMemsetAsync(cnt, 0, 64*4, stream);
  hipMemsetAsync(hist, 0, (size_t)HBINS*4, stream);   // upfront; rank_fill restores zeros each pool

  auto scan = [&](const int* in, int* sout, const int* pN, int Ns, int* total){
    int nb = CDIV(Ns+1, SCH);
    scan_p1<<<nb,256,0,stream>>>(in,pN,Ns,bsums);
    scan_p2<<<1,256,0,stream>>>(bsums,nb);
    scan_p3<<<nb,256,0,stream>>>(in,sout,pN,Ns,bsums,total);
  };

  auto build_csr_dst = [&](const int* es, const int* ed, const int* pE, int Emax, int N){
    hipMemsetAsync(ccnt,0,(size_t)N*4,stream);
    count_src<<<CDIV(Emax,256),256,0,stream>>>(ed,pE,Emax,ccnt);
    scan(ccnt,dstarts,nullptr,N,nullptr);
    hipMemsetAsync(cursor,0,(size_t)N*4,stream);
    fill_eord<<<CDIV(Emax,256),256,0,stream>>>(es,ed,pE,Emax,dstarts,cursor,insrc);
  };

  auto feat_conv = [&](const float* Wl, const float* Wr, const float* We, const float* att, const float* bias,
                       int N, const float* pcur, bool conv0mode){
    if(conv0mode)
      gemm_k<0,true><<<CDIV(N,32),256,0,stream>>>(x,pcur,yv,Wl,Wr,nullptr,A,B,N);
    else
      gemm_k<1,true><<<CDIV(N,32),256,0,stream>>>(h,pcur,nullptr,Wl,Wr,nullptr,A,B,N);
    feat_fused<<<CDIV(N,4),256,0,stream>>>(insrc,dstarts,A,B,pcur,We,att,bias,h,N);
  };

  auto pool = [&](int l, int N, int k, const int* es, const int* ed, const int* pE, int Emax,
                  const float* pcur, float* pnext, int* ns, int* nd, int eslot){
    hipMemsetAsync(rank, 0x3f, (size_t)N*4, stream);     // rank init (0x3f3f3f3f)
    gemm_score<<<CDIV(N,8),256,0,stream>>>(h,pcur,pWl+l*131,pWr+l*131,xls,xrs,N);
    score_fused2<<<CDIV(N,4),256,0,stream>>>(insrc,dstarts,pcur,xls,xrs,pWe+l*3,pa+l,pb+l,score,ek,N);
    // top-k: 2-round refine select (hist is all-zero entering round 0)
    hipMemsetAsync(sel,0,16,stream);
    for(int r=0;r<2;r++){
      int sh = 43 - 21*r;
      if(r>0) hipMemsetAsync(hist,0,(size_t)HBINS*4,stream);
      hist_g<<<CDIV(N,256),256,0,stream>>>(ek,N,sh,selT,hist);
      part21<<<2048,256,0,stream>>>(hist,partial);
      findbin_g<<<1,256,0,stream>>>(partial,hist,selT,selRB,k,sh);
    }
    // bucketed exact ranking (rank_fill consumes hist back to all-zero)
    hipMemsetAsync(hist,0,(size_t)HBINS*4,stream);
    rank_hist  <<<CDIV(N,256),256,0,stream>>>(ek,N,selT,hist);
    part21     <<<2048,256,0,stream>>>(hist,partial);
    scan(partial,partial2,nullptr,2048,nullptr);
    binscan    <<<2048,256,0,stream>>>(hist,partial2,binstarts);
    rank_fill  <<<CDIV(N,256),256,0,stream>>>(ek,N,selT,binstarts,hist,mkeys,midx);
    rank_within<<<CDIV(N,256),256,0,stream>>>(binstarts,mkeys,midx,rank,N);
    scatter_perm<<<CDIV(N,256),256,0,stream>>>(rank,N,k,perm);
    pool_gather<<<CDIV(k*32,256),256,0,stream>>>(h,score,perm,k,A);
    hipMemcpyAsync(h,A,(size_t)k*128*4,hipMemcpyDeviceToDevice,stream);
    pos_gather<<<CDIV(k*3,256),256,0,stream>>>(pcur,perm,k,pnext);
    // fused filter_adj scan (flags inline, direct ns/nd write)
    {
      int nb = CDIV(Emax+1, SCH);
      fscan_p1<<<nb,256,0,stream>>>(es,ed,pE,Emax,rank,k,bsums);
      scan_p2<<<1,256,0,stream>>>(bsums,nb);
      fscan_p3<<<nb,256,0,stream>>>(es,ed,pE,Emax,rank,k,bsums,ns,nd,cnt+eslot);
    }
  };

  // ================= pipeline =================
  build_csr_dst(eisrc,eidst,nullptr,EE0, NN0);
  feat_conv(Wl0,Wr0,We0,a0,b0, NN0, pos0, true);
  feat_conv(Wls+0*16768,Wrs+0*16768,Wes+0*384,atts+0*128,bs+0*128, NN0, pos0, false);
  pool(0, NN0, KK1, eisrc,eidst,nullptr,EE0, pos0,pos1, eb0s,eb0d, C_E1);
  build_csr_dst(eb0s,eb0d,cnt+C_E1,EE0, KK1);
  feat_conv(Wls+1*16768,Wrs+1*16768,Wes+1*384,atts+1*128,bs+1*128, KK1, pos1, false);
  pool(1, KK1, KK2, eb0s,eb0d,cnt+C_E1,EE0, pos1,pos2, eb1s,eb1d, C_E2);
  build_csr_dst(eb1s,eb1d,cnt+C_E2,EE0, KK2);
  feat_conv(Wls+2*16768,Wrs+2*16768,Wes+2*384,atts+2*128,bs+2*128, KK2, pos2, false);
  feat_conv(Wls+3*16768,Wrs+3*16768,Wes+3*384,atts+3*128,bs+3*128, KK2, pos2, false);
  gemm_k<2,false><<<CDIV(KK2,32),256,0,stream>>>(h,nullptr,nullptr,linW,nullptr,linb,out,nullptr,KK2);

  calc_offsets<<<1,32,0,stream>>>(cnt,offs);
  {
    dim3 g(CDIV(EE0,256),3);
    emit3_pe <<<g,256,0,stream>>>(eb1s,eb1d,cnt+C_E2, eb0s,eb0d,cnt+C_E1, eisrc,eidst, offs,out);
    emit3_eas<<<g,256,0,stream>>>(eb1s,eb1d,cnt+C_E2,pos2, eb0s,eb0d,cnt+C_E1,pos1, eisrc,eidst,pos0, offs,out);
  }
  {
    dim3 g(CDIV(NN0*3,256),3);
    emit3_pp <<<g,256,0,stream>>>(pos2,pos1,pos0,offs,out);
  }
}

// Round 13
// 1637.459 us; speedup vs baseline: 1.3316x; 1.0748x over previous
//
#include <hip/hip_runtime.h>

typedef unsigned long long ull;

#define NN0 80000
#define EE0 480000
#define KK1 40000
#define KK2 20000
#define FLATMAX 8000000
#define SCH 4096
#define CDIV(a,b) (((a)+(b)-1)/(b))
#define HBINS (1<<21)
#define LSW 1024
#define FCAP 512
#define JCAP 8

// counter slots
#define C_E1 2
#define C_E2 3
#define C_M0 5
#define C_M1 6

__device__ __forceinline__ int getE(const int* p, int s){ if(!p) return s; int e=*p; return e<s? e : s; }
__device__ __forceinline__ float leakyf(float x){ return x>0.f? x : 0.2f*x; }
__device__ __forceinline__ double leakyd(double x){ return x>0.0? x : 0.2*x; }
__device__ __forceinline__ float eluf(float x){ return x>0.f? x : (expf(x)-1.f); }

__device__ __forceinline__ ull encd(double f){ ull u=(ull)__double_as_longlong(f); return (u>>63)? ~u : (u|0x8000000000000000ULL); }

// ---------------- GEMM: xl/xr projections ----------------
// In-place safe for F1==O1/O2: each block stages its 32 rows to LDS (syncthreads)
// before writing the same 32 rows; blocks own disjoint rows.
template<int MODE, bool DUAL>
__global__ void gemm_k(const float* __restrict__ F1, const float* __restrict__ pos,
                       const float* __restrict__ yv,
                       const float* __restrict__ W1, const float* __restrict__ W2,
                       const float* __restrict__ bias,
                       float* __restrict__ O1, float* __restrict__ O2, int N)
{
  const int K = MODE==0? 11 : (MODE==1? 131 : 128);
  __shared__ float lf[32][132];
  int t = threadIdx.x;
  int row0 = blockIdx.x*32;

  if(MODE==0){
    for(int i=t;i<32*11;i+=256){
      int r=i/11, k=i-r*11; int row=row0+r;
      float f=0.f;
      if(row<N) f = (k<5)? F1[(size_t)row*5+k] : (k<8? pos[(size_t)row*3+(k-5)] : yv[0]);
      lf[r][k]=f;
    }
  } else {
    for(int i=t;i<32*32;i+=256){
      int r=i>>5, c4=i&31; int row=row0+r;
      float4 v; v.x=0.f;v.y=0.f;v.z=0.f;v.w=0.f;
      if(row<N) v = *(const float4*)(F1+(size_t)row*128+c4*4);
      *(float4*)(&lf[r][c4*4]) = v;
    }
    if(MODE==1){
      for(int i=t;i<32*3;i+=256){
        int r=i/3, d=i-r*3; int row=row0+r;
        lf[r][128+d] = (row<N)? pos[(size_t)row*3+d] : 0.f;
      }
    }
  }
  __syncthreads();

  int cg = t&31, rg = t>>5;
  int g = cg*4;
  int rbase = rg*4;

  float acc1[4][4]; float acc2[4][4];
  #pragma unroll
  for(int rr=0;rr<4;rr++)
    #pragma unroll
    for(int c=0;c<4;c++){ acc1[rr][c]=0.f; acc2[rr][c]=0.f; }

  #pragma unroll 4
  for(int k=0;k<K;k++){
    float4 w = *(const float4*)(W1 + (size_t)k*128 + g);
    float4 v; v.x=0.f;v.y=0.f;v.z=0.f;v.w=0.f;
    if(DUAL) v = *(const float4*)(W2 + (size_t)k*128 + g);
    #pragma unroll
    for(int rr=0;rr<4;rr++){
      float f = lf[rbase+rr][k];
      acc1[rr][0]+=f*w.x; acc1[rr][1]+=f*w.y; acc1[rr][2]+=f*w.z; acc1[rr][3]+=f*w.w;
      if(DUAL){ acc2[rr][0]+=f*v.x; acc2[rr][1]+=f*v.y; acc2[rr][2]+=f*v.z; acc2[rr][3]+=f*v.w; }
    }
  }

  float4 bb; bb.x=0.f;bb.y=0.f;bb.z=0.f;bb.w=0.f;
  if(bias) bb = *(const float4*)(bias+g);
  #pragma unroll
  for(int rr=0;rr<4;rr++){
    int row = row0 + rbase + rr;
    if(row<N){
      float4 r1; r1.x=acc1[rr][0]+bb.x; r1.y=acc1[rr][1]+bb.y; r1.z=acc1[rr][2]+bb.z; r1.w=acc1[rr][3]+bb.w;
      *(float4*)(O1+(size_t)row*128+g) = r1;
      if(DUAL){
        float4 r2; r2.x=acc2[rr][0]; r2.y=acc2[rr][1]; r2.z=acc2[rr][2]; r2.w=acc2[rr][3];
        *(float4*)(O2+(size_t)row*128+g) = r2;
      }
    }
  }
}

// ---------------- multi-block exclusive scan (generic) ----------------
__global__ void scan_p1(const int* __restrict__ in, const int* pN, int Ns, int* __restrict__ bsums){
  __shared__ int red[256];
  int n = getE(pN,Ns);
  int base = blockIdx.x*SCH;
  int s=0;
  for(int i=base+threadIdx.x; i<base+SCH; i+=256) if(i<n) s+=in[i];
  red[threadIdx.x]=s; __syncthreads();
  for(int o=128;o;o>>=1){ if(threadIdx.x<(unsigned)o) red[threadIdx.x]+=red[threadIdx.x+o]; __syncthreads(); }
  if(threadIdx.x==0) bsums[blockIdx.x]=red[0];
}
__global__ void scan_p2(int* bsums, int nb){
  __shared__ int lds[256];
  int t=threadIdx.x;
  int v = (t<nb)? bsums[t] : 0;
  lds[t]=v; __syncthreads();
  for(int o=1;o<256;o<<=1){ int u=0; if(t>=o) u=lds[t-o]; __syncthreads(); lds[t]+=u; __syncthreads(); }
  if(t<nb) bsums[t]=lds[t]-v;
}
__global__ void scan_p3(const int* __restrict__ in, int* __restrict__ out, const int* pN, int Ns,
                        const int* __restrict__ bsums, int* total){
  __shared__ int tsum[256];
  int n = getE(pN,Ns);
  int base = blockIdx.x*SCH + threadIdx.x*16;
  int v[16]; int s=0;
  #pragma unroll
  for(int q=0;q<16;q++){ int i=base+q; int xv=(i<n)? in[i]:0; v[q]=s; s+=xv; }
  tsum[threadIdx.x]=s; __syncthreads();
  int mine=s;
  for(int o=1;o<256;o<<=1){ int u=0; if(threadIdx.x>=(unsigned)o) u=tsum[threadIdx.x-o]; __syncthreads(); tsum[threadIdx.x]+=u; __syncthreads(); }
  int pre = bsums[blockIdx.x] + tsum[threadIdx.x] - mine;
  #pragma unroll
  for(int q=0;q<16;q++){
    int i=base+q;
    if(i<=n){
      int val = pre+v[q];
      out[i]=val;
      if(i==n && total) *total=val;
    }
  }
}

// ---------------- fused filter_adj scan: flags computed inline from rank ----------------
__global__ void fscan_p1(const int* __restrict__ es, const int* __restrict__ ed, const int* pE, int Es,
                         const int* __restrict__ rank, int k, int* __restrict__ bsums){
  __shared__ int red[256];
  int n = getE(pE,Es);
  int base = blockIdx.x*SCH;
  int s=0;
  for(int i=base+threadIdx.x; i<base+SCH; i+=256)
    if(i<n) s += (rank[es[i]]<k && rank[ed[i]]<k) ? 1 : 0;
  red[threadIdx.x]=s; __syncthreads();
  for(int o=128;o;o>>=1){ if(threadIdx.x<(unsigned)o) red[threadIdx.x]+=red[threadIdx.x+o]; __syncthreads(); }
  if(threadIdx.x==0) bsums[blockIdx.x]=red[0];
}
__global__ void fscan_p3(const int* __restrict__ es, const int* __restrict__ ed, const int* pE, int Es,
                         const int* __restrict__ rank, int k, const int* __restrict__ bsums,
                         int* __restrict__ ns, int* __restrict__ nd, int* total){
  __shared__ int tsum[256];
  int n = getE(pE,Es);
  int base = blockIdx.x*SCH + threadIdx.x*16;
  int v[16]; int rs[16], rd[16]; unsigned fm=0; int s=0;
  #pragma unroll
  for(int q=0;q<16;q++){
    int i=base+q; int xv=0;
    if(i<n){
      int a=rank[es[i]], b=rank[ed[i]];
      rs[q]=a; rd[q]=b;
      if(a<k && b<k){ xv=1; fm |= 1u<<q; }
    }
    v[q]=s; s+=xv;
  }
  tsum[threadIdx.x]=s; __syncthreads();
  int mine=s;
  for(int o=1;o<256;o<<=1){ int u=0; if(threadIdx.x>=(unsigned)o) u=tsum[threadIdx.x-o]; __syncthreads(); tsum[threadIdx.x]+=u; __syncthreads(); }
  int pre = bsums[blockIdx.x] + tsum[threadIdx.x] - mine;
  #pragma unroll
  for(int q=0;q<16;q++){
    int i=base+q;
    if(i<n && ((fm>>q)&1u)){
      int p = pre+v[q];
      ns[p]=rs[q]; nd[p]=rd[q];
    }
    if(i==n && total) *total = pre+v[q];
  }
}

// ---------------- CSR builders ----------------
__global__ void count_src(const int* __restrict__ es, const int* pE, int Es, int* cnts){
  int e = blockIdx.x*256+threadIdx.x; int E = getE(pE,Es); if(e>=E) return;
  atomicAdd(&cnts[es[e]], 1);
}
__global__ void fill_eord(const int* __restrict__ es, const int* __restrict__ ed, const int* pE, int Es,
                          const int* __restrict__ dstarts, int* cursor, int* insrc){
  int e = blockIdx.x*256+threadIdx.x; int E = getE(pE,Es); if(e>=E) return;
  int d = ed[e];
  int p = dstarts[d] + atomicAdd(&cursor[d],1);
  insrc[p] = es[e];
}

// ---------------- FUSED feature GATv2 (fp32): logits + softmax-accumulate ----------------
__global__ void feat_fused(const int* __restrict__ insrc, const int* __restrict__ dstarts,
                           const float* __restrict__ A, const float* __restrict__ B,
                           const float* __restrict__ pos,
                           const float* __restrict__ We, const float* __restrict__ att,
                           const float* __restrict__ bias, float* __restrict__ h, int N)
{
  __shared__ float lgAll[4][FCAP];
  int wv = threadIdx.x>>6, lane = threadIdx.x&63;
  int w = blockIdx.x*4 + wv;
  bool active = (w<N);
  if(!active) w = N-1;
  float* lg = lgAll[wv];
  int r0=dstarts[w], r1=dstarts[w+1]; int din=r1-r0;
  int c=lane, c2=lane+64;
  float B0 = B[(size_t)w*128+c], B1 = B[(size_t)w*128+c2];
  float We0c=We[c], We1c=We[128+c], We2c=We[256+c];
  float We0d=We[c2], We1d=We[128+c2], We2d=We[256+c2];
  float attc=att[c], attd=att[c2];
  float pw0=pos[w*3], pw1=pos[w*3+1], pw2=pos[w*3+2];

  float ra0[JCAP], ra1[JCAP];
  float l0=0,l1=0,l2=0;
  for(int jb=0;jb<din;jb+=JCAP){
    #pragma unroll
    for(int u=0;u<JCAP;u++){
      int j=jb+u;
      if(j<din){
        int s = insrc[r0+j];
        float e0=pw0-pos[s*3], e1=pw1-pos[s*3+1], e2=pw2-pos[s*3+2];
        l0+=e0; l1+=e1; l2+=e2;
        float a0=A[(size_t)s*128+c], a1=A[(size_t)s*128+c2];
        if(jb==0){ ra0[u]=a0; ra1[u]=a1; }
        float m1 = a0 + B0 + e0*We0c + e1*We1c + e2*We2c;
        float m2 = a1 + B1 + e0*We0d + e1*We1d + e2*We2d;
        float p = leakyf(m1)*attc + leakyf(m2)*attd;
        for(int o=32;o;o>>=1) p += __shfl_down(p,o,64);
        if(lane==0 && j<FCAP) lg[j]=p;
      }
    }
  }
  float inv = 1.f/fmaxf((float)din, 1.f);
  float q0=l0*inv, q1=l1*inv, q2=l2*inv;
  float a0w=A[(size_t)w*128+c], a1w=A[(size_t)w*128+c2];
  float pself;
  {
    float m1 = a0w + B0 + q0*We0c + q1*We1c + q2*We2c;
    float m2 = a1w + B1 + q0*We0d + q1*We1d + q2*We2d;
    float p = leakyf(m1)*attc + leakyf(m2)*attd;
    for(int o=32;o;o>>=1) p += __shfl_down(p,o,64);
    pself = __shfl(p,0,64);
  }
  float mx = pself;
  int dc = din<FCAP? din : FCAP;
  for(int j=lane;j<dc;j+=64) mx = fmaxf(mx, lg[j]);
  for(int o=32;o;o>>=1) mx = fmaxf(mx, __shfl_down(mx,o,64));
  mx = __shfl(mx,0,64);
  for(int j=FCAP;j<din;j++){
    int s = insrc[r0+j];
    float e0=pw0-pos[s*3], e1=pw1-pos[s*3+1], e2=pw2-pos[s*3+2];
    float a0=A[(size_t)s*128+c], a1=A[(size_t)s*128+c2];
    float m1 = a0 + B0 + e0*We0c + e1*We1c + e2*We2c;
    float m2 = a1 + B1 + e0*We0d + e1*We1d + e2*We2d;
    float p = leakyf(m1)*attc + leakyf(m2)*attd;
    for(int o=32;o;o>>=1) p += __shfl_down(p,o,64);
    p = __shfl(p,0,64);
    mx = fmaxf(mx, p);
  }

  float denom=0.f, acc0=0.f, acc1=0.f;
  for(int jb=0;jb<din;jb+=JCAP){
    #pragma unroll
    for(int u=0;u<JCAP;u++){
      int j=jb+u;
      if(j<din){
        float a0,a1; int s=-1;
        if(jb==0){ a0=ra0[u]; a1=ra1[u]; }
        else {
          s = insrc[r0+j];
          a0=A[(size_t)s*128+c]; a1=A[(size_t)s*128+c2];
        }
        float lgj;
        if(j<FCAP) lgj = lg[j];
        else {
          float e0=pw0-pos[s*3], e1=pw1-pos[s*3+1], e2=pw2-pos[s*3+2];
          float m1 = a0 + B0 + e0*We0c + e1*We1c + e2*We2c;
          float m2 = a1 + B1 + e0*We0d + e1*We1d + e2*We2d;
          float p = leakyf(m1)*attc + leakyf(m2)*attd;
          for(int o=32;o;o>>=1) p += __shfl_down(p,o,64);
          lgj = __shfl(p,0,64);
        }
        float z = expf(lgj - mx);
        denom += z;
        acc0 += z*a0;
        acc1 += z*a1;
      }
    }
  }
  {
    float z = expf(pself - mx);
    denom += z;
    acc0 += z*a0w; acc1 += z*a1w;
  }
  float iv = 1.f/denom;
  float b0v=bias[c], b1v=bias[c2];
  acc0 = eluf(acc0*iv + b0v); acc1 = eluf(acc1*iv + b1v);
  if(active){
    h[(size_t)w*128+c ] = acc0;
    h[(size_t)w*128+c2] = acc1;
  }
}

// ---------------- score GATv2 (fp64) ----------------
__global__ void gemm_score(const float* __restrict__ h, const float* __restrict__ pos,
                           const float* __restrict__ pWl, const float* __restrict__ pWr,
                           double* __restrict__ xls, double* __restrict__ xrs, int N)
{
  int t = threadIdx.x;
  int lane = t&31;
  int n = blockIdx.x*8 + (t>>5);
  if(n>=N) return;
  double sl=0, sr=0;
  #pragma unroll
  for(int q=0;q<4;q++){
    int k = lane + q*32;
    double f = (double)h[(size_t)n*128+k];
    sl += f*(double)pWl[k]; sr += f*(double)pWr[k];
  }
  if(lane<3){
    double f = (double)pos[n*3+lane];
    sl += f*(double)pWl[128+lane]; sr += f*(double)pWr[128+lane];
  }
  for(int o=16;o;o>>=1){ sl += __shfl_down(sl,o,32); sr += __shfl_down(sr,o,32); }
  if(lane==0){ xls[n]=sl; xrs[n]=sr; }
}

// fused score GATv2 (writes score AND encoded key ek directly)
__global__ void score_fused2(const int* __restrict__ insrc, const int* __restrict__ dstarts,
                             const float* __restrict__ pos,
                             const double* __restrict__ xls, const double* __restrict__ xrs,
                             const float* __restrict__ pWe, const float* __restrict__ paP,
                             const float* __restrict__ pbP,
                             double* __restrict__ score, ull* __restrict__ ek, int N)
{
  __shared__ int lsAll[4][LSW];
  int wv = threadIdx.x>>6;
  int lane = threadIdx.x&63;
  int w = blockIdx.x*4 + wv;
  bool active = (w<N);
  if(!active) w = N-1;
  int* ls = lsAll[wv];
  int r0=dstarts[w], r1=dstarts[w+1]; int din=r1-r0;
  for(int j=lane;j<din && j<LSW;j+=64) ls[j]=insrc[r0+j];
  __syncthreads();
  int off = din<LSW? din : LSW;
  for(int base=0; base<din && base<LSW; base+=64){
    int t = base + lane;
    int u0=0, len=0;
    if(t<din && t<LSW){
      int u = ls[t];
      u0 = dstarts[u]; len = dstarts[u+1]-u0;
    }
    int pre = len;
    #pragma unroll
    for(int o=1;o<64;o<<=1){ int v=__shfl_up(pre,o,64); if(lane>=o) pre+=v; }
    int tot = __shfl(pre, 63, 64);
    int myoff = off + pre - len;
    for(int j=0;j<len;j++){ int p=myoff+j; if(p<LSW) ls[p]=insrc[u0+j]; }
    off += tot;
  }
  int d = off<LSW? off : LSW;
  __syncthreads();

  float pd0=pos[w*3], pd1=pos[w*3+1], pd2=pos[w*3+2];
  double w0=(double)pWe[0], w1=(double)pWe[1], w2=(double)pWe[2], pa=(double)paP[0];
  double xrd=xrs[w];
  ull umask=0;
  double lgv[4], xv[4];
  double mx=-1e300, s0=0,s1=0,s2=0; int ucnt=0;
  #pragma unroll
  for(int it=0; it<4; it++){
    int j = lane + it*64;
    if(j<d){
      int s = ls[j];
      bool uniq = true;
      for(int q=0;q<j;q++) if(ls[q]==s){ uniq=false; break; }
      if(uniq){
        umask |= 1ULL<<it;
        ucnt++;
        double e0=(double)(pd0-pos[s*3]), e1=(double)(pd1-pos[s*3+1]), e2=(double)(pd2-pos[s*3+2]);
        s0+=e0; s1+=e1; s2+=e2;
        double xl = xls[s];
        double lg = leakyd(xl+xrd + e0*w0+e1*w1+e2*w2) * pa;
        lgv[it]=lg; xv[it]=xl;
        mx = fmax(mx, lg);
      }
    }
  }
  int nb=4;
  for(int j=lane+256; j<d; j+=64, nb++){
    int s = ls[j];
    bool uniq = true;
    for(int q=0;q<j;q++) if(ls[q]==s){ uniq=false; break; }
    if(uniq){
      umask |= 1ULL<<nb;
      ucnt++;
      double e0=(double)(pd0-pos[s*3]), e1=(double)(pd1-pos[s*3+1]), e2=(double)(pd2-pos[s*3+2]);
      s0+=e0; s1+=e1; s2+=e2;
      double lg = leakyd(xls[s]+xrd + e0*w0+e1*w1+e2*w2) * pa;
      mx = fmax(mx, lg);
    }
  }
  for(int o=32;o;o>>=1){
    mx = fmax(mx, __shfl_down(mx,o,64));
    s0 += __shfl_down(s0,o,64);
    s1 += __shfl_down(s1,o,64);
    s2 += __shfl_down(s2,o,64);
    ucnt += __shfl_down(ucnt,o,64);
  }
  mx=__shfl(mx,0,64); s0=__shfl(s0,0,64); s1=__shfl(s1,0,64); s2=__shfl(s2,0,64); ucnt=__shfl(ucnt,0,64);
  double invd = 1.0/(double)(ucnt>0? ucnt : 1);
  double lg_self = leakyd(xls[w]+xrd + (s0*invd)*w0 + (s1*invd)*w1 + (s2*invd)*w2) * pa;
  mx = fmax(mx, lg_self);
  double den=0, acc=0;
  #pragma unroll
  for(int it=0; it<4; it++){
    if((umask>>it)&1ULL){
      double z = exp(lgv[it]-mx);
      den += z; acc += z*xv[it];
    }
  }
  nb=4;
  for(int j=lane+256; j<d; j+=64, nb++){
    if((umask>>nb)&1ULL){
      int s = ls[j];
      double e0=(double)(pd0-pos[s*3]), e1=(double)(pd1-pos[s*3+1]), e2=(double)(pd2-pos[s*3+2]);
      double lg = leakyd(xls[s]+xrd + e0*w0+e1*w1+e2*w2) * pa;
      double z = exp(lg-mx);
      den += z; acc += z*xls[s];
    }
  }
  for(int o=32;o;o>>=1){
    den += __shfl_down(den,o,64);
    acc += __shfl_down(acc,o,64);
  }
  if(lane==0 && active){
    double z = exp(lg_self-mx);
    den += z; acc += z*xls[w];
    double sc = tanh(acc/den + (double)pbP[0]);
    score[w] = sc;
    ek[w] = encd(sc);
  }
}

// ---------------- top-k: 2-round 21-bit refine select + bucketed ranking ----------------
__global__ void hist_g(const ull* __restrict__ ek, int N, int shift, const ull* __restrict__ selT,
                       int* __restrict__ hist){
  int i = blockIdx.x*256+threadIdx.x; if(i>=N) return;
  ull key = ek[i];
  if(shift+21 < 64){
    if((key >> (shift+21)) != ((*selT) >> (shift+21))) return;
  }
  atomicAdd(&hist[(int)((key>>shift)&0x1FFFFF)], 1);
}
__global__ void part21(const int* __restrict__ hist, int* __restrict__ partial){
  __shared__ int red[256];
  int b = blockIdx.x;
  int s=0;
  for(int i=threadIdx.x;i<1024;i+=256) s += hist[b*1024+i];
  red[threadIdx.x]=s; __syncthreads();
  for(int o=128;o;o>>=1){ if(threadIdx.x<(unsigned)o) red[threadIdx.x]+=red[threadIdx.x+o]; __syncthreads(); }
  if(threadIdx.x==0) partial[b]=red[0];
}
__global__ void findbin_g(const int* __restrict__ partial, const int* __restrict__ hist,
                          ull* __restrict__ selT, int* __restrict__ selRB, int k, int shift){
  __shared__ int ts[256];
  __shared__ int cstar, rbase;
  int t=threadIdx.x;
  int keff = k - *selRB;
  int s8[8]; int mysum=0;
  #pragma unroll
  for(int q=0;q<8;q++){ s8[q]=partial[t*8+q]; mysum+=s8[q]; }
  ts[t]=mysum; __syncthreads();
  for(int o=1;o<256;o<<=1){ int u=(t+o<256)? ts[t+o]:0; __syncthreads(); ts[t]+=u; __syncthreads(); }
  int after = (t<255)? ts[t+1] : 0;
  if(ts[t] >= keff && after < keff){
    int run = after;
    for(int q=7;q>=0;q--){
      if(run < keff && run + s8[q] >= keff){ cstar = t*8+q; rbase = run; }
      run += s8[q];
    }
  }
  __syncthreads();
  int cs=cstar, rb=rbase;
  int b4[4]; int ms=0;
  #pragma unroll
  for(int q=0;q<4;q++){ b4[q]=hist[cs*1024 + t*4 + q]; ms+=b4[q]; }
  ts[t]=ms; __syncthreads();
  for(int o=1;o<256;o<<=1){ int u=(t+o<256)? ts[t+o]:0; __syncthreads(); ts[t]+=u; __syncthreads(); }
  int after2 = (t<255)? ts[t+1] : 0;
  if(rb+ts[t] >= keff && rb+after2 < keff){
    int run = rb+after2;
    for(int q=3;q>=0;q--){
      if(run < keff && run + b4[q] >= keff){
        *selT |= ((ull)(cs*1024 + t*4 + q)) << shift;
        *selRB = (k - keff) + run;
      }
      run += b4[q];
    }
  }
}
// suffix sums of partial[2048]: csum[b] = sum_{b'>b} partial[b']
__global__ void sufscan2048(const int* __restrict__ in, int* __restrict__ outcs){
  __shared__ int ts[256];
  int t=threadIdx.x;
  int v[8]; int s=0;
  #pragma unroll
  for(int q=7;q>=0;q--){ v[q]=s; s+=in[t*8+q]; }
  ts[t]=s; __syncthreads();
  int mine=s;
  for(int o=1;o<256;o<<=1){ int u=(t+o<256)? ts[t+o]:0; __syncthreads(); ts[t]+=u; __syncthreads(); }
  int post = ts[t] - mine;
  #pragma unroll
  for(int q=0;q<8;q++) outcs[t*8+q] = post + v[q];
}
// binstarts over COMPLEMENTED bin order, read directly from round-1 hist (reversed).
__global__ void binscan_rev(const int* __restrict__ hist1, const int* __restrict__ csum,
                            int* __restrict__ binstarts){
  __shared__ int ts[256];
  int cb = blockIdx.x, t = threadIdx.x;
  int v[4]; int s=0;
  #pragma unroll
  for(int q=0;q<4;q++){
    int ci = cb*1024 + t*4 + q;
    v[q]=s; s += hist1[HBINS-1-ci];
  }
  ts[t]=s; __syncthreads();
  int mine=s;
  for(int o=1;o<256;o<<=1){ int u=0; if(t>=(unsigned)o) u=ts[t-o]; __syncthreads(); ts[t]+=u; __syncthreads(); }
  int base = csum[2047-cb];
  int pre = base + ts[t] - mine;
  #pragma unroll
  for(int q=0;q<4;q++) binstarts[cb*1024 + t*4 + q] = pre + v[q];
  if(cb==2047 && t==255) binstarts[HBINS] = csum[0] + ts[255];
}
// scatter candidate (key,idx); cursors = intact round-1 hist (uncomplemented digit)
__global__ void rank_fill(const ull* __restrict__ ek, int N, const ull* __restrict__ selT,
                          const int* __restrict__ binstarts, int* __restrict__ hist1,
                          ull* __restrict__ mkeys, int* __restrict__ midx){
  int i = blockIdx.x*256+threadIdx.x; if(i>=N) return;
  ull key = ek[i]; if(key < *selT) return;
  int dg  = (int)((key >> 43) & 0x1FFFFF);
  int cdg = 0x1FFFFF - dg;
  int o = atomicSub(&hist1[dg], 1) - 1;
  int p = binstarts[cdg] + o;
  mkeys[p] = key; midx[p] = i;
}
// exact rank over member slots; garbage slots (zeroed mkeys) and sub-threshold guarded.
__global__ void rank_within(const int* __restrict__ binstarts,
                            const ull* __restrict__ mkeys, const int* __restrict__ midx,
                            const ull* __restrict__ selT, int* __restrict__ rank, int Nmax){
  int m = blockIdx.x*256+threadIdx.x; if(m>=Nmax) return;
  ull key = mkeys[m]; if(key < *selT) return;
  int ii = midx[m];
  int dg = (int)((~key >> 43) & 0x1FFFFF);
  int s = binstarts[dg], e = binstarts[dg+1];
  int cnt = 0;
  for(int j=s;j<e;j++){
    ull kj = mkeys[j];
    cnt += (kj > key) || (kj == key && midx[j] < ii);
  }
  rank[ii] = s + cnt;
}
__global__ void scatter_perm(const int* __restrict__ rank, int N, int k, int* __restrict__ perm){
  int i = blockIdx.x*256+threadIdx.x; if(i>=N) return;
  int r = rank[i]; if(r<k) perm[r]=i;
}
__global__ void pool_gather(const float* __restrict__ h, const double* __restrict__ score,
                            const int* __restrict__ perm, int k, float* __restrict__ outA){
  int idx = blockIdx.x*256+threadIdx.x; if(idx>=k*32) return;
  int r = idx>>5, g = (idx&31)*4;
  int p = perm[r]; float sc = (float)score[p];
  const float4 x = *(const float4*)(h + (size_t)p*128 + g);
  float4 o; o.x=x.x*sc; o.y=x.y*sc; o.z=x.z*sc; o.w=x.w*sc;
  *(float4*)(outA + (size_t)r*128 + g) = o;
}
__global__ void pos_gather(const float* __restrict__ posc, const int* __restrict__ perm, int k, float* __restrict__ posn){
  int idx = blockIdx.x*256+threadIdx.x; if(idx>=k*3) return;
  int r = idx/3, j = idx-r*3;
  posn[idx] = posc[perm[r]*3+j];
}

// ---------------- output emit (fused over 3 levels via blockIdx.y) ----------------
__global__ void calc_offsets(const int* __restrict__ cnt, long long* __restrict__ offs){
  if(blockIdx.x==0 && threadIdx.x==0){
    long long E1 = cnt[C_E1], E2 = cnt[C_E2];
    long long o = (long long)KK2*128;
    offs[0]=0;
    offs[1]=o; o += 2*E2;
    offs[2]=o; o += 2*E1;
    offs[3]=o; o += 2*(long long)EE0;
    offs[4]=o; o += (long long)KK2*3;
    offs[5]=o; o += (long long)KK1*3;
    offs[6]=o; o += (long long)NN0*3;
    offs[7]=o; o += 3*E2;
    offs[8]=o; o += 3*E1;
    offs[9]=o;
  }
}
__global__ void emit3_pe(const int* __restrict__ s2, const int* __restrict__ d2, const int* pE2,
                         const int* __restrict__ s1, const int* __restrict__ d1, const int* pE1,
                         const int* __restrict__ s0, const int* __restrict__ d0,
                         const long long* __restrict__ offs, float* __restrict__ out){
  int e = blockIdx.x*256+threadIdx.x;
  int L = blockIdx.y;
  const int* s; const int* d; int E; int oi;
  if(L==0){ s=s2; d=d2; E=getE(pE2,EE0); oi=1; }
  else if(L==1){ s=s1; d=d1; E=getE(pE1,EE0); oi=2; }
  else { s=s0; d=d0; E=EE0; oi=3; }
  if(e>=E) return;
  long long o = offs[oi];
  out[o+e]   = (float)s[e];
  out[o+E+e] = (float)d[e];
}
__global__ void emit3_pp(const float* __restrict__ p2, const float* __restrict__ p1,
                         const float* __restrict__ p0,
                         const long long* __restrict__ offs, float* __restrict__ out){
  int i = blockIdx.x*256+threadIdx.x;
  int L = blockIdx.y;
  const float* p; int n; int oi;
  if(L==0){ p=p2; n=KK2*3; oi=4; }
  else if(L==1){ p=p1; n=KK1*3; oi=5; }
  else { p=p0; n=NN0*3; oi=6; }
  if(i>=n) return;
  out[offs[oi]+i] = p[i];
}
__global__ void emit3_eas(const int* __restrict__ s2, const int* __restrict__ d2, const int* pE2, const float* __restrict__ q2,
                          const int* __restrict__ s1, const int* __restrict__ d1, const int* pE1, const float* __restrict__ q1,
                          const int* __restrict__ s0, const int* __restrict__ d0, const float* __restrict__ q0,
                          const long long* __restrict__ offs, float* __restrict__ out){
  int e = blockIdx.x*256+threadIdx.x;
  int L = blockIdx.y;
  const int* s; const int* d; const float* pos; int E; int oi;
  if(L==0){ s=s2; d=d2; pos=q2; E=getE(pE2,EE0); oi=7; }
  else if(L==1){ s=s1; d=d1; pos=q1; E=getE(pE1,EE0); oi=8; }
  else { s=s0; d=d0; pos=q0; E=EE0; oi=9; }
  if(e>=E) return;
  long long o = offs[oi];
  int ss=s[e], dd=d[e];
  out[o+3*e+0] = pos[dd*3+0]-pos[ss*3+0];
  out[o+3*e+1] = pos[dd*3+1]-pos[ss*3+1];
  out[o+3*e+2] = pos[dd*3+2]-pos[ss*3+2];
}

// =======================================================================
extern "C" void kernel_launch(void* const* d_in, const int* in_sizes, int n_in,
                              void* d_out, int out_size, void* d_ws, size_t ws_size,
                              hipStream_t stream)
{
  const float* x    = (const float*)d_in[0];
  const float* yv   = (const float*)d_in[1];
  const float* pos0 = (const float*)d_in[2];
  const int*   ei   = (const int*)d_in[3];
  const float* Wl0  = (const float*)d_in[4];
  const float* Wr0  = (const float*)d_in[5];
  const float* We0  = (const float*)d_in[6];
  const float* a0   = (const float*)d_in[7];
  const float* b0   = (const float*)d_in[8];
  const float* Wls  = (const float*)d_in[9];
  const float* Wrs  = (const float*)d_in[10];
  const float* Wes  = (const float*)d_in[11];
  const float* atts = (const float*)d_in[12];
  const float* bs   = (const float*)d_in[13];
  const float* pWl  = (const float*)d_in[14];
  const float* pWr  = (const float*)d_in[15];
  const float* pWe  = (const float*)d_in[16];
  const float* pa   = (const float*)d_in[17];
  const float* pb   = (const float*)d_in[18];
  const float* linW = (const float*)d_in[19];
  const float* linb = (const float*)d_in[20];
  float* out = (float*)d_out;

  const int* eisrc = ei;
  const int* eidst = ei + EE0;

  char* base = (char*)d_ws; size_t off = 0;
  auto alloc = [&](size_t b)->void*{
    off = (off + 255) & ~(size_t)255;
    void* p = base + off; off += b; return p;
  };
  int*       cnt     = (int*)alloc(64*4);
  long long* offs    = (long long*)alloc(16*8);
  int*       bsums   = (int*)alloc(256*4);
  ull*       sel     = (ull*)alloc(2*8);
  int*       hist    = (int*)alloc((size_t)HBINS*4);
  int*       hist2   = (int*)alloc((size_t)HBINS*4);
  int*       partial = (int*)alloc(2048*4);
  int*       partialB= (int*)alloc(2048*4);
  int*       partial2= (int*)alloc(2304*4);
  double*    xls     = (double*)alloc((size_t)NN0*8);
  double*    xrs     = (double*)alloc((size_t)NN0*8);
  double*    score   = (double*)alloc((size_t)NN0*8);
  ull*       ek      = (ull*)alloc((size_t)NN0*8);
  int*       rank    = (int*)alloc((size_t)NN0*4);
  int*       perm    = (int*)alloc((size_t)NN0*4);
  int*       cursor  = (int*)alloc((size_t)NN0*4);
  int*       ccnt    = (int*)alloc((size_t)NN0*4);
  int*       dstarts = (int*)alloc((size_t)(NN0+1)*4);
  int*       insrc   = (int*)alloc((size_t)EE0*4);
  int*       eb0s    = (int*)alloc((size_t)EE0*4);
  int*       eb0d    = (int*)alloc((size_t)EE0*4);
  int*       eb1s    = (int*)alloc((size_t)EE0*4);
  int*       eb1d    = (int*)alloc((size_t)EE0*4);
  float*     pos1    = (float*)alloc((size_t)KK1*12);
  float*     pos2    = (float*)alloc((size_t)KK2*12);
  float*     A       = (float*)alloc((size_t)NN0*128*4);
  float*     B       = (float*)alloc((size_t)NN0*128*4);
  float*     h       = (float*)alloc((size_t)NN0*128*4);
  void*      uni     = alloc((size_t)(EE0+FLATMAX)*8);   // union: binstarts+mkeys+midx (ranking)
  if(off > ws_size) return;

  int*    binstarts= (int*)uni;
  ull*    mkeys    = (ull*)((int*)uni + (HBINS + 256));
  int*    midx     = (int*)(mkeys + NN0);
  ull*    selT  = sel;
  int*    selRB = (int*)(sel+1);

  hipMemsetAsync(cnt, 0, 64*4, stream);
  hipMemsetAsync(hist, 0, (size_t)HBINS*4, stream);   // pool0 round-1 entry

  auto scan = [&](const int* in, int* sout, const int* pN, int Ns, int* total){
    int nb = CDIV(Ns+1, SCH);
    scan_p1<<<nb,256,0,stream>>>(in,pN,Ns,bsums);
    scan_p2<<<1,256,0,stream>>>(bsums,nb);
    scan_p3<<<nb,256,0,stream>>>(in,sout,pN,Ns,bsums,total);
  };

  auto build_csr_dst = [&](const int* es, const int* ed, const int* pE, int Emax, int N){
    hipMemsetAsync(ccnt,0,(size_t)N*4,stream);
    count_src<<<CDIV(Emax,256),256,0,stream>>>(ed,pE,Emax,ccnt);
    scan(ccnt,dstarts,nullptr,N,nullptr);
    hipMemsetAsync(cursor,0,(size_t)N*4,stream);
    fill_eord<<<CDIV(Emax,256),256,0,stream>>>(es,ed,pE,Emax,dstarts,cursor,insrc);
  };

  auto feat_conv = [&](const float* Wl, const float* Wr, const float* We, const float* att, const float* bias,
                       int N, const float* pcur, const float* hin, bool conv0mode){
    if(conv0mode)
      gemm_k<0,true><<<CDIV(N,32),256,0,stream>>>(x,pcur,yv,Wl,Wr,nullptr,A,B,N);
    else
      gemm_k<1,true><<<CDIV(N,32),256,0,stream>>>(hin,pcur,nullptr,Wl,Wr,nullptr,A,B,N);
    feat_fused<<<CDIV(N,4),256,0,stream>>>(insrc,dstarts,A,B,pcur,We,att,bias,h,N);
  };

  auto pool = [&](int l, int N, int k, const int* es, const int* ed, const int* pE, int Emax,
                  const float* pcur, float* pnext, int* ns, int* nd, int eslot){
    hipMemsetAsync(rank, 0x3f, (size_t)N*4, stream);
    if(l>0) hipMemsetAsync(hist, 0, (size_t)HBINS*4, stream);   // re-zero round-1 hist
    gemm_score<<<CDIV(N,8),256,0,stream>>>(h,pcur,pWl+l*131,pWr+l*131,xls,xrs,N);
    score_fused2<<<CDIV(N,4),256,0,stream>>>(insrc,dstarts,pcur,xls,xrs,pWe+l*3,pa+l,pb+l,score,ek,N);
    hipMemsetAsync(sel,0,16,stream);
    // round 1 (hist zero on entry) — hist/partial preserved for ranking
    hist_g<<<CDIV(N,256),256,0,stream>>>(ek,N,43,selT,hist);
    part21<<<2048,256,0,stream>>>(hist,partial);
    findbin_g<<<1,256,0,stream>>>(partial,hist,selT,selRB,k,43);
    // round 2 (separate hist2/partialB)
    hipMemsetAsync(hist2,0,(size_t)HBINS*4,stream);
    hist_g<<<CDIV(N,256),256,0,stream>>>(ek,N,22,selT,hist2);
    part21<<<2048,256,0,stream>>>(hist2,partialB);
    findbin_g<<<1,256,0,stream>>>(partialB,hist2,selT,selRB,k,22);
    // bucketed exact ranking, reusing intact round-1 hist
    hipMemsetAsync(mkeys,0,(size_t)N*8,stream);
    sufscan2048<<<1,256,0,stream>>>(partial,partial2);
    binscan_rev<<<2048,256,0,stream>>>(hist,partial2,binstarts);
    rank_fill  <<<CDIV(N,256),256,0,stream>>>(ek,N,selT,binstarts,hist,mkeys,midx);
    rank_within<<<CDIV(N,256),256,0,stream>>>(binstarts,mkeys,midx,selT,rank,N);
    scatter_perm<<<CDIV(N,256),256,0,stream>>>(rank,N,k,perm);
    pool_gather<<<CDIV(k*32,256),256,0,stream>>>(h,score,perm,k,B);   // gathered features -> B
    pos_gather<<<CDIV(k*3,256),256,0,stream>>>(pcur,perm,k,pnext);
    {
      int nb = CDIV(Emax+1, SCH);
      fscan_p1<<<nb,256,0,stream>>>(es,ed,pE,Emax,rank,k,bsums);
      scan_p2<<<1,256,0,stream>>>(bsums,nb);
      fscan_p3<<<nb,256,0,stream>>>(es,ed,pE,Emax,rank,k,bsums,ns,nd,cnt+eslot);
    }
  };

  // ================= pipeline =================
  build_csr_dst(eisrc,eidst,nullptr,EE0, NN0);
  feat_conv(Wl0,Wr0,We0,a0,b0, NN0, pos0, nullptr, true);
  feat_conv(Wls+0*16768,Wrs+0*16768,Wes+0*384,atts+0*128,bs+0*128, NN0, pos0, h, false);
  pool(0, NN0, KK1, eisrc,eidst,nullptr,EE0, pos0,pos1, eb0s,eb0d, C_E1);   // features -> B
  build_csr_dst(eb0s,eb0d,cnt+C_E1,EE0, KK1);
  feat_conv(Wls+1*16768,Wrs+1*16768,Wes+1*384,atts+1*128,bs+1*128, KK1, pos1, B, false);  // in-place gemm on B
  pool(1, KK1, KK2, eb0s,eb0d,cnt+C_E1,EE0, pos1,pos2, eb1s,eb1d, C_E2);    // features -> B
  build_csr_dst(eb1s,eb1d,cnt+C_E2,EE0, KK2);
  feat_conv(Wls+2*16768,Wrs+2*16768,Wes+2*384,atts+2*128,bs+2*128, KK2, pos2, B, false);
  feat_conv(Wls+3*16768,Wrs+3*16768,Wes+3*384,atts+3*128,bs+3*128, KK2, pos2, h, false);
  gemm_k<2,false><<<CDIV(KK2,32),256,0,stream>>>(h,nullptr,nullptr,linW,nullptr,linb,out,nullptr,KK2);

  calc_offsets<<<1,32,0,stream>>>(cnt,offs);
  {
    dim3 g(CDIV(EE0,256),3);
    emit3_pe <<<g,256,0,stream>>>(eb1s,eb1d,cnt+C_E2, eb0s,eb0d,cnt+C_E1, eisrc,eidst, offs,out);
    emit3_eas<<<g,256,0,stream>>>(eb1s,eb1d,cnt+C_E2,pos2, eb0s,eb0d,cnt+C_E1,pos1, eisrc,eidst,pos0, offs,out);
  }
  {
    dim3 g(CDIV(NN0*3,256),3);
    emit3_pp <<<g,256,0,stream>>>(pos2,pos1,pos0,offs,out);
  }
}